// Round 15
// baseline (75.005 us; speedup 1.0000x reference)
//
#include <hip/hip_runtime.h>
#include <hip/hip_bf16.h>
#include <stdint.h>

#define SEQ     4096
#define HIDDEN  640
#define HDIM    80
#define NH      8
#define NKV     2
#define WINDOW  512
#define SINK    4
#define BQG     32    // flash q-tile (shared by 4 heads)
#define BK      128   // flash key-tile
#define KSTR    104   // Ks row stride (bf16): 2-way banks on b128 reads
#define VSTR    136   // Vt/Pl row stride (bf16): 2-way banks (128+8)
#define VSTRK   40    // Vtk sink row stride

typedef __bf16 bf16x8 __attribute__((ext_vector_type(8)));
typedef float  f32x4  __attribute__((ext_vector_type(4)));

typedef __attribute__((address_space(1))) const void gas_void;
typedef __attribute__((address_space(3))) void las_void;

__device__ inline __bf16 f2bf(float f) {
    union { float f; uint32_t u; } x; x.f = f;
    uint32_t r = x.u + 0x7FFF + ((x.u >> 16) & 1);   // RNE, no NaN inputs
    union { unsigned short s; __bf16 b; } y; y.s = (unsigned short)(r >> 16);
    return y.b;
}
__device__ inline float bf2f(unsigned short u) {
    union { uint32_t u; float f; } c; c.u = ((uint32_t)u) << 16; return c.f;
}
__device__ inline float fexp2(float x) {
#if __has_builtin(__builtin_amdgcn_exp2f)
    return __builtin_amdgcn_exp2f(x);
#else
    return exp2f(x);
#endif
}

// ---------------------------------------------------------------------------
// Fused prep: x -> bf16 (blocks [0,2560)) + all weight transposes
// (blocks [2560,3560), 32x32 tiles).  (r12-proven)
// ---------------------------------------------------------------------------
__global__ __launch_bounds__(256) void prep_kernel(
    const float* __restrict__ x, const float* __restrict__ Wq,
    const float* __restrict__ Wk, const float* __restrict__ Wv,
    const float* __restrict__ Wo, __bf16* __restrict__ xb,
    __bf16* __restrict__ WqkvT, __bf16* __restrict__ WoT)
{
    const int flat = blockIdx.x;
    const int tid  = threadIdx.x;
    if (flat < 2560) {
        int i = flat * 256 + tid;
        const float4 v = *(const float4*)&x[4 * i];
        xb[4 * i + 0] = f2bf(v.x);
        xb[4 * i + 1] = f2bf(v.y);
        xb[4 * i + 2] = f2bf(v.z);
        xb[4 * i + 3] = f2bf(v.w);
        return;
    }
    const int wf = flat - 2560;
    const float* src;
    __bf16* dstb;
    int idx, tiles_x, N;
    if (wf < 400)      { src = Wq; dstb = WqkvT;             idx = wf;       tiles_x = 20; N = 640; }
    else if (wf < 500) { src = Wk; dstb = WqkvT + 640 * 640; idx = wf - 400; tiles_x = 5;  N = 160; }
    else if (wf < 600) { src = Wv; dstb = WqkvT + 800 * 640; idx = wf - 500; tiles_x = 5;  N = 160; }
    else               { src = Wo; dstb = WoT;               idx = wf - 600; tiles_x = 20; N = 640; }
    const int n0 = (idx % tiles_x) * 32;
    const int k0 = (idx / tiles_x) * 32;

    __shared__ float t[32][33];
    const int tx = tid & 31, ty = tid >> 5;     // 32 x 8
    #pragma unroll
    for (int i = 0; i < 4; ++i) {
        int r = ty + 8 * i;
        t[r][tx] = src[(size_t)(k0 + r) * N + n0 + tx];
    }
    __syncthreads();
    #pragma unroll
    for (int i = 0; i < 4; ++i) {
        int r = ty + 8 * i;
        dstb[(size_t)(n0 + r) * 640 + k0 + tx] = f2bf(t[tx][r]);
    }
}

// ---------------------------------------------------------------------------
// MFMA bf16 GEMM v2: 512 threads = 8 waves (2M x 4N), tile 128x128,
// macro-step BK=64, dbuf LDS, staging via global_load_lds width=16
// (m151/m193: direct-to-LDS beats reg-staging at this tile).
// LDS layout: linear [128][64] (gl_lds requires base+lane*16), with XOR
// slot swizzle applied on the GLOBAL source (rule #21 both-sides):
//   physical slot p holds logical k-slot s = p ^ (row&7);
//   frag reads use p = (4h+lq) ^ (row&7)  -> 2-way banks (free).
// 1 barrier per macro-step (compiler emits vmcnt(0) before s_barrier).
// ---------------------------------------------------------------------------
template <typename OutT>
__global__ __launch_bounds__(512) void gemm_bf16_mfma(
    const __bf16* __restrict__ A, const __bf16* __restrict__ BT,
    OutT* __restrict__ C, int M, int N, int K, int ldc)
{
    __shared__ __bf16 As[2][128][64];   // 16384 B per buf
    __shared__ __bf16 Bs[2][128][64];
    const int BUFE = 128 * 64;          // elems per buffer

    const int tid  = threadIdx.x;
    const int wave = tid >> 6;
    const int lane = tid & 63;
    const int wr = wave >> 2, wc = wave & 3;
    const int l15 = lane & 15, lq = lane >> 4;
    const int m0 = blockIdx.y * 128, n0 = blockIdx.x * 128;

    f32x4 acc[4][2];
    #pragma unroll
    for (int m = 0; m < 4; ++m)
        #pragma unroll
        for (int n = 0; n < 2; ++n) acc[m][n] = (f32x4)0.0f;

    // ---- staging descriptors: 2048 chunks of 16 B (A: 0..1023, B: 1024..2047)
    // chunk c: arr = c>>10, cl = c&1023, row = cl>>3, phys slot p = cl&7,
    // logical slot s = p ^ (row&7). Per-thread chunks: c = j*512 + tid.
    const __bf16* gsrcs[2] = { A, BT };
    size_t goff[4];          // per-lane global element offset (ks term added later)
    #pragma unroll
    for (int j = 0; j < 4; ++j) {
        int c   = j * 512 + tid;
        int arr = c >> 10;
        int cl  = c & 1023;
        int row = cl >> 3;
        int s   = (cl & 7) ^ (row & 7);
        int gr  = (arr ? n0 : m0) + row;
        goff[j] = (size_t)gr * K + 8 * s;
    }
    // wave-uniform LDS chunk base for each issue j: cb = j*512 + wave*64
    int lbase[4];            // element offset within the arr (A or B) buffer
    int larr[4];
    #pragma unroll
    for (int j = 0; j < 4; ++j) {
        int cb = j * 512 + wave * 64;
        larr[j]  = cb >> 10;
        lbase[j] = (cb & 1023) * 8;      // 8 bf16 per chunk
    }

#define STAGE(NBUF, KS)                                                        \
    {                                                                          \
        _Pragma("unroll")                                                      \
        for (int j = 0; j < 4; ++j) {                                          \
            const __bf16* gp = gsrcs[j >= 2] + goff[j] + (size_t)(KS) * 64;    \
            __bf16* lp = (larr[j] ? &Bs[NBUF][0][0] : &As[NBUF][0][0]) + lbase[j]; \
            __builtin_amdgcn_global_load_lds((gas_void*)gp, (las_void*)lp, 16, 0, 0); \
        }                                                                      \
    }

    const int nk = K >> 6;               // macro-steps of 64

    STAGE(0, 0);
    __syncthreads();

    for (int ks = 0; ks < nk; ++ks) {
        const int cur = ks & 1;
        if (ks + 1 < nk) STAGE(cur ^ 1, ks + 1);

        __builtin_amdgcn_s_setprio(1);
        #pragma unroll
        for (int h = 0; h < 2; ++h) {
            bf16x8 af[4], bfr[2];
            #pragma unroll
            for (int m = 0; m < 4; ++m) {
                int row = wr * 64 + m * 16 + l15;
                int p   = (4 * h + lq) ^ (row & 7);
                af[m] = *(const bf16x8*)&As[cur][row][8 * p];
            }
            #pragma unroll
            for (int n = 0; n < 2; ++n) {
                int row = wc * 32 + n * 16 + l15;
                int p   = (4 * h + lq) ^ (row & 7);
                bfr[n] = *(const bf16x8*)&Bs[cur][row][8 * p];
            }
            #pragma unroll
            for (int m = 0; m < 4; ++m)
                #pragma unroll
                for (int n = 0; n < 2; ++n)
                    acc[m][n] = __builtin_amdgcn_mfma_f32_16x16x32_bf16(af[m], bfr[n], acc[m][n], 0, 0, 0);
        }
        __builtin_amdgcn_s_setprio(0);

        __syncthreads();   // vmcnt(0)+lgkmcnt(0) drain: next buf ready, cur reads done
    }
#undef STAGE

    #pragma unroll
    for (int m = 0; m < 4; ++m) {
        #pragma unroll
        for (int n = 0; n < 2; ++n) {
            const int col = n0 + wc * 32 + n * 16 + l15;
            if (col < N) {
                const int rbase = m0 + wr * 64 + m * 16 + 4 * lq;
                #pragma unroll
                for (int r = 0; r < 4; ++r) {
                    if constexpr (sizeof(OutT) == 2)
                        C[(size_t)(rbase + r) * ldc + col] = f2bf(acc[m][n][r]);
                    else
                        C[(size_t)(rbase + r) * ldc + col] = acc[m][n][r];
                }
            }
        }
    }
}

// ---------------------------------------------------------------------------
// Fused RMSNorm+RoPE (blocks [0,2048): 2 rows each) and V-transpose
// (blocks [2048,2688): 32x32 tiles). 256 threads. (r12-proven)
// ---------------------------------------------------------------------------
__global__ __launch_bounds__(256) void normrope_vt_kernel(
    const unsigned short* __restrict__ qkvb, const float* __restrict__ cosb,
    const float* __restrict__ sinb, const float* __restrict__ qw,
    const float* __restrict__ kw, __bf16* __restrict__ qb,
    __bf16* __restrict__ kb, unsigned short* __restrict__ vtb)
{
    const int flat = blockIdx.x;
    const int tid  = threadIdx.x;

    __shared__ float red[4];
    __shared__ unsigned short t[32][33];

    if (flat < 2048) {
        const int half = tid >> 7;           // 0..1 -> row pair
        const int lt   = tid & 127;
        const int row  = flat * 2 + half;

        float c = 0.f, s = 0.f, wqv = 0.f, wkv = 0.f;
        if (lt < HDIM) {
            c   = cosb[(size_t)row * (HDIM / 2) + (lt >> 1)];
            s   = sinb[(size_t)row * (HDIM / 2) + (lt >> 1)];
            wqv = qw[lt];
            wkv = kw[lt];
        }
        const float sgn = (lt & 1) ? 1.0f : -1.0f;
        const float QSCALE = 0.11180339887498948f * 1.4426950408889634f;

        for (int hh = 0; hh < 10; ++hh) {
            const unsigned short* p = (hh < NH)
                ? qkvb + (size_t)row * 960 + hh * HDIM
                : qkvb + (size_t)row * 960 + HIDDEN + (hh - NH) * HDIM;
            float v = (lt < HDIM) ? bf2f(p[lt]) : 0.0f;
            float sq = v * v;
            #pragma unroll
            for (int off = 32; off; off >>= 1) sq += __shfl_down(sq, off);
            if ((lt & 63) == 0) red[half * 2 + (lt >> 6)] = sq;
            __syncthreads();
            float rms = rsqrtf((red[half * 2] + red[half * 2 + 1]) * (1.0f / HDIM) + 1e-5f);

            float w  = (hh < NH) ? wqv : wkv;
            float vn = v * rms * w;
            float vp = __shfl_xor(vn, 1);
            float o  = vn * c + sgn * vp * s;

            if (lt < HDIM) {
                if (hh < NH) qb[(size_t)row * HIDDEN + hh * HDIM + lt] = (__bf16)(o * QSCALE);
                else         kb[(size_t)row * (NKV * HDIM) + (hh - NH) * HDIM + lt] = (__bf16)o;
            }
            __syncthreads();
        }
        return;
    }

    // ---- V transpose: vtb[kvh][d][seq] ----
    const int idx = flat - 2048;             // 0..639
    const int s0 = (idx & 127) * 32;
    const int c0 = (idx >> 7) * 32;
    const int tx = tid & 31, ty = tid >> 5;  // 32 x 8
    #pragma unroll
    for (int i = 0; i < 4; ++i)
        t[ty + 8 * i][tx] = qkvb[(size_t)(s0 + ty + 8 * i) * 960 + 800 + c0 + tx];
    __syncthreads();
    #pragma unroll
    for (int i = 0; i < 4; ++i) {
        int g = c0 + ty + 8 * i;             // 0..159
        int kvh = g / HDIM, d = g % HDIM;
        vtb[((size_t)kvh * HDIM + d) * SEQ + s0 + tx] = t[tx][ty + 8 * i];
    }
}

// ---------------------------------------------------------------------------
// GQA-fused MFMA flash attention (r13/r14-proven): BK=128, K/V
// double-buffered (1 barrier/tile) + sink prepass. Block = (32-query tile,
// kvh), 512 threads = 8 waves. LDS 141 KB (1 block/CU).
// Per tile: [load t+1 regs] S -> softmax -> PV -> write t+1 -> barrier.
// ---------------------------------------------------------------------------
__global__ __launch_bounds__(512) void flash_attn_mfma(
    const __bf16* __restrict__ qb, const __bf16* __restrict__ kb,
    const __bf16* __restrict__ vtb, __bf16* __restrict__ attnb)
{
    const int i0   = blockIdx.x * BQG;
    const int kvh  = blockIdx.y;
    const int tid  = threadIdx.x;        // 0..511
    const int w    = tid >> 6;           // 0..7
    const int h    = kvh * 4 + (w >> 1);
    const int wsub = w & 1;
    const int lane = tid & 63;
    const int l15  = lane & 15;
    const int lq   = lane >> 4;

    __shared__ __bf16 Ks[2][BK][KSTR];   // 53248 B
    __shared__ __bf16 Vt[2][HDIM][VSTR]; // 43520 B
    __shared__ __bf16 Pl[128][VSTR];     // 34816 B
    __shared__ __bf16 Ksk[16][KSTR];     //  3328 B (sink K, keys 0..15)
    __shared__ __bf16 Vtk[HDIM][VSTRK];  //  6400 B (sink V, keys 0..31)

    // zero K pad columns 80..95 of BOTH buffers
    {
        int b = tid >> 8, r = (tid >> 1) & 127, c = HDIM + 8 * (tid & 1);
        *(float4*)&Ks[b][r][c] = make_float4(0.f, 0.f, 0.f, 0.f);
    }

    // window staging maps: 1280 chunks of 8 bf16 each (chunk = tid + 512*i)
    int koff[3], voff[3];
    __bf16* ksdst0[3];
    __bf16* vsdst0[3];
    bool act[3];
    #pragma unroll
    for (int i = 0; i < 3; ++i) {
        int c = tid + 512 * i;
        act[i] = (c < 1280);
        int cc = act[i] ? c : 0;
        koff[i] = (cc / 10) * (NKV * HDIM) + 8 * (cc % 10);
        voff[i] = (cc >> 4) * SEQ + 8 * (cc & 15);
        ksdst0[i] = &Ks[0][cc / 10][8 * (cc % 10)];
        vsdst0[i] = &Vt[0][cc >> 4][8 * (cc & 15)];
    }
    const size_t ksbuf = (size_t)BK * KSTR;
    const size_t vsbuf = (size_t)HDIM * VSTR;
    const __bf16* kbase = kb + kvh * HDIM;
    const __bf16* vbase = vtb + (size_t)kvh * HDIM * SEQ;

    // preload Q A-fragments
    bf16x8 qf[3];
    {
        const __bf16* qrow = qb + (size_t)(i0 + 16 * wsub + l15) * HIDDEN + h * HDIM;
        #pragma unroll
        for (int ks = 0; ks < 3; ++ks) {
            int off = 32 * ks + 8 * lq;
            if (off >= HDIM) off = 0;     // dummy: multiplied by zeroed K pad
            qf[ks] = *(const bf16x8*)&qrow[off];
        }
    }

    float m_i[4], l_i[4];
    f32x4 o[5];
    #pragma unroll
    for (int r = 0; r < 4; ++r) { m_i[r] = -1e30f; l_i[r] = 0.0f; }
    #pragma unroll
    for (int n = 0; n < 5; ++n) o[n] = (f32x4)0.0f;

    const int w_lo   = i0 - (WINDOW - 1);
    const int w_tile = (w_lo <= 0) ? 0 : (w_lo & ~(BK - 1));
    const int lastt  = (i0 + BQG - 1) & ~(BK - 1);
    const int n_win  = (lastt - w_tile) / BK + 1;
    const bool has_sink = (w_tile > 0);   // sinks disjoint from window

    // ---- prologue: stage tile 0 + sink K/V, one barrier ----
    bf16x8 krg[3], vrg[3];
    #pragma unroll
    for (int i = 0; i < 3; ++i) {
        if (act[i]) {
            krg[i] = *(const bf16x8*)&kbase[(size_t)w_tile * (NKV * HDIM) + koff[i]];
            vrg[i] = *(const bf16x8*)&vbase[(size_t)w_tile + voff[i]];
        }
    }
    if (has_sink) {
        if (tid < 160) {                 // Ksk: 16 rows x 10 chunks
            int r = tid / 10, c8 = tid % 10;
            *(bf16x8*)&Ksk[r][8 * c8] =
                *(const bf16x8*)&kbase[(size_t)r * (NKV * HDIM) + 8 * c8];
        } else if (tid < 192) {          // Ksk pad cols 80..95
            int r = (tid - 160) >> 1, c = HDIM + 8 * (tid & 1);
            *(float4*)&Ksk[r][c] = make_float4(0.f, 0.f, 0.f, 0.f);
        } else if (tid < 512) {          // Vtk: 80 rows x 4 chunks
            int c = tid - 192;           // 0..319
            *(bf16x8*)&Vtk[c >> 2][8 * (c & 3)] =
                *(const bf16x8*)&vbase[(size_t)(c >> 2) * SEQ + 8 * (c & 3)];
        }
    }
    #pragma unroll
    for (int i = 0; i < 3; ++i) {
        if (act[i]) {
            *(bf16x8*)ksdst0[i] = krg[i];
            *(bf16x8*)vsdst0[i] = vrg[i];
        }
    }
    __syncthreads();

    // ---- sink prepass: 3 MFMA (S) + 5 MFMA (PV) ----
    if (has_sink) {
        f32x4 sk = (f32x4)0.0f;
        #pragma unroll
        for (int ks = 0; ks < 3; ++ks) {
            bf16x8 kf = *(const bf16x8*)&Ksk[l15][32 * ks + 8 * lq];
            sk = __builtin_amdgcn_mfma_f32_16x16x32_bf16(qf[ks], kf, sk, 0, 0, 0);
        }
        if (l15 >= SINK) {
            #pragma unroll
            for (int r = 0; r < 4; ++r) sk[r] = -1e30f;
        }
        #pragma unroll
        for (int r = 0; r < 4; ++r) {
            float rmax = sk[r];
            rmax = fmaxf(rmax, __shfl_xor(rmax, 1));
            rmax = fmaxf(rmax, __shfl_xor(rmax, 2));
            rmax = fmaxf(rmax, __shfl_xor(rmax, 4));
            rmax = fmaxf(rmax, __shfl_xor(rmax, 8));
            m_i[r] = rmax;
            float pe = fexp2(sk[r] - rmax);
            Pl[16 * w + 4 * lq + r][l15]      = (__bf16)pe;
            Pl[16 * w + 4 * lq + r][16 + l15] = (__bf16)0.0f;
            float rsum = pe;
            rsum += __shfl_xor(rsum, 1);
            rsum += __shfl_xor(rsum, 2);
            rsum += __shfl_xor(rsum, 4);
            rsum += __shfl_xor(rsum, 8);
            l_i[r] = rsum;
        }
        #pragma unroll
        for (int n = 0; n < 5; ++n) {
            bf16x8 pf = *(const bf16x8*)&Pl[16 * w + l15][8 * lq];
            bf16x8 vf = *(const bf16x8*)&Vtk[16 * n + l15][8 * lq];
            o[n] = __builtin_amdgcn_mfma_f32_16x16x32_bf16(pf, vf, o[n], 0, 0, 0);
        }
    }

    // ---- main loop: window tiles only, 1 barrier/tile ----
    for (int t = 0; t < n_win; ++t) {
        const int cur = t & 1;
        const int j0 = w_tile + t * BK;
        const bool more = (t + 1 < n_win);

        if (more) {
            const int j1 = j0 + BK;
            #pragma unroll
            for (int i = 0; i < 3; ++i) {
                if (act[i]) {
                    krg[i] = *(const bf16x8*)&kbase[(size_t)j1 * (NKV * HDIM) + koff[i]];
                    vrg[i] = *(const bf16x8*)&vbase[(size_t)j1 + voff[i]];
                }
            }
        }

        // ---- S = Q K^T : 24 MFMA per wave ----
        f32x4 sacc[8];
        #pragma unroll
        for (int n = 0; n < 8; ++n) sacc[n] = (f32x4)0.0f;
        __builtin_amdgcn_s_setprio(1);
        #pragma unroll
        for (int ks = 0; ks < 3; ++ks) {
            #pragma unroll
            for (int n = 0; n < 8; ++n) {
                bf16x8 kf = *(const bf16x8*)&Ks[cur][n * 16 + l15][32 * ks + 8 * lq];
                sacc[n] = __builtin_amdgcn_mfma_f32_16x16x32_bf16(qf[ks], kf, sacc[n], 0, 0, 0);
            }
        }
        __builtin_amdgcn_s_setprio(0);

        // ---- mask ----
        const bool full = (j0 >= i0 - 480) && (j0 <= i0 - 128);
        if (!full) {
            #pragma unroll
            for (int n = 0; n < 8; ++n) {
                int j = j0 + 16 * n + l15;
                #pragma unroll
                for (int r = 0; r < 4; ++r) {
                    int i = i0 + 16 * wsub + 4 * lq + r;
                    bool allowed = (j <= i) && ((j >= i - (WINDOW - 1)) || (j < SINK));
                    if (!allowed) sacc[n][r] = -1e30f;
                }
            }
        }

        // ---- online softmax (exp2 domain, exact skip-rescale) ----
        #pragma unroll
        for (int r = 0; r < 4; ++r) {
            float rmax = sacc[0][r];
            #pragma unroll
            for (int n = 1; n < 8; ++n) rmax = fmaxf(rmax, sacc[n][r]);
            rmax = fmaxf(rmax, __shfl_xor(rmax, 1));
            rmax = fmaxf(rmax, __shfl_xor(rmax, 2));
            rmax = fmaxf(rmax, __shfl_xor(rmax, 4));
            rmax = fmaxf(rmax, __shfl_xor(rmax, 8));
            if (rmax > m_i[r]) {
                float alpha = fexp2(m_i[r] - rmax);
                m_i[r] = rmax;
                l_i[r] *= alpha;
                #pragma unroll
                for (int n = 0; n < 5; ++n) o[n][r] *= alpha;
            }
            float rsum = 0.0f;
            #pragma unroll
            for (int n = 0; n < 8; ++n) {
                float pe = fexp2(sacc[n][r] - m_i[r]);
                Pl[16 * w + 4 * lq + r][16 * n + l15] = (__bf16)pe;
                rsum += pe;
            }
            rsum += __shfl_xor(rsum, 1);
            rsum += __shfl_xor(rsum, 2);
            rsum += __shfl_xor(rsum, 4);
            rsum += __shfl_xor(rsum, 8);
            l_i[r] += rsum;
        }

        // ---- O += P V : 20 MFMA per wave ----
        __builtin_amdgcn_s_setprio(1);
        #pragma unroll
        for (int ks = 0; ks < 4; ++ks) {
            bf16x8 pf = *(const bf16x8*)&Pl[16 * w + l15][32 * ks + 8 * lq];
            #pragma unroll
            for (int n = 0; n < 5; ++n) {
                bf16x8 vf = *(const bf16x8*)&Vt[cur][16 * n + l15][32 * ks + 8 * lq];
                o[n] = __builtin_amdgcn_mfma_f32_16x16x32_bf16(pf, vf, o[n], 0, 0, 0);
            }
        }
        __builtin_amdgcn_s_setprio(0);

        // ---- write next tile into the other buffer, then one barrier ----
        if (more) {
            #pragma unroll
            for (int i = 0; i < 3; ++i) {
                if (act[i]) {
                    *(bf16x8*)(ksdst0[i] + (cur ^ 1) * ksbuf) = krg[i];
                    *(bf16x8*)(vsdst0[i] + (cur ^ 1) * vsbuf) = vrg[i];
                }
            }
            __syncthreads();
        }
    }

    // ---- epilogue ----
    #pragma unroll
    for (int r = 0; r < 4; ++r) {
        float inv = 1.0f / l_i[r];
        int row = i0 + 16 * wsub + 4 * lq + r;
        #pragma unroll
        for (int n = 0; n < 5; ++n)
            attnb[(size_t)row * HIDDEN + h * HDIM + 16 * n + l15] = (__bf16)(o[n][r] * inv);
    }
}

// ---------------------------------------------------------------------------
extern "C" void kernel_launch(void* const* d_in, const int* in_sizes, int n_in,
                              void* d_out, int out_size, void* d_ws, size_t ws_size,
                              hipStream_t stream)
{
    const float* x    = (const float*)d_in[0];
    const float* cosb = (const float*)d_in[1];
    const float* sinb = (const float*)d_in[2];
    const float* Wq   = (const float*)d_in[3];
    const float* Wk   = (const float*)d_in[4];
    const float* Wv   = (const float*)d_in[5];
    const float* Wo   = (const float*)d_in[6];
    const float* qw   = (const float*)d_in[7];
    const float* kw   = (const float*)d_in[8];
    float* out = (float*)d_out;

    char* ws = (char*)d_ws;
    __bf16* qkvb  = (__bf16*)ws;                                 // [4096][960]
    __bf16* xb    = qkvb + (size_t)SEQ * 960;                    // [4096][640] = attnb
    __bf16* qb    = xb   + (size_t)SEQ * HIDDEN;                 // [4096][640]
    __bf16* kb    = qb   + (size_t)SEQ * HIDDEN;                 // [4096][160]
    __bf16* vtb   = kb   + (size_t)SEQ * 160;                    // [2][80][4096]
    __bf16* WqkvT = vtb  + (size_t)2 * HDIM * SEQ;               // [1024][640]
    __bf16* WoT   = WqkvT + (size_t)1024 * HIDDEN;               // [640][640]

    prep_kernel<<<dim3(3560), dim3(256), 0, stream>>>(
        x, Wq, Wk, Wv, Wo, xb, WqkvT, WoT);

    gemm_bf16_mfma<__bf16><<<dim3(8, SEQ / 128), dim3(512), 0, stream>>>(
        xb, WqkvT, qkvb, SEQ, 960, HIDDEN, 960);

    normrope_vt_kernel<<<dim3(2688), dim3(256), 0, stream>>>(
        (const unsigned short*)qkvb, cosb, sinb, qw, kw, qb, kb,
        (unsigned short*)vtb);

    flash_attn_mfma<<<dim3(SEQ / BQG, NKV), dim3(512), 0, stream>>>(
        qb, kb, vtb, xb);

    gemm_bf16_mfma<float><<<dim3(HIDDEN / 128, SEQ / 128), dim3(512), 0, stream>>>(
        xb, WoT, out, SEQ, HIDDEN, HIDDEN, HIDDEN);
}

// Round 16
// 72.067 us; speedup vs baseline: 1.0408x; 1.0408x over previous
//
#include <hip/hip_runtime.h>
#include <hip/hip_bf16.h>
#include <stdint.h>

#define SEQ     4096
#define HIDDEN  640
#define HDIM    80
#define NH      8
#define NKV     2
#define WINDOW  512
#define SINK    4
#define BQG     32    // flash q-tile (shared by 4 heads)
#define BK      128   // flash key-tile
#define KSTR    104   // Ks row stride (bf16): 2-way banks on b128 reads
#define VSTR    136   // Vt/Pl row stride (bf16): 2-way banks (128+8)
#define VSTRK   40    // Vtk sink row stride

typedef __bf16 bf16x8 __attribute__((ext_vector_type(8)));
typedef float  f32x4  __attribute__((ext_vector_type(4)));

__device__ inline __bf16 f2bf(float f) {
    union { float f; uint32_t u; } x; x.f = f;
    uint32_t r = x.u + 0x7FFF + ((x.u >> 16) & 1);   // RNE, no NaN inputs
    union { unsigned short s; __bf16 b; } y; y.s = (unsigned short)(r >> 16);
    return y.b;
}
__device__ inline float bf2f(unsigned short u) {
    union { uint32_t u; float f; } c; c.u = ((uint32_t)u) << 16; return c.f;
}
__device__ inline float fexp2(float x) {
#if __has_builtin(__builtin_amdgcn_exp2f)
    return __builtin_amdgcn_exp2f(x);
#else
    return exp2f(x);
#endif
}

// ---------------------------------------------------------------------------
// Fused prep: x -> bf16 (blocks [0,2560)) + all weight transposes
// (blocks [2560,3560), 32x32 tiles).  (r12-proven)
// ---------------------------------------------------------------------------
__global__ __launch_bounds__(256) void prep_kernel(
    const float* __restrict__ x, const float* __restrict__ Wq,
    const float* __restrict__ Wk, const float* __restrict__ Wv,
    const float* __restrict__ Wo, __bf16* __restrict__ xb,
    __bf16* __restrict__ WqkvT, __bf16* __restrict__ WoT)
{
    const int flat = blockIdx.x;
    const int tid  = threadIdx.x;
    if (flat < 2560) {
        int i = flat * 256 + tid;
        const float4 v = *(const float4*)&x[4 * i];
        xb[4 * i + 0] = f2bf(v.x);
        xb[4 * i + 1] = f2bf(v.y);
        xb[4 * i + 2] = f2bf(v.z);
        xb[4 * i + 3] = f2bf(v.w);
        return;
    }
    const int wf = flat - 2560;
    const float* src;
    __bf16* dstb;
    int idx, tiles_x, N;
    if (wf < 400)      { src = Wq; dstb = WqkvT;             idx = wf;       tiles_x = 20; N = 640; }
    else if (wf < 500) { src = Wk; dstb = WqkvT + 640 * 640; idx = wf - 400; tiles_x = 5;  N = 160; }
    else if (wf < 600) { src = Wv; dstb = WqkvT + 800 * 640; idx = wf - 500; tiles_x = 5;  N = 160; }
    else               { src = Wo; dstb = WoT;               idx = wf - 600; tiles_x = 20; N = 640; }
    const int n0 = (idx % tiles_x) * 32;
    const int k0 = (idx / tiles_x) * 32;

    __shared__ float t[32][33];
    const int tx = tid & 31, ty = tid >> 5;     // 32 x 8
    #pragma unroll
    for (int i = 0; i < 4; ++i) {
        int r = ty + 8 * i;
        t[r][tx] = src[(size_t)(k0 + r) * N + n0 + tx];
    }
    __syncthreads();
    #pragma unroll
    for (int i = 0; i < 4; ++i) {
        int r = ty + 8 * i;
        dstb[(size_t)(n0 + r) * 640 + k0 + tx] = f2bf(t[tx][r]);
    }
}

// ---------------------------------------------------------------------------
// MFMA bf16 GEMM (r12/r14-proven): 512 threads = 8 waves (2M x 4N), tile
// 128x128, macro-step BK=64 (two 32-wide sub-tiles in separate LDS arrays),
// dbuf LDS, single-step-ahead reg prefetch, 1 barrier per macro-step.
// ---------------------------------------------------------------------------
template <typename OutT>
__global__ __launch_bounds__(512) void gemm_bf16_mfma(
    const __bf16* __restrict__ A, const __bf16* __restrict__ BT,
    OutT* __restrict__ C, int M, int N, int K, int ldc)
{
    __shared__ __bf16 As[2][2][128][40];   // [h][buf]
    __shared__ __bf16 Bs[2][2][128][40];
    const int BUFE = 128 * 40;

    const int tid  = threadIdx.x;
    const int wave = tid >> 6;
    const int lane = tid & 63;
    const int wr = wave >> 2, wc = wave & 3;
    const int l15 = lane & 15, lq = lane >> 4;
    const int m0 = blockIdx.y * 128, n0 = blockIdx.x * 128;

    f32x4 acc[4][2];
    #pragma unroll
    for (int m = 0; m < 4; ++m)
        #pragma unroll
        for (int n = 0; n < 2; ++n) acc[m][n] = (f32x4)0.0f;

    const int sArr  = tid >> 8;          // 0: stage A, 1: stage B
    const int sc    = tid & 255;
    const int srow  = sc >> 1;           // 0..127
    const int shalf = sc & 1;
    const __bf16* gsrc = sArr ? BT : A;
    const int     grow = sArr ? n0 : m0;
    const size_t  gb   = (size_t)(grow + srow) * K + 16 * shalf;
    __bf16* ld0 = (sArr ? &Bs[0][0][0][0] : &As[0][0][0][0]) + srow * 40 + 16 * shalf;
    __bf16* ld1 = (sArr ? &Bs[1][0][0][0] : &As[1][0][0][0]) + srow * 40 + 16 * shalf;

    const int nk = K >> 6;               // macro-steps of 64

    // prologue: macro-step 0 into buffer 0
    bf16x8 r00 = *(const bf16x8*)&gsrc[gb];
    bf16x8 r01 = *(const bf16x8*)&gsrc[gb + 8];
    bf16x8 r10 = *(const bf16x8*)&gsrc[gb + 32];
    bf16x8 r11 = *(const bf16x8*)&gsrc[gb + 40];
    *(bf16x8*)ld0       = r00;
    *(bf16x8*)(ld0 + 8) = r01;
    *(bf16x8*)ld1       = r10;
    *(bf16x8*)(ld1 + 8) = r11;
    __syncthreads();

    for (int ks = 0; ks < nk; ++ks) {
        const int cur = ks & 1;
        if (ks + 1 < nk) {
            const size_t gg = gb + (size_t)(ks + 1) * 64;
            r00 = *(const bf16x8*)&gsrc[gg];
            r01 = *(const bf16x8*)&gsrc[gg + 8];
            r10 = *(const bf16x8*)&gsrc[gg + 32];
            r11 = *(const bf16x8*)&gsrc[gg + 40];
        }

        __builtin_amdgcn_s_setprio(1);
        #pragma unroll
        for (int h = 0; h < 2; ++h) {
            bf16x8 af[4], bfr[2];
            #pragma unroll
            for (int m = 0; m < 4; ++m)
                af[m] = *(const bf16x8*)&As[h][cur][wr * 64 + m * 16 + l15][8 * lq];
            #pragma unroll
            for (int n = 0; n < 2; ++n)
                bfr[n] = *(const bf16x8*)&Bs[h][cur][wc * 32 + n * 16 + l15][8 * lq];
            #pragma unroll
            for (int m = 0; m < 4; ++m)
                #pragma unroll
                for (int n = 0; n < 2; ++n)
                    acc[m][n] = __builtin_amdgcn_mfma_f32_16x16x32_bf16(af[m], bfr[n], acc[m][n], 0, 0, 0);
        }
        __builtin_amdgcn_s_setprio(0);

        if (ks + 1 < nk) {
            const int nb = (cur ^ 1) * BUFE;
            *(bf16x8*)(ld0 + nb)     = r00;
            *(bf16x8*)(ld0 + nb + 8) = r01;
            *(bf16x8*)(ld1 + nb)     = r10;
            *(bf16x8*)(ld1 + nb + 8) = r11;
        }
        __syncthreads();
    }

    #pragma unroll
    for (int m = 0; m < 4; ++m) {
        #pragma unroll
        for (int n = 0; n < 2; ++n) {
            const int col = n0 + wc * 32 + n * 16 + l15;
            if (col < N) {
                const int rbase = m0 + wr * 64 + m * 16 + 4 * lq;
                #pragma unroll
                for (int r = 0; r < 4; ++r) {
                    if constexpr (sizeof(OutT) == 2)
                        C[(size_t)(rbase + r) * ldc + col] = f2bf(acc[m][n][r]);
                    else
                        C[(size_t)(rbase + r) * ldc + col] = acc[m][n][r];
                }
            }
        }
    }
}

// ---------------------------------------------------------------------------
// Fused RMSNorm+RoPE (blocks [0,2048): 2 rows each) and V-transpose
// (blocks [2048,2688): 32x32 tiles). 256 threads. (r12-proven)
// ---------------------------------------------------------------------------
__global__ __launch_bounds__(256) void normrope_vt_kernel(
    const unsigned short* __restrict__ qkvb, const float* __restrict__ cosb,
    const float* __restrict__ sinb, const float* __restrict__ qw,
    const float* __restrict__ kw, __bf16* __restrict__ qb,
    __bf16* __restrict__ kb, unsigned short* __restrict__ vtb)
{
    const int flat = blockIdx.x;
    const int tid  = threadIdx.x;

    __shared__ float red[4];
    __shared__ unsigned short t[32][33];

    if (flat < 2048) {
        const int half = tid >> 7;           // 0..1 -> row pair
        const int lt   = tid & 127;
        const int row  = flat * 2 + half;

        float c = 0.f, s = 0.f, wqv = 0.f, wkv = 0.f;
        if (lt < HDIM) {
            c   = cosb[(size_t)row * (HDIM / 2) + (lt >> 1)];
            s   = sinb[(size_t)row * (HDIM / 2) + (lt >> 1)];
            wqv = qw[lt];
            wkv = kw[lt];
        }
        const float sgn = (lt & 1) ? 1.0f : -1.0f;
        const float QSCALE = 0.11180339887498948f * 1.4426950408889634f;

        for (int hh = 0; hh < 10; ++hh) {
            const unsigned short* p = (hh < NH)
                ? qkvb + (size_t)row * 960 + hh * HDIM
                : qkvb + (size_t)row * 960 + HIDDEN + (hh - NH) * HDIM;
            float v = (lt < HDIM) ? bf2f(p[lt]) : 0.0f;
            float sq = v * v;
            #pragma unroll
            for (int off = 32; off; off >>= 1) sq += __shfl_down(sq, off);
            if ((lt & 63) == 0) red[half * 2 + (lt >> 6)] = sq;
            __syncthreads();
            float rms = rsqrtf((red[half * 2] + red[half * 2 + 1]) * (1.0f / HDIM) + 1e-5f);

            float w  = (hh < NH) ? wqv : wkv;
            float vn = v * rms * w;
            float vp = __shfl_xor(vn, 1);
            float o  = vn * c + sgn * vp * s;

            if (lt < HDIM) {
                if (hh < NH) qb[(size_t)row * HIDDEN + hh * HDIM + lt] = (__bf16)(o * QSCALE);
                else         kb[(size_t)row * (NKV * HDIM) + (hh - NH) * HDIM + lt] = (__bf16)o;
            }
            __syncthreads();
        }
        return;
    }

    // ---- V transpose: vtb[kvh][d][seq] ----
    const int idx = flat - 2048;             // 0..639
    const int s0 = (idx & 127) * 32;
    const int c0 = (idx >> 7) * 32;
    const int tx = tid & 31, ty = tid >> 5;  // 32 x 8
    #pragma unroll
    for (int i = 0; i < 4; ++i)
        t[ty + 8 * i][tx] = qkvb[(size_t)(s0 + ty + 8 * i) * 960 + 800 + c0 + tx];
    __syncthreads();
    #pragma unroll
    for (int i = 0; i < 4; ++i) {
        int g = c0 + ty + 8 * i;             // 0..159
        int kvh = g / HDIM, d = g % HDIM;
        vtb[((size_t)kvh * HDIM + d) * SEQ + s0 + tx] = t[tx][ty + 8 * i];
    }
}

// ---------------------------------------------------------------------------
// GQA-fused MFMA flash attention (r14 + ones-column l-sum): BK=128, K/V
// double-buffered (1 barrier/tile) + sink prepass. Vt extended to 96 rows:
// row 80 = ones, 81..95 = zero -> PV n=5 block accumulates the P row-sum
// into o[5] (col l15=0), replacing the per-tile shfl-add reduce.
// Block = (32-query tile, kvh), 512 threads = 8 waves. LDS ~147 KB.
// Per tile: [load t+1 regs] S -> softmax(max only) -> PV(6 blocks) ->
//           write t+1 -> barrier.
// ---------------------------------------------------------------------------
__global__ __launch_bounds__(512) void flash_attn_mfma(
    const __bf16* __restrict__ qb, const __bf16* __restrict__ kb,
    const __bf16* __restrict__ vtb, __bf16* __restrict__ attnb)
{
    const int i0   = blockIdx.x * BQG;
    const int kvh  = blockIdx.y;
    const int tid  = threadIdx.x;        // 0..511
    const int w    = tid >> 6;           // 0..7
    const int h    = kvh * 4 + (w >> 1);
    const int wsub = w & 1;
    const int lane = tid & 63;
    const int l15  = lane & 15;
    const int lq   = lane >> 4;

    __shared__ __bf16 Ks[2][BK][KSTR];   // 53248 B
    __shared__ __bf16 Vt[2][96][VSTR];   // 52224 B (rows 80..95: ones/zeros)
    __shared__ __bf16 Pl[128][VSTR];     // 34816 B
    __shared__ __bf16 Ksk[16][KSTR];     //  3328 B (sink K, keys 0..15)
    __shared__ __bf16 Vtk[HDIM][VSTRK];  //  6400 B (sink V, keys 0..31)
    // total 150016 B

    // zero K pad columns 80..95 of BOTH buffers
    {
        int b = tid >> 8, r = (tid >> 1) & 127, c = HDIM + 8 * (tid & 1);
        *(float4*)&Ks[b][r][c] = make_float4(0.f, 0.f, 0.f, 0.f);
    }
    // Vt rows 80..95: row 80 = 1.0 (l-accumulator), 81..95 = 0.0
    for (int i = tid; i < 2 * 16 * VSTR; i += 512) {
        int b = i / (16 * VSTR), rem = i % (16 * VSTR);
        int r = rem / VSTR, c = rem % VSTR;
        Vt[b][80 + r][c] = (r == 0) ? (__bf16)1.0f : (__bf16)0.0f;
    }

    // window staging maps: 1280 chunks of 8 bf16 each (chunk = tid + 512*i)
    int koff[3], voff[3];
    __bf16* ksdst0[3];
    __bf16* vsdst0[3];
    bool act[3];
    #pragma unroll
    for (int i = 0; i < 3; ++i) {
        int c = tid + 512 * i;
        act[i] = (c < 1280);
        int cc = act[i] ? c : 0;
        koff[i] = (cc / 10) * (NKV * HDIM) + 8 * (cc % 10);
        voff[i] = (cc >> 4) * SEQ + 8 * (cc & 15);
        ksdst0[i] = &Ks[0][cc / 10][8 * (cc % 10)];
        vsdst0[i] = &Vt[0][cc >> 4][8 * (cc & 15)];
    }
    const size_t ksbuf = (size_t)BK * KSTR;
    const size_t vsbuf = (size_t)96 * VSTR;
    const __bf16* kbase = kb + kvh * HDIM;
    const __bf16* vbase = vtb + (size_t)kvh * HDIM * SEQ;

    // preload Q A-fragments
    bf16x8 qf[3];
    {
        const __bf16* qrow = qb + (size_t)(i0 + 16 * wsub + l15) * HIDDEN + h * HDIM;
        #pragma unroll
        for (int ks = 0; ks < 3; ++ks) {
            int off = 32 * ks + 8 * lq;
            if (off >= HDIM) off = 0;     // dummy: multiplied by zeroed K pad
            qf[ks] = *(const bf16x8*)&qrow[off];
        }
    }

    float m_i[4], l_i[4];
    f32x4 o[6];                           // o[5] = P row-sum accumulator
    #pragma unroll
    for (int r = 0; r < 4; ++r) { m_i[r] = -1e30f; l_i[r] = 0.0f; }
    #pragma unroll
    for (int n = 0; n < 6; ++n) o[n] = (f32x4)0.0f;

    const int w_lo   = i0 - (WINDOW - 1);
    const int w_tile = (w_lo <= 0) ? 0 : (w_lo & ~(BK - 1));
    const int lastt  = (i0 + BQG - 1) & ~(BK - 1);
    const int n_win  = (lastt - w_tile) / BK + 1;
    const bool has_sink = (w_tile > 0);   // sinks disjoint from window

    // ---- prologue: stage tile 0 + sink K/V, one barrier ----
    bf16x8 krg[3], vrg[3];
    #pragma unroll
    for (int i = 0; i < 3; ++i) {
        if (act[i]) {
            krg[i] = *(const bf16x8*)&kbase[(size_t)w_tile * (NKV * HDIM) + koff[i]];
            vrg[i] = *(const bf16x8*)&vbase[(size_t)w_tile + voff[i]];
        }
    }
    if (has_sink) {
        if (tid < 160) {                 // Ksk: 16 rows x 10 chunks
            int r = tid / 10, c8 = tid % 10;
            *(bf16x8*)&Ksk[r][8 * c8] =
                *(const bf16x8*)&kbase[(size_t)r * (NKV * HDIM) + 8 * c8];
        } else if (tid < 192) {          // Ksk pad cols 80..95
            int r = (tid - 160) >> 1, c = HDIM + 8 * (tid & 1);
            *(float4*)&Ksk[r][c] = make_float4(0.f, 0.f, 0.f, 0.f);
        } else if (tid < 512) {          // Vtk: 80 rows x 4 chunks
            int c = tid - 192;           // 0..319
            *(bf16x8*)&Vtk[c >> 2][8 * (c & 3)] =
                *(const bf16x8*)&vbase[(size_t)(c >> 2) * SEQ + 8 * (c & 3)];
        }
    }
    #pragma unroll
    for (int i = 0; i < 3; ++i) {
        if (act[i]) {
            *(bf16x8*)ksdst0[i] = krg[i];
            *(bf16x8*)vsdst0[i] = vrg[i];
        }
    }
    __syncthreads();

    // ---- sink prepass: 3 MFMA (S) + 5 MFMA (PV), shfl-based l init ----
    if (has_sink) {
        f32x4 sk = (f32x4)0.0f;
        #pragma unroll
        for (int ks = 0; ks < 3; ++ks) {
            bf16x8 kf = *(const bf16x8*)&Ksk[l15][32 * ks + 8 * lq];
            sk = __builtin_amdgcn_mfma_f32_16x16x32_bf16(qf[ks], kf, sk, 0, 0, 0);
        }
        if (l15 >= SINK) {
            #pragma unroll
            for (int r = 0; r < 4; ++r) sk[r] = -1e30f;
        }
        #pragma unroll
        for (int r = 0; r < 4; ++r) {
            float rmax = sk[r];
            rmax = fmaxf(rmax, __shfl_xor(rmax, 1));
            rmax = fmaxf(rmax, __shfl_xor(rmax, 2));
            rmax = fmaxf(rmax, __shfl_xor(rmax, 4));
            rmax = fmaxf(rmax, __shfl_xor(rmax, 8));
            m_i[r] = rmax;
            float pe = fexp2(sk[r] - rmax);
            Pl[16 * w + 4 * lq + r][l15]      = (__bf16)pe;
            Pl[16 * w + 4 * lq + r][16 + l15] = (__bf16)0.0f;
            float rsum = pe;
            rsum += __shfl_xor(rsum, 1);
            rsum += __shfl_xor(rsum, 2);
            rsum += __shfl_xor(rsum, 4);
            rsum += __shfl_xor(rsum, 8);
            l_i[r] = rsum;
        }
        #pragma unroll
        for (int n = 0; n < 5; ++n) {
            bf16x8 pf = *(const bf16x8*)&Pl[16 * w + l15][8 * lq];
            bf16x8 vf = *(const bf16x8*)&Vtk[16 * n + l15][8 * lq];
            o[n] = __builtin_amdgcn_mfma_f32_16x16x32_bf16(pf, vf, o[n], 0, 0, 0);
        }
    }

    // ---- main loop: window tiles only, 1 barrier/tile ----
    for (int t = 0; t < n_win; ++t) {
        const int cur = t & 1;
        const int j0 = w_tile + t * BK;
        const bool more = (t + 1 < n_win);

        if (more) {
            const int j1 = j0 + BK;
            #pragma unroll
            for (int i = 0; i < 3; ++i) {
                if (act[i]) {
                    krg[i] = *(const bf16x8*)&kbase[(size_t)j1 * (NKV * HDIM) + koff[i]];
                    vrg[i] = *(const bf16x8*)&vbase[(size_t)j1 + voff[i]];
                }
            }
        }

        // ---- S = Q K^T : 24 MFMA per wave ----
        f32x4 sacc[8];
        #pragma unroll
        for (int n = 0; n < 8; ++n) sacc[n] = (f32x4)0.0f;
        __builtin_amdgcn_s_setprio(1);
        #pragma unroll
        for (int ks = 0; ks < 3; ++ks) {
            #pragma unroll
            for (int n = 0; n < 8; ++n) {
                bf16x8 kf = *(const bf16x8*)&Ks[cur][n * 16 + l15][32 * ks + 8 * lq];
                sacc[n] = __builtin_amdgcn_mfma_f32_16x16x32_bf16(qf[ks], kf, sacc[n], 0, 0, 0);
            }
        }
        __builtin_amdgcn_s_setprio(0);

        // ---- mask ----
        const bool full = (j0 >= i0 - 480) && (j0 <= i0 - 128);
        if (!full) {
            #pragma unroll
            for (int n = 0; n < 8; ++n) {
                int j = j0 + 16 * n + l15;
                #pragma unroll
                for (int r = 0; r < 4; ++r) {
                    int i = i0 + 16 * wsub + 4 * lq + r;
                    bool allowed = (j <= i) && ((j >= i - (WINDOW - 1)) || (j < SINK));
                    if (!allowed) sacc[n][r] = -1e30f;
                }
            }
        }

        // ---- online softmax: max-reduce + exp only (sum via PV ones-col) ----
        #pragma unroll
        for (int r = 0; r < 4; ++r) {
            float rmax = sacc[0][r];
            #pragma unroll
            for (int n = 1; n < 8; ++n) rmax = fmaxf(rmax, sacc[n][r]);
            rmax = fmaxf(rmax, __shfl_xor(rmax, 1));
            rmax = fmaxf(rmax, __shfl_xor(rmax, 2));
            rmax = fmaxf(rmax, __shfl_xor(rmax, 4));
            rmax = fmaxf(rmax, __shfl_xor(rmax, 8));
            if (rmax > m_i[r]) {
                float alpha = fexp2(m_i[r] - rmax);
                m_i[r] = rmax;
                l_i[r] *= alpha;
                #pragma unroll
                for (int n = 0; n < 6; ++n) o[n][r] *= alpha;
            }
            #pragma unroll
            for (int n = 0; n < 8; ++n) {
                float pe = fexp2(sacc[n][r] - m_i[r]);
                Pl[16 * w + 4 * lq + r][16 * n + l15] = (__bf16)pe;
            }
        }

        // ---- O += P V : 24 MFMA per wave (block 5 = l-accumulator) ----
        __builtin_amdgcn_s_setprio(1);
        #pragma unroll
        for (int ks = 0; ks < 4; ++ks) {
            bf16x8 pf = *(const bf16x8*)&Pl[16 * w + l15][32 * ks + 8 * lq];
            #pragma unroll
            for (int n = 0; n < 6; ++n) {
                bf16x8 vf = *(const bf16x8*)&Vt[cur][16 * n + l15][32 * ks + 8 * lq];
                o[n] = __builtin_amdgcn_mfma_f32_16x16x32_bf16(pf, vf, o[n], 0, 0, 0);
            }
        }
        __builtin_amdgcn_s_setprio(0);

        // ---- write next tile into the other buffer, then one barrier ----
        if (more) {
            #pragma unroll
            for (int i = 0; i < 3; ++i) {
                if (act[i]) {
                    *(bf16x8*)(ksdst0[i] + (cur ^ 1) * ksbuf) = krg[i];
                    *(bf16x8*)(vsdst0[i] + (cur ^ 1) * vsbuf) = vrg[i];
                }
            }
            __syncthreads();
        }
    }

    // ---- epilogue: l = l_i(sink) + o[5]@(l15==0) ----
    #pragma unroll
    for (int r = 0; r < 4; ++r) {
        float l_pv = __shfl(o[5][r], lane & 48);   // lane with l15==0 in group
        float inv = 1.0f / (l_i[r] + l_pv);
        int row = i0 + 16 * wsub + 4 * lq + r;
        #pragma unroll
        for (int n = 0; n < 5; ++n)
            attnb[(size_t)row * HIDDEN + h * HDIM + 16 * n + l15] = (__bf16)(o[n][r] * inv);
    }
}

// ---------------------------------------------------------------------------
extern "C" void kernel_launch(void* const* d_in, const int* in_sizes, int n_in,
                              void* d_out, int out_size, void* d_ws, size_t ws_size,
                              hipStream_t stream)
{
    const float* x    = (const float*)d_in[0];
    const float* cosb = (const float*)d_in[1];
    const float* sinb = (const float*)d_in[2];
    const float* Wq   = (const float*)d_in[3];
    const float* Wk   = (const float*)d_in[4];
    const float* Wv   = (const float*)d_in[5];
    const float* Wo   = (const float*)d_in[6];
    const float* qw   = (const float*)d_in[7];
    const float* kw   = (const float*)d_in[8];
    float* out = (float*)d_out;

    char* ws = (char*)d_ws;
    __bf16* qkvb  = (__bf16*)ws;                                 // [4096][960]
    __bf16* xb    = qkvb + (size_t)SEQ * 960;                    // [4096][640] = attnb
    __bf16* qb    = xb   + (size_t)SEQ * HIDDEN;                 // [4096][640]
    __bf16* kb    = qb   + (size_t)SEQ * HIDDEN;                 // [4096][160]
    __bf16* vtb   = kb   + (size_t)SEQ * 160;                    // [2][80][4096]
    __bf16* WqkvT = vtb  + (size_t)2 * HDIM * SEQ;               // [1024][640]
    __bf16* WoT   = WqkvT + (size_t)1024 * HIDDEN;               // [640][640]

    prep_kernel<<<dim3(3560), dim3(256), 0, stream>>>(
        x, Wq, Wk, Wv, Wo, xb, WqkvT, WoT);

    gemm_bf16_mfma<__bf16><<<dim3(8, SEQ / 128), dim3(512), 0, stream>>>(
        xb, WqkvT, qkvb, SEQ, 960, HIDDEN, 960);

    normrope_vt_kernel<<<dim3(2688), dim3(256), 0, stream>>>(
        (const unsigned short*)qkvb, cosb, sinb, qw, kw, qb, kb,
        (unsigned short*)vtb);

    flash_attn_mfma<<<dim3(SEQ / BQG, NKV), dim3(512), 0, stream>>>(
        qb, kb, vtb, xb);

    gemm_bf16_mfma<float><<<dim3(HIDDEN / 128, SEQ / 128), dim3(512), 0, stream>>>(
        xb, WoT, out, SEQ, HIDDEN, HIDDEN, HIDDEN);
}

// Round 17
// 71.469 us; speedup vs baseline: 1.0495x; 1.0084x over previous
//
#include <hip/hip_runtime.h>
#include <hip/hip_bf16.h>
#include <stdint.h>

#define SEQ     4096
#define HIDDEN  640
#define HDIM    80
#define NH      8
#define NKV     2
#define WINDOW  512
#define SINK    4
#define BQG     32    // flash q-tile (shared by 4 heads)
#define BK      128   // flash key-tile
#define KSTR    104   // Ks row stride (bf16): 2-way banks on b128 reads
#define VSTR    136   // Vt/Pl row stride (bf16): 2-way banks (128+8)
#define VSTRK   40    // Vtk sink row stride

typedef __bf16 bf16x8 __attribute__((ext_vector_type(8)));
typedef __bf16 bf16x4 __attribute__((ext_vector_type(4)));
typedef float  f32x4  __attribute__((ext_vector_type(4)));

__device__ inline __bf16 f2bf(float f) {
    union { float f; uint32_t u; } x; x.f = f;
    uint32_t r = x.u + 0x7FFF + ((x.u >> 16) & 1);   // RNE, no NaN inputs
    union { unsigned short s; __bf16 b; } y; y.s = (unsigned short)(r >> 16);
    return y.b;
}
__device__ inline float bf2f(unsigned short u) {
    union { uint32_t u; float f; } c; c.u = ((uint32_t)u) << 16; return c.f;
}
__device__ inline float fexp2(float x) {
#if __has_builtin(__builtin_amdgcn_exp2f)
    return __builtin_amdgcn_exp2f(x);
#else
    return exp2f(x);
#endif
}

// ---------------------------------------------------------------------------
// Fused prep: x -> bf16 (blocks [0,2560)) + all weight transposes
// (blocks [2560,3560), 32x32 tiles).  (r12-proven)
// ---------------------------------------------------------------------------
__global__ __launch_bounds__(256) void prep_kernel(
    const float* __restrict__ x, const float* __restrict__ Wq,
    const float* __restrict__ Wk, const float* __restrict__ Wv,
    const float* __restrict__ Wo, __bf16* __restrict__ xb,
    __bf16* __restrict__ WqkvT, __bf16* __restrict__ WoT)
{
    const int flat = blockIdx.x;
    const int tid  = threadIdx.x;
    if (flat < 2560) {
        int i = flat * 256 + tid;
        const float4 v = *(const float4*)&x[4 * i];
        xb[4 * i + 0] = f2bf(v.x);
        xb[4 * i + 1] = f2bf(v.y);
        xb[4 * i + 2] = f2bf(v.z);
        xb[4 * i + 3] = f2bf(v.w);
        return;
    }
    const int wf = flat - 2560;
    const float* src;
    __bf16* dstb;
    int idx, tiles_x, N;
    if (wf < 400)      { src = Wq; dstb = WqkvT;             idx = wf;       tiles_x = 20; N = 640; }
    else if (wf < 500) { src = Wk; dstb = WqkvT + 640 * 640; idx = wf - 400; tiles_x = 5;  N = 160; }
    else if (wf < 600) { src = Wv; dstb = WqkvT + 800 * 640; idx = wf - 500; tiles_x = 5;  N = 160; }
    else               { src = Wo; dstb = WoT;               idx = wf - 600; tiles_x = 20; N = 640; }
    const int n0 = (idx % tiles_x) * 32;
    const int k0 = (idx / tiles_x) * 32;

    __shared__ float t[32][33];
    const int tx = tid & 31, ty = tid >> 5;     // 32 x 8
    #pragma unroll
    for (int i = 0; i < 4; ++i) {
        int r = ty + 8 * i;
        t[r][tx] = src[(size_t)(k0 + r) * N + n0 + tx];
    }
    __syncthreads();
    #pragma unroll
    for (int i = 0; i < 4; ++i) {
        int r = ty + 8 * i;
        dstb[(size_t)(n0 + r) * 640 + k0 + tx] = f2bf(t[tx][r]);
    }
}

// ---------------------------------------------------------------------------
// MFMA bf16 GEMM (r12/r14-proven): 512 threads = 8 waves (2M x 4N), tile
// 128x128, macro-step BK=64 (two 32-wide sub-tiles in separate LDS arrays),
// dbuf LDS, single-step-ahead reg prefetch, 1 barrier per macro-step.
// ---------------------------------------------------------------------------
template <typename OutT>
__global__ __launch_bounds__(512) void gemm_bf16_mfma(
    const __bf16* __restrict__ A, const __bf16* __restrict__ BT,
    OutT* __restrict__ C, int M, int N, int K, int ldc)
{
    __shared__ __bf16 As[2][2][128][40];   // [h][buf]
    __shared__ __bf16 Bs[2][2][128][40];
    const int BUFE = 128 * 40;

    const int tid  = threadIdx.x;
    const int wave = tid >> 6;
    const int lane = tid & 63;
    const int wr = wave >> 2, wc = wave & 3;
    const int l15 = lane & 15, lq = lane >> 4;
    const int m0 = blockIdx.y * 128, n0 = blockIdx.x * 128;

    f32x4 acc[4][2];
    #pragma unroll
    for (int m = 0; m < 4; ++m)
        #pragma unroll
        for (int n = 0; n < 2; ++n) acc[m][n] = (f32x4)0.0f;

    const int sArr  = tid >> 8;          // 0: stage A, 1: stage B
    const int sc    = tid & 255;
    const int srow  = sc >> 1;           // 0..127
    const int shalf = sc & 1;
    const __bf16* gsrc = sArr ? BT : A;
    const int     grow = sArr ? n0 : m0;
    const size_t  gb   = (size_t)(grow + srow) * K + 16 * shalf;
    __bf16* ld0 = (sArr ? &Bs[0][0][0][0] : &As[0][0][0][0]) + srow * 40 + 16 * shalf;
    __bf16* ld1 = (sArr ? &Bs[1][0][0][0] : &As[1][0][0][0]) + srow * 40 + 16 * shalf;

    const int nk = K >> 6;               // macro-steps of 64

    // prologue: macro-step 0 into buffer 0
    bf16x8 r00 = *(const bf16x8*)&gsrc[gb];
    bf16x8 r01 = *(const bf16x8*)&gsrc[gb + 8];
    bf16x8 r10 = *(const bf16x8*)&gsrc[gb + 32];
    bf16x8 r11 = *(const bf16x8*)&gsrc[gb + 40];
    *(bf16x8*)ld0       = r00;
    *(bf16x8*)(ld0 + 8) = r01;
    *(bf16x8*)ld1       = r10;
    *(bf16x8*)(ld1 + 8) = r11;
    __syncthreads();

    for (int ks = 0; ks < nk; ++ks) {
        const int cur = ks & 1;
        if (ks + 1 < nk) {
            const size_t gg = gb + (size_t)(ks + 1) * 64;
            r00 = *(const bf16x8*)&gsrc[gg];
            r01 = *(const bf16x8*)&gsrc[gg + 8];
            r10 = *(const bf16x8*)&gsrc[gg + 32];
            r11 = *(const bf16x8*)&gsrc[gg + 40];
        }

        __builtin_amdgcn_s_setprio(1);
        #pragma unroll
        for (int h = 0; h < 2; ++h) {
            bf16x8 af[4], bfr[2];
            #pragma unroll
            for (int m = 0; m < 4; ++m)
                af[m] = *(const bf16x8*)&As[h][cur][wr * 64 + m * 16 + l15][8 * lq];
            #pragma unroll
            for (int n = 0; n < 2; ++n)
                bfr[n] = *(const bf16x8*)&Bs[h][cur][wc * 32 + n * 16 + l15][8 * lq];
            #pragma unroll
            for (int m = 0; m < 4; ++m)
                #pragma unroll
                for (int n = 0; n < 2; ++n)
                    acc[m][n] = __builtin_amdgcn_mfma_f32_16x16x32_bf16(af[m], bfr[n], acc[m][n], 0, 0, 0);
        }
        __builtin_amdgcn_s_setprio(0);

        if (ks + 1 < nk) {
            const int nb = (cur ^ 1) * BUFE;
            *(bf16x8*)(ld0 + nb)     = r00;
            *(bf16x8*)(ld0 + nb + 8) = r01;
            *(bf16x8*)(ld1 + nb)     = r10;
            *(bf16x8*)(ld1 + nb + 8) = r11;
        }
        __syncthreads();
    }

    #pragma unroll
    for (int m = 0; m < 4; ++m) {
        #pragma unroll
        for (int n = 0; n < 2; ++n) {
            const int col = n0 + wc * 32 + n * 16 + l15;
            if (col < N) {
                const int rbase = m0 + wr * 64 + m * 16 + 4 * lq;
                #pragma unroll
                for (int r = 0; r < 4; ++r) {
                    if constexpr (sizeof(OutT) == 2)
                        C[(size_t)(rbase + r) * ldc + col] = f2bf(acc[m][n][r]);
                    else
                        C[(size_t)(rbase + r) * ldc + col] = acc[m][n][r];
                }
            }
        }
    }
}

// ---------------------------------------------------------------------------
// Fused RMSNorm+RoPE (blocks [0,2048): 2 rows each) and V-transpose
// (blocks [2048,2688): 32x32 tiles). 256 threads. (r12-proven)
// ---------------------------------------------------------------------------
__global__ __launch_bounds__(256) void normrope_vt_kernel(
    const unsigned short* __restrict__ qkvb, const float* __restrict__ cosb,
    const float* __restrict__ sinb, const float* __restrict__ qw,
    const float* __restrict__ kw, __bf16* __restrict__ qb,
    __bf16* __restrict__ kb, unsigned short* __restrict__ vtb)
{
    const int flat = blockIdx.x;
    const int tid  = threadIdx.x;

    __shared__ float red[4];
    __shared__ unsigned short t[32][33];

    if (flat < 2048) {
        const int half = tid >> 7;           // 0..1 -> row pair
        const int lt   = tid & 127;
        const int row  = flat * 2 + half;

        float c = 0.f, s = 0.f, wqv = 0.f, wkv = 0.f;
        if (lt < HDIM) {
            c   = cosb[(size_t)row * (HDIM / 2) + (lt >> 1)];
            s   = sinb[(size_t)row * (HDIM / 2) + (lt >> 1)];
            wqv = qw[lt];
            wkv = kw[lt];
        }
        const float sgn = (lt & 1) ? 1.0f : -1.0f;
        const float QSCALE = 0.11180339887498948f * 1.4426950408889634f;

        for (int hh = 0; hh < 10; ++hh) {
            const unsigned short* p = (hh < NH)
                ? qkvb + (size_t)row * 960 + hh * HDIM
                : qkvb + (size_t)row * 960 + HIDDEN + (hh - NH) * HDIM;
            float v = (lt < HDIM) ? bf2f(p[lt]) : 0.0f;
            float sq = v * v;
            #pragma unroll
            for (int off = 32; off; off >>= 1) sq += __shfl_down(sq, off);
            if ((lt & 63) == 0) red[half * 2 + (lt >> 6)] = sq;
            __syncthreads();
            float rms = rsqrtf((red[half * 2] + red[half * 2 + 1]) * (1.0f / HDIM) + 1e-5f);

            float w  = (hh < NH) ? wqv : wkv;
            float vn = v * rms * w;
            float vp = __shfl_xor(vn, 1);
            float o  = vn * c + sgn * vp * s;

            if (lt < HDIM) {
                if (hh < NH) qb[(size_t)row * HIDDEN + hh * HDIM + lt] = (__bf16)(o * QSCALE);
                else         kb[(size_t)row * (NKV * HDIM) + (hh - NH) * HDIM + lt] = (__bf16)o;
            }
            __syncthreads();
        }
        return;
    }

    // ---- V transpose: vtb[kvh][d][seq] ----
    const int idx = flat - 2048;             // 0..639
    const int s0 = (idx & 127) * 32;
    const int c0 = (idx >> 7) * 32;
    const int tx = tid & 31, ty = tid >> 5;  // 32 x 8
    #pragma unroll
    for (int i = 0; i < 4; ++i)
        t[ty + 8 * i][tx] = qkvb[(size_t)(s0 + ty + 8 * i) * 960 + 800 + c0 + tx];
    __syncthreads();
    #pragma unroll
    for (int i = 0; i < 4; ++i) {
        int g = c0 + ty + 8 * i;             // 0..159
        int kvh = g / HDIM, d = g % HDIM;
        vtb[((size_t)kvh * HDIM + d) * SEQ + s0 + tx] = t[tx][ty + 8 * i];
    }
}

// ---------------------------------------------------------------------------
// GQA-fused MFMA flash attention (r16 + SWAPPED S-operands):
// S = mfma(K, Q) -> lane holds one q-row (l15), keys 16n+4lq+{0..3}.
// P-writes become 8x ds_write_b64 (packed bf16x4) instead of 32x b16;
// row-max is in-lane + 2 shfl_xor; m_i/l_i are scalars. PV + ones-column
// l-sum + sink prepass + K/V double-buffer (1 barrier/tile) unchanged.
// Block = (32-query tile, kvh), 512 threads = 8 waves. LDS ~147 KB.
// ---------------------------------------------------------------------------
__global__ __launch_bounds__(512) void flash_attn_mfma(
    const __bf16* __restrict__ qb, const __bf16* __restrict__ kb,
    const __bf16* __restrict__ vtb, __bf16* __restrict__ attnb)
{
    const int i0   = blockIdx.x * BQG;
    const int kvh  = blockIdx.y;
    const int tid  = threadIdx.x;        // 0..511
    const int w    = tid >> 6;           // 0..7
    const int h    = kvh * 4 + (w >> 1);
    const int wsub = w & 1;
    const int lane = tid & 63;
    const int l15  = lane & 15;
    const int lq   = lane >> 4;

    __shared__ __bf16 Ks[2][BK][KSTR];   // 53248 B
    __shared__ __bf16 Vt[2][96][VSTR];   // 52224 B (rows 80..95: ones/zeros)
    __shared__ __bf16 Pl[128][VSTR];     // 34816 B
    __shared__ __bf16 Ksk[16][KSTR];     //  3328 B (sink K, keys 0..15)
    __shared__ __bf16 Vtk[HDIM][VSTRK];  //  6400 B (sink V, keys 0..31)

    // zero K pad columns 80..95 of BOTH buffers
    {
        int b = tid >> 8, r = (tid >> 1) & 127, c = HDIM + 8 * (tid & 1);
        *(float4*)&Ks[b][r][c] = make_float4(0.f, 0.f, 0.f, 0.f);
    }
    // Vt rows 80..95: row 80 = 1.0 (l-accumulator), 81..95 = 0.0
    for (int i = tid; i < 2 * 16 * VSTR; i += 512) {
        int b = i / (16 * VSTR), rem = i % (16 * VSTR);
        int r = rem / VSTR, c = rem % VSTR;
        Vt[b][80 + r][c] = (r == 0) ? (__bf16)1.0f : (__bf16)0.0f;
    }

    // window staging maps: 1280 chunks of 8 bf16 each (chunk = tid + 512*i)
    int koff[3], voff[3];
    __bf16* ksdst0[3];
    __bf16* vsdst0[3];
    bool act[3];
    #pragma unroll
    for (int i = 0; i < 3; ++i) {
        int c = tid + 512 * i;
        act[i] = (c < 1280);
        int cc = act[i] ? c : 0;
        koff[i] = (cc / 10) * (NKV * HDIM) + 8 * (cc % 10);
        voff[i] = (cc >> 4) * SEQ + 8 * (cc & 15);
        ksdst0[i] = &Ks[0][cc / 10][8 * (cc % 10)];
        vsdst0[i] = &Vt[0][cc >> 4][8 * (cc & 15)];
    }
    const size_t ksbuf = (size_t)BK * KSTR;
    const size_t vsbuf = (size_t)96 * VSTR;
    const __bf16* kbase = kb + kvh * HDIM;
    const __bf16* vbase = vtb + (size_t)kvh * HDIM * SEQ;

    // preload Q A-fragments (q-row i0 + 16*wsub + l15)
    bf16x8 qf[3];
    {
        const __bf16* qrow = qb + (size_t)(i0 + 16 * wsub + l15) * HIDDEN + h * HDIM;
        #pragma unroll
        for (int ks = 0; ks < 3; ++ks) {
            int off = 32 * ks + 8 * lq;
            if (off >= HDIM) off = 0;     // dummy: multiplied by zeroed K pad
            qf[ks] = *(const bf16x8*)&qrow[off];
        }
    }

    float m_i = -1e30f, l_i = 0.0f;       // per-lane: q-row i0+16*wsub+l15
    f32x4 o[6];                           // o[5] = P row-sum accumulator
    #pragma unroll
    for (int n = 0; n < 6; ++n) o[n] = (f32x4)0.0f;

    const int w_lo   = i0 - (WINDOW - 1);
    const int w_tile = (w_lo <= 0) ? 0 : (w_lo & ~(BK - 1));
    const int lastt  = (i0 + BQG - 1) & ~(BK - 1);
    const int n_win  = (lastt - w_tile) / BK + 1;
    const bool has_sink = (w_tile > 0);   // sinks disjoint from window

    // ---- prologue: stage tile 0 + sink K/V, one barrier ----
    bf16x8 krg[3], vrg[3];
    #pragma unroll
    for (int i = 0; i < 3; ++i) {
        if (act[i]) {
            krg[i] = *(const bf16x8*)&kbase[(size_t)w_tile * (NKV * HDIM) + koff[i]];
            vrg[i] = *(const bf16x8*)&vbase[(size_t)w_tile + voff[i]];
        }
    }
    if (has_sink) {
        if (tid < 160) {                 // Ksk: 16 rows x 10 chunks
            int r = tid / 10, c8 = tid % 10;
            *(bf16x8*)&Ksk[r][8 * c8] =
                *(const bf16x8*)&kbase[(size_t)r * (NKV * HDIM) + 8 * c8];
        } else if (tid < 192) {          // Ksk pad cols 80..95
            int r = (tid - 160) >> 1, c = HDIM + 8 * (tid & 1);
            *(float4*)&Ksk[r][c] = make_float4(0.f, 0.f, 0.f, 0.f);
        } else if (tid < 512) {          // Vtk: 80 rows x 4 chunks
            int c = tid - 192;           // 0..319
            *(bf16x8*)&Vtk[c >> 2][8 * (c & 3)] =
                *(const bf16x8*)&vbase[(size_t)(c >> 2) * SEQ + 8 * (c & 3)];
        }
    }
    #pragma unroll
    for (int i = 0; i < 3; ++i) {
        if (act[i]) {
            *(bf16x8*)ksdst0[i] = krg[i];
            *(bf16x8*)vsdst0[i] = vrg[i];
        }
    }
    __syncthreads();

    // ---- sink prepass (swapped): keys = 4lq+r, q-row = l15 ----
    if (has_sink) {
        f32x4 sk = (f32x4)0.0f;
        #pragma unroll
        for (int ks = 0; ks < 3; ++ks) {
            bf16x8 kf = *(const bf16x8*)&Ksk[l15][32 * ks + 8 * lq];
            sk = __builtin_amdgcn_mfma_f32_16x16x32_bf16(kf, qf[ks], sk, 0, 0, 0);
        }
        // mask keys >= SINK: key = 4lq + r, valid only lq==0 (r<4)
        if (lq != 0) {
            #pragma unroll
            for (int r = 0; r < 4; ++r) sk[r] = -1e30f;
        }
        float mx = fmaxf(fmaxf(sk[0], sk[1]), fmaxf(sk[2], sk[3]));
        mx = fmaxf(mx, __shfl_xor(mx, 16));
        mx = fmaxf(mx, __shfl_xor(mx, 32));
        m_i = mx;
        bf16x4 pk;
        float rsum = 0.0f;
        #pragma unroll
        for (int r = 0; r < 4; ++r) {
            float pe = fexp2(sk[r] - m_i);
            pk[r] = (__bf16)pe;
            rsum += pe;
        }
        *(bf16x4*)&Pl[16 * w + l15][4 * lq] = pk;
        bf16x4 zz;
        #pragma unroll
        for (int r = 0; r < 4; ++r) zz[r] = (__bf16)0.0f;
        *(bf16x4*)&Pl[16 * w + l15][16 + 4 * lq] = zz;
        rsum += __shfl_xor(rsum, 16);
        rsum += __shfl_xor(rsum, 32);
        l_i = rsum;
        #pragma unroll
        for (int n = 0; n < 5; ++n) {
            bf16x8 pf = *(const bf16x8*)&Pl[16 * w + l15][8 * lq];
            bf16x8 vf = *(const bf16x8*)&Vtk[16 * n + l15][8 * lq];
            o[n] = __builtin_amdgcn_mfma_f32_16x16x32_bf16(pf, vf, o[n], 0, 0, 0);
        }
    }

    // ---- main loop: window tiles only, 1 barrier/tile ----
    for (int t = 0; t < n_win; ++t) {
        const int cur = t & 1;
        const int j0 = w_tile + t * BK;
        const bool more = (t + 1 < n_win);

        if (more) {
            const int j1 = j0 + BK;
            #pragma unroll
            for (int i = 0; i < 3; ++i) {
                if (act[i]) {
                    krg[i] = *(const bf16x8*)&kbase[(size_t)j1 * (NKV * HDIM) + koff[i]];
                    vrg[i] = *(const bf16x8*)&vbase[(size_t)j1 + voff[i]];
                }
            }
        }

        // ---- S = K Q^T (swapped): 24 MFMA per wave ----
        f32x4 sacc[8];
        #pragma unroll
        for (int n = 0; n < 8; ++n) sacc[n] = (f32x4)0.0f;
        __builtin_amdgcn_s_setprio(1);
        #pragma unroll
        for (int ks = 0; ks < 3; ++ks) {
            #pragma unroll
            for (int n = 0; n < 8; ++n) {
                bf16x8 kf = *(const bf16x8*)&Ks[cur][n * 16 + l15][32 * ks + 8 * lq];
                sacc[n] = __builtin_amdgcn_mfma_f32_16x16x32_bf16(kf, qf[ks], sacc[n], 0, 0, 0);
            }
        }
        __builtin_amdgcn_s_setprio(0);

        // ---- mask: key j = j0+16n+4lq+r, q i = i0+16wsub+l15 ----
        const bool full = (j0 >= i0 - 480) && (j0 <= i0 - 128);
        if (!full) {
            const int i = i0 + 16 * wsub + l15;
            #pragma unroll
            for (int n = 0; n < 8; ++n) {
                #pragma unroll
                for (int r = 0; r < 4; ++r) {
                    int j = j0 + 16 * n + 4 * lq + r;
                    bool allowed = (j <= i) && ((j >= i - (WINDOW - 1)) || (j < SINK));
                    if (!allowed) sacc[n][r] = -1e30f;
                }
            }
        }

        // ---- online softmax (swapped): in-lane max + 2 shfl ----
        {
            float mx = sacc[0][0];
            #pragma unroll
            for (int n = 0; n < 8; ++n) {
                float a = fmaxf(fmaxf(sacc[n][0], sacc[n][1]),
                                fmaxf(sacc[n][2], sacc[n][3]));
                mx = (n == 0) ? a : fmaxf(mx, a);
            }
            mx = fmaxf(mx, __shfl_xor(mx, 16));
            mx = fmaxf(mx, __shfl_xor(mx, 32));

            float alpha_own = 1.0f;
            bool grow = (mx > m_i);
            if (grow) {
                alpha_own = fexp2(m_i - mx);
                m_i = mx;
                l_i *= alpha_own;
            }
            if (__any(grow)) {
                // redistribute alpha from l15-space to (4lq+r)-space
                #pragma unroll
                for (int r = 0; r < 4; ++r) {
                    float ar = __shfl(alpha_own, 4 * lq + r);
                    #pragma unroll
                    for (int n = 0; n < 6; ++n) o[n][r] *= ar;
                }
            }
            // pe + packed b64 writes (8 per lane)
            #pragma unroll
            for (int n = 0; n < 8; ++n) {
                bf16x4 pk;
                #pragma unroll
                for (int r = 0; r < 4; ++r)
                    pk[r] = (__bf16)fexp2(sacc[n][r] - m_i);
                *(bf16x4*)&Pl[16 * w + l15][16 * n + 4 * lq] = pk;
            }
        }

        // ---- O += P V : 24 MFMA per wave (block 5 = l-accumulator) ----
        __builtin_amdgcn_s_setprio(1);
        #pragma unroll
        for (int ks = 0; ks < 4; ++ks) {
            bf16x8 pf = *(const bf16x8*)&Pl[16 * w + l15][32 * ks + 8 * lq];
            #pragma unroll
            for (int n = 0; n < 6; ++n) {
                bf16x8 vf = *(const bf16x8*)&Vt[cur][16 * n + l15][32 * ks + 8 * lq];
                o[n] = __builtin_amdgcn_mfma_f32_16x16x32_bf16(pf, vf, o[n], 0, 0, 0);
            }
        }
        __builtin_amdgcn_s_setprio(0);

        // ---- write next tile into the other buffer, then one barrier ----
        if (more) {
            #pragma unroll
            for (int i = 0; i < 3; ++i) {
                if (act[i]) {
                    *(bf16x8*)(ksdst0[i] + (cur ^ 1) * ksbuf) = krg[i];
                    *(bf16x8*)(vsdst0[i] + (cur ^ 1) * vsbuf) = vrg[i];
                }
            }
            __syncthreads();
        }
    }

    // ---- epilogue: l(row 4lq+r) = shfl(l_i) + o[5]@(l15==0) ----
    #pragma unroll
    for (int r = 0; r < 4; ++r) {
        float l_snk = __shfl(l_i, 4 * lq + r);
        float l_pv  = __shfl(o[5][r], lane & 48);
        float inv = 1.0f / (l_snk + l_pv);
        int row = i0 + 16 * wsub + 4 * lq + r;
        #pragma unroll
        for (int n = 0; n < 5; ++n)
            attnb[(size_t)row * HIDDEN + h * HDIM + 16 * n + l15] = (__bf16)(o[n][r] * inv);
    }
}

// ---------------------------------------------------------------------------
extern "C" void kernel_launch(void* const* d_in, const int* in_sizes, int n_in,
                              void* d_out, int out_size, void* d_ws, size_t ws_size,
                              hipStream_t stream)
{
    const float* x    = (const float*)d_in[0];
    const float* cosb = (const float*)d_in[1];
    const float* sinb = (const float*)d_in[2];
    const float* Wq   = (const float*)d_in[3];
    const float* Wk   = (const float*)d_in[4];
    const float* Wv   = (const float*)d_in[5];
    const float* Wo   = (const float*)d_in[6];
    const float* qw   = (const float*)d_in[7];
    const float* kw   = (const float*)d_in[8];
    float* out = (float*)d_out;

    char* ws = (char*)d_ws;
    __bf16* qkvb  = (__bf16*)ws;                                 // [4096][960]
    __bf16* xb    = qkvb + (size_t)SEQ * 960;                    // [4096][640] = attnb
    __bf16* qb    = xb   + (size_t)SEQ * HIDDEN;                 // [4096][640]
    __bf16* kb    = qb   + (size_t)SEQ * HIDDEN;                 // [4096][160]
    __bf16* vtb   = kb   + (size_t)SEQ * 160;                    // [2][80][4096]
    __bf16* WqkvT = vtb  + (size_t)2 * HDIM * SEQ;               // [1024][640]
    __bf16* WoT   = WqkvT + (size_t)1024 * HIDDEN;               // [640][640]

    prep_kernel<<<dim3(3560), dim3(256), 0, stream>>>(
        x, Wq, Wk, Wv, Wo, xb, WqkvT, WoT);

    gemm_bf16_mfma<__bf16><<<dim3(8, SEQ / 128), dim3(512), 0, stream>>>(
        xb, WqkvT, qkvb, SEQ, 960, HIDDEN, 960);

    normrope_vt_kernel<<<dim3(2688), dim3(256), 0, stream>>>(
        (const unsigned short*)qkvb, cosb, sinb, qw, kw, qb, kb,
        (unsigned short*)vtb);

    flash_attn_mfma<<<dim3(SEQ / BQG, NKV), dim3(512), 0, stream>>>(
        qb, kb, vtb, xb);

    gemm_bf16_mfma<float><<<dim3(HIDDEN / 128, SEQ / 128), dim3(512), 0, stream>>>(
        xb, WoT, out, SEQ, HIDDEN, HIDDEN, HIDDEN);
}

// Round 18
// 64.691 us; speedup vs baseline: 1.1594x; 1.1048x over previous
//
#include <hip/hip_runtime.h>
#include <hip/hip_bf16.h>
#include <stdint.h>

#define SEQ     4096
#define HIDDEN  640
#define HDIM    80
#define NH      8
#define NKV     2
#define WINDOW  512
#define SINK    4
#define BQG     32    // flash q-tile (shared by 4 heads)
#define BK      128   // flash key-tile
#define KSTR    104   // Ks row stride (bf16): 2-way banks on b128 reads
#define VSTR    136   // Vt/Pl row stride (bf16): 2-way banks (128+8)
#define VSTRK   40    // Vtk sink row stride

typedef __bf16 bf16x8 __attribute__((ext_vector_type(8)));
typedef __bf16 bf16x4 __attribute__((ext_vector_type(4)));
typedef float  f32x4  __attribute__((ext_vector_type(4)));

__device__ inline __bf16 f2bf(float f) {
    union { float f; uint32_t u; } x; x.f = f;
    uint32_t r = x.u + 0x7FFF + ((x.u >> 16) & 1);   // RNE, no NaN inputs
    union { unsigned short s; __bf16 b; } y; y.s = (unsigned short)(r >> 16);
    return y.b;
}
__device__ inline float bf2f(unsigned short u) {
    union { uint32_t u; float f; } c; c.u = ((uint32_t)u) << 16; return c.f;
}
__device__ inline float fexp2(float x) {
#if __has_builtin(__builtin_amdgcn_exp2f)
    return __builtin_amdgcn_exp2f(x);
#else
    return exp2f(x);
#endif
}

// ---------------------------------------------------------------------------
// Fused prep: x -> bf16 (blocks [0,2560)) + all weight transposes
// (blocks [2560,3560), 32x32 tiles).  (r12-proven)
// ---------------------------------------------------------------------------
__global__ __launch_bounds__(256) void prep_kernel(
    const float* __restrict__ x, const float* __restrict__ Wq,
    const float* __restrict__ Wk, const float* __restrict__ Wv,
    const float* __restrict__ Wo, __bf16* __restrict__ xb,
    __bf16* __restrict__ WqkvT, __bf16* __restrict__ WoT)
{
    const int flat = blockIdx.x;
    const int tid  = threadIdx.x;
    if (flat < 2560) {
        int i = flat * 256 + tid;
        const float4 v = *(const float4*)&x[4 * i];
        xb[4 * i + 0] = f2bf(v.x);
        xb[4 * i + 1] = f2bf(v.y);
        xb[4 * i + 2] = f2bf(v.z);
        xb[4 * i + 3] = f2bf(v.w);
        return;
    }
    const int wf = flat - 2560;
    const float* src;
    __bf16* dstb;
    int idx, tiles_x, N;
    if (wf < 400)      { src = Wq; dstb = WqkvT;             idx = wf;       tiles_x = 20; N = 640; }
    else if (wf < 500) { src = Wk; dstb = WqkvT + 640 * 640; idx = wf - 400; tiles_x = 5;  N = 160; }
    else if (wf < 600) { src = Wv; dstb = WqkvT + 800 * 640; idx = wf - 500; tiles_x = 5;  N = 160; }
    else               { src = Wo; dstb = WoT;               idx = wf - 600; tiles_x = 20; N = 640; }
    const int n0 = (idx % tiles_x) * 32;
    const int k0 = (idx / tiles_x) * 32;

    __shared__ float t[32][33];
    const int tx = tid & 31, ty = tid >> 5;     // 32 x 8
    #pragma unroll
    for (int i = 0; i < 4; ++i) {
        int r = ty + 8 * i;
        t[r][tx] = src[(size_t)(k0 + r) * N + n0 + tx];
    }
    __syncthreads();
    #pragma unroll
    for (int i = 0; i < 4; ++i) {
        int r = ty + 8 * i;
        dstb[(size_t)(n0 + r) * 640 + k0 + tx] = f2bf(t[tx][r]);
    }
}

// ---------------------------------------------------------------------------
// MFMA bf16 GEMM (r12/r14-proven): 512 threads = 8 waves (2M x 4N), tile
// 128x128, macro-step BK=64 (two 32-wide sub-tiles in separate LDS arrays),
// dbuf LDS, single-step-ahead reg prefetch, 1 barrier per macro-step.
// ---------------------------------------------------------------------------
template <typename OutT>
__global__ __launch_bounds__(512) void gemm_bf16_mfma(
    const __bf16* __restrict__ A, const __bf16* __restrict__ BT,
    OutT* __restrict__ C, int M, int N, int K, int ldc)
{
    __shared__ __bf16 As[2][2][128][40];   // [h][buf]
    __shared__ __bf16 Bs[2][2][128][40];
    const int BUFE = 128 * 40;

    const int tid  = threadIdx.x;
    const int wave = tid >> 6;
    const int lane = tid & 63;
    const int wr = wave >> 2, wc = wave & 3;
    const int l15 = lane & 15, lq = lane >> 4;
    const int m0 = blockIdx.y * 128, n0 = blockIdx.x * 128;

    f32x4 acc[4][2];
    #pragma unroll
    for (int m = 0; m < 4; ++m)
        #pragma unroll
        for (int n = 0; n < 2; ++n) acc[m][n] = (f32x4)0.0f;

    const int sArr  = tid >> 8;          // 0: stage A, 1: stage B
    const int sc    = tid & 255;
    const int srow  = sc >> 1;           // 0..127
    const int shalf = sc & 1;
    const __bf16* gsrc = sArr ? BT : A;
    const int     grow = sArr ? n0 : m0;
    const size_t  gb   = (size_t)(grow + srow) * K + 16 * shalf;
    __bf16* ld0 = (sArr ? &Bs[0][0][0][0] : &As[0][0][0][0]) + srow * 40 + 16 * shalf;
    __bf16* ld1 = (sArr ? &Bs[1][0][0][0] : &As[1][0][0][0]) + srow * 40 + 16 * shalf;

    const int nk = K >> 6;               // macro-steps of 64

    // prologue: macro-step 0 into buffer 0
    bf16x8 r00 = *(const bf16x8*)&gsrc[gb];
    bf16x8 r01 = *(const bf16x8*)&gsrc[gb + 8];
    bf16x8 r10 = *(const bf16x8*)&gsrc[gb + 32];
    bf16x8 r11 = *(const bf16x8*)&gsrc[gb + 40];
    *(bf16x8*)ld0       = r00;
    *(bf16x8*)(ld0 + 8) = r01;
    *(bf16x8*)ld1       = r10;
    *(bf16x8*)(ld1 + 8) = r11;
    __syncthreads();

    for (int ks = 0; ks < nk; ++ks) {
        const int cur = ks & 1;
        if (ks + 1 < nk) {
            const size_t gg = gb + (size_t)(ks + 1) * 64;
            r00 = *(const bf16x8*)&gsrc[gg];
            r01 = *(const bf16x8*)&gsrc[gg + 8];
            r10 = *(const bf16x8*)&gsrc[gg + 32];
            r11 = *(const bf16x8*)&gsrc[gg + 40];
        }

        __builtin_amdgcn_s_setprio(1);
        #pragma unroll
        for (int h = 0; h < 2; ++h) {
            bf16x8 af[4], bfr[2];
            #pragma unroll
            for (int m = 0; m < 4; ++m)
                af[m] = *(const bf16x8*)&As[h][cur][wr * 64 + m * 16 + l15][8 * lq];
            #pragma unroll
            for (int n = 0; n < 2; ++n)
                bfr[n] = *(const bf16x8*)&Bs[h][cur][wc * 32 + n * 16 + l15][8 * lq];
            #pragma unroll
            for (int m = 0; m < 4; ++m)
                #pragma unroll
                for (int n = 0; n < 2; ++n)
                    acc[m][n] = __builtin_amdgcn_mfma_f32_16x16x32_bf16(af[m], bfr[n], acc[m][n], 0, 0, 0);
        }
        __builtin_amdgcn_s_setprio(0);

        if (ks + 1 < nk) {
            const int nb = (cur ^ 1) * BUFE;
            *(bf16x8*)(ld0 + nb)     = r00;
            *(bf16x8*)(ld0 + nb + 8) = r01;
            *(bf16x8*)(ld1 + nb)     = r10;
            *(bf16x8*)(ld1 + nb + 8) = r11;
        }
        __syncthreads();
    }

    #pragma unroll
    for (int m = 0; m < 4; ++m) {
        #pragma unroll
        for (int n = 0; n < 2; ++n) {
            const int col = n0 + wc * 32 + n * 16 + l15;
            if (col < N) {
                const int rbase = m0 + wr * 64 + m * 16 + 4 * lq;
                #pragma unroll
                for (int r = 0; r < 4; ++r) {
                    if constexpr (sizeof(OutT) == 2)
                        C[(size_t)(rbase + r) * ldc + col] = f2bf(acc[m][n][r]);
                    else
                        C[(size_t)(rbase + r) * ldc + col] = acc[m][n][r];
                }
            }
        }
    }
}

// ---------------------------------------------------------------------------
// Fused RMSNorm+RoPE v2 (VECTORIZED, G13) + V-transpose.
// Blocks [0,2048): 2 rows each, 256 threads. Per row, 128 threads; thread
// lt<100 owns chunk lt = elems [8lt, 8lt+8) of the row's 800 used cols
// (q 0..639 = heads 0..7, k 640..799 = heads 8..9; head = lt/10, c10 = lt%10).
// bf16x8 load -> partial sumsq -> LDS reduce (10 partials/head) -> rms ->
// weight/rope via float4 loads (pairs chunk-internal) -> bf16x8 store.
// Blocks [2048,2688): V-transpose 32x32 tiles (r12-proven).
// ---------------------------------------------------------------------------
__global__ __launch_bounds__(256) void normrope_vt_kernel(
    const unsigned short* __restrict__ qkvb, const float* __restrict__ cosb,
    const float* __restrict__ sinb, const float* __restrict__ qw,
    const float* __restrict__ kw, __bf16* __restrict__ qb,
    __bf16* __restrict__ kb, unsigned short* __restrict__ vtb)
{
    const int flat = blockIdx.x;
    const int tid  = threadIdx.x;

    __shared__ float partial[2][100];
    __shared__ float red[2][10];
    __shared__ unsigned short t[32][33];

    if (flat < 2048) {
        const int half = tid >> 7;           // 0..1 -> row of the pair
        const int lt   = tid & 127;
        const int row  = flat * 2 + half;
        const int head = lt / 10;            // 0..9 (lt<100)
        const int c10  = lt - head * 10;     // chunk within head

        // ---- load chunk (8 bf16) ----
        float v[8];
        if (lt < 100) {
            const unsigned short* p = qkvb + (size_t)row * 960 + 8 * lt;
            bf16x8 raw = *(const bf16x8*)p;
            #pragma unroll
            for (int j = 0; j < 8; ++j) v[j] = bf2f(((unsigned short*)&raw)[j]);
            float sq = 0.0f;
            #pragma unroll
            for (int j = 0; j < 8; ++j) sq += v[j] * v[j];
            partial[half][lt] = sq;
        }
        __syncthreads();

        // ---- per-head reduce: 10 partials each ----
        if (lt < 10) {
            float s = 0.0f;
            #pragma unroll
            for (int c = 0; c < 10; ++c) s += partial[half][10 * lt + c];
            red[half][lt] = s;
        }
        __syncthreads();

        if (lt < 100) {
            const float rms = rsqrtf(red[half][head] * (1.0f / HDIM) + 1e-5f);
            const bool  isq = (head < NH);
            const float outscale = isq ? (0.11180339887498948f * 1.4426950408889634f) : 1.0f;

            // weights (within-head index 8*c10 + j)
            const float* wsrc = isq ? qw : kw;
            float4 w0 = *(const float4*)&wsrc[8 * c10];
            float4 w1 = *(const float4*)&wsrc[8 * c10 + 4];
            // cos/sin (d-pair index = (8*c10)/2 + j = 4*c10 + j)
            float4 cc = *(const float4*)&cosb[(size_t)row * 40 + 4 * c10];
            float4 ss = *(const float4*)&sinb[(size_t)row * 40 + 4 * c10];

            float wv[8] = { w0.x, w0.y, w0.z, w0.w, w1.x, w1.y, w1.z, w1.w };
            float cv[4] = { cc.x, cc.y, cc.z, cc.w };
            float sv[4] = { ss.x, ss.y, ss.z, ss.w };

            bf16x8 outp;
            #pragma unroll
            for (int j = 0; j < 4; ++j) {
                float ve = v[2 * j]     * rms * wv[2 * j];
                float vo = v[2 * j + 1] * rms * wv[2 * j + 1];
                float re = (ve * cv[j] - vo * sv[j]) * outscale;
                float ro = (vo * cv[j] + ve * sv[j]) * outscale;
                outp[2 * j]     = (__bf16)re;
                outp[2 * j + 1] = (__bf16)ro;
            }
            if (isq) {
                *(bf16x8*)&qb[(size_t)row * HIDDEN + 8 * lt] = outp;
            } else {
                *(bf16x8*)&kb[(size_t)row * (NKV * HDIM) + 8 * lt - HIDDEN] = outp;
            }
        }
        return;
    }

    // ---- V transpose: vtb[kvh][d][seq] ----
    const int idx = flat - 2048;             // 0..639
    const int s0 = (idx & 127) * 32;
    const int c0 = (idx >> 7) * 32;
    const int tx = tid & 31, ty = tid >> 5;  // 32 x 8
    #pragma unroll
    for (int i = 0; i < 4; ++i)
        t[ty + 8 * i][tx] = qkvb[(size_t)(s0 + ty + 8 * i) * 960 + 800 + c0 + tx];
    __syncthreads();
    #pragma unroll
    for (int i = 0; i < 4; ++i) {
        int g = c0 + ty + 8 * i;             // 0..159
        int kvh = g / HDIM, d = g % HDIM;
        vtb[((size_t)kvh * HDIM + d) * SEQ + s0 + tx] = t[tx][ty + 8 * i];
    }
}

// ---------------------------------------------------------------------------
// GQA-fused MFMA flash attention (r17-proven, swapped S-operands):
// S = mfma(K, Q) -> lane holds one q-row (l15), keys 16n+4lq+{0..3}.
// Packed b64 P-writes, scalar m/l, ones-column l-sum, sink prepass,
// K/V double-buffer (1 barrier/tile). 512 threads = 8 waves. LDS ~147 KB.
// ---------------------------------------------------------------------------
__global__ __launch_bounds__(512) void flash_attn_mfma(
    const __bf16* __restrict__ qb, const __bf16* __restrict__ kb,
    const __bf16* __restrict__ vtb, __bf16* __restrict__ attnb)
{
    const int i0   = blockIdx.x * BQG;
    const int kvh  = blockIdx.y;
    const int tid  = threadIdx.x;        // 0..511
    const int w    = tid >> 6;           // 0..7
    const int h    = kvh * 4 + (w >> 1);
    const int wsub = w & 1;
    const int lane = tid & 63;
    const int l15  = lane & 15;
    const int lq   = lane >> 4;

    __shared__ __bf16 Ks[2][BK][KSTR];   // 53248 B
    __shared__ __bf16 Vt[2][96][VSTR];   // 52224 B (rows 80..95: ones/zeros)
    __shared__ __bf16 Pl[128][VSTR];     // 34816 B
    __shared__ __bf16 Ksk[16][KSTR];     //  3328 B (sink K, keys 0..15)
    __shared__ __bf16 Vtk[HDIM][VSTRK];  //  6400 B (sink V, keys 0..31)

    // zero K pad columns 80..95 of BOTH buffers
    {
        int b = tid >> 8, r = (tid >> 1) & 127, c = HDIM + 8 * (tid & 1);
        *(float4*)&Ks[b][r][c] = make_float4(0.f, 0.f, 0.f, 0.f);
    }
    // Vt rows 80..95: row 80 = 1.0 (l-accumulator), 81..95 = 0.0
    for (int i = tid; i < 2 * 16 * VSTR; i += 512) {
        int b = i / (16 * VSTR), rem = i % (16 * VSTR);
        int r = rem / VSTR, c = rem % VSTR;
        Vt[b][80 + r][c] = (r == 0) ? (__bf16)1.0f : (__bf16)0.0f;
    }

    // window staging maps: 1280 chunks of 8 bf16 each (chunk = tid + 512*i)
    int koff[3], voff[3];
    __bf16* ksdst0[3];
    __bf16* vsdst0[3];
    bool act[3];
    #pragma unroll
    for (int i = 0; i < 3; ++i) {
        int c = tid + 512 * i;
        act[i] = (c < 1280);
        int cc = act[i] ? c : 0;
        koff[i] = (cc / 10) * (NKV * HDIM) + 8 * (cc % 10);
        voff[i] = (cc >> 4) * SEQ + 8 * (cc & 15);
        ksdst0[i] = &Ks[0][cc / 10][8 * (cc % 10)];
        vsdst0[i] = &Vt[0][cc >> 4][8 * (cc & 15)];
    }
    const size_t ksbuf = (size_t)BK * KSTR;
    const size_t vsbuf = (size_t)96 * VSTR;
    const __bf16* kbase = kb + kvh * HDIM;
    const __bf16* vbase = vtb + (size_t)kvh * HDIM * SEQ;

    // preload Q A-fragments (q-row i0 + 16*wsub + l15)
    bf16x8 qf[3];
    {
        const __bf16* qrow = qb + (size_t)(i0 + 16 * wsub + l15) * HIDDEN + h * HDIM;
        #pragma unroll
        for (int ks = 0; ks < 3; ++ks) {
            int off = 32 * ks + 8 * lq;
            if (off >= HDIM) off = 0;     // dummy: multiplied by zeroed K pad
            qf[ks] = *(const bf16x8*)&qrow[off];
        }
    }

    float m_i = -1e30f, l_i = 0.0f;       // per-lane: q-row i0+16*wsub+l15
    f32x4 o[6];                           // o[5] = P row-sum accumulator
    #pragma unroll
    for (int n = 0; n < 6; ++n) o[n] = (f32x4)0.0f;

    const int w_lo   = i0 - (WINDOW - 1);
    const int w_tile = (w_lo <= 0) ? 0 : (w_lo & ~(BK - 1));
    const int lastt  = (i0 + BQG - 1) & ~(BK - 1);
    const int n_win  = (lastt - w_tile) / BK + 1;
    const bool has_sink = (w_tile > 0);   // sinks disjoint from window

    // ---- prologue: stage tile 0 + sink K/V, one barrier ----
    bf16x8 krg[3], vrg[3];
    #pragma unroll
    for (int i = 0; i < 3; ++i) {
        if (act[i]) {
            krg[i] = *(const bf16x8*)&kbase[(size_t)w_tile * (NKV * HDIM) + koff[i]];
            vrg[i] = *(const bf16x8*)&vbase[(size_t)w_tile + voff[i]];
        }
    }
    if (has_sink) {
        if (tid < 160) {                 // Ksk: 16 rows x 10 chunks
            int r = tid / 10, c8 = tid % 10;
            *(bf16x8*)&Ksk[r][8 * c8] =
                *(const bf16x8*)&kbase[(size_t)r * (NKV * HDIM) + 8 * c8];
        } else if (tid < 192) {          // Ksk pad cols 80..95
            int r = (tid - 160) >> 1, c = HDIM + 8 * (tid & 1);
            *(float4*)&Ksk[r][c] = make_float4(0.f, 0.f, 0.f, 0.f);
        } else if (tid < 512) {          // Vtk: 80 rows x 4 chunks
            int c = tid - 192;           // 0..319
            *(bf16x8*)&Vtk[c >> 2][8 * (c & 3)] =
                *(const bf16x8*)&vbase[(size_t)(c >> 2) * SEQ + 8 * (c & 3)];
        }
    }
    #pragma unroll
    for (int i = 0; i < 3; ++i) {
        if (act[i]) {
            *(bf16x8*)ksdst0[i] = krg[i];
            *(bf16x8*)vsdst0[i] = vrg[i];
        }
    }
    __syncthreads();

    // ---- sink prepass (swapped): keys = 4lq+r, q-row = l15 ----
    if (has_sink) {
        f32x4 sk = (f32x4)0.0f;
        #pragma unroll
        for (int ks = 0; ks < 3; ++ks) {
            bf16x8 kf = *(const bf16x8*)&Ksk[l15][32 * ks + 8 * lq];
            sk = __builtin_amdgcn_mfma_f32_16x16x32_bf16(kf, qf[ks], sk, 0, 0, 0);
        }
        // mask keys >= SINK: key = 4lq + r, valid only lq==0 (r<4)
        if (lq != 0) {
            #pragma unroll
            for (int r = 0; r < 4; ++r) sk[r] = -1e30f;
        }
        float mx = fmaxf(fmaxf(sk[0], sk[1]), fmaxf(sk[2], sk[3]));
        mx = fmaxf(mx, __shfl_xor(mx, 16));
        mx = fmaxf(mx, __shfl_xor(mx, 32));
        m_i = mx;
        bf16x4 pk;
        float rsum = 0.0f;
        #pragma unroll
        for (int r = 0; r < 4; ++r) {
            float pe = fexp2(sk[r] - m_i);
            pk[r] = (__bf16)pe;
            rsum += pe;
        }
        *(bf16x4*)&Pl[16 * w + l15][4 * lq] = pk;
        bf16x4 zz;
        #pragma unroll
        for (int r = 0; r < 4; ++r) zz[r] = (__bf16)0.0f;
        *(bf16x4*)&Pl[16 * w + l15][16 + 4 * lq] = zz;
        rsum += __shfl_xor(rsum, 16);
        rsum += __shfl_xor(rsum, 32);
        l_i = rsum;
        #pragma unroll
        for (int n = 0; n < 5; ++n) {
            bf16x8 pf = *(const bf16x8*)&Pl[16 * w + l15][8 * lq];
            bf16x8 vf = *(const bf16x8*)&Vtk[16 * n + l15][8 * lq];
            o[n] = __builtin_amdgcn_mfma_f32_16x16x32_bf16(pf, vf, o[n], 0, 0, 0);
        }
    }

    // ---- main loop: window tiles only, 1 barrier/tile ----
    for (int t = 0; t < n_win; ++t) {
        const int cur = t & 1;
        const int j0 = w_tile + t * BK;
        const bool more = (t + 1 < n_win);

        if (more) {
            const int j1 = j0 + BK;
            #pragma unroll
            for (int i = 0; i < 3; ++i) {
                if (act[i]) {
                    krg[i] = *(const bf16x8*)&kbase[(size_t)j1 * (NKV * HDIM) + koff[i]];
                    vrg[i] = *(const bf16x8*)&vbase[(size_t)j1 + voff[i]];
                }
            }
        }

        // ---- S = K Q^T (swapped): 24 MFMA per wave ----
        f32x4 sacc[8];
        #pragma unroll
        for (int n = 0; n < 8; ++n) sacc[n] = (f32x4)0.0f;
        __builtin_amdgcn_s_setprio(1);
        #pragma unroll
        for (int ks = 0; ks < 3; ++ks) {
            #pragma unroll
            for (int n = 0; n < 8; ++n) {
                bf16x8 kf = *(const bf16x8*)&Ks[cur][n * 16 + l15][32 * ks + 8 * lq];
                sacc[n] = __builtin_amdgcn_mfma_f32_16x16x32_bf16(kf, qf[ks], sacc[n], 0, 0, 0);
            }
        }
        __builtin_amdgcn_s_setprio(0);

        // ---- mask: key j = j0+16n+4lq+r, q i = i0+16wsub+l15 ----
        const bool full = (j0 >= i0 - 480) && (j0 <= i0 - 128);
        if (!full) {
            const int i = i0 + 16 * wsub + l15;
            #pragma unroll
            for (int n = 0; n < 8; ++n) {
                #pragma unroll
                for (int r = 0; r < 4; ++r) {
                    int j = j0 + 16 * n + 4 * lq + r;
                    bool allowed = (j <= i) && ((j >= i - (WINDOW - 1)) || (j < SINK));
                    if (!allowed) sacc[n][r] = -1e30f;
                }
            }
        }

        // ---- online softmax (swapped): in-lane max + 2 shfl ----
        {
            float mx = sacc[0][0];
            #pragma unroll
            for (int n = 0; n < 8; ++n) {
                float a = fmaxf(fmaxf(sacc[n][0], sacc[n][1]),
                                fmaxf(sacc[n][2], sacc[n][3]));
                mx = (n == 0) ? a : fmaxf(mx, a);
            }
            mx = fmaxf(mx, __shfl_xor(mx, 16));
            mx = fmaxf(mx, __shfl_xor(mx, 32));

            float alpha_own = 1.0f;
            bool grow = (mx > m_i);
            if (grow) {
                alpha_own = fexp2(m_i - mx);
                m_i = mx;
                l_i *= alpha_own;
            }
            if (__any(grow)) {
                // redistribute alpha from l15-space to (4lq+r)-space
                #pragma unroll
                for (int r = 0; r < 4; ++r) {
                    float ar = __shfl(alpha_own, 4 * lq + r);
                    #pragma unroll
                    for (int n = 0; n < 6; ++n) o[n][r] *= ar;
                }
            }
            // pe + packed b64 writes (8 per lane)
            #pragma unroll
            for (int n = 0; n < 8; ++n) {
                bf16x4 pk;
                #pragma unroll
                for (int r = 0; r < 4; ++r)
                    pk[r] = (__bf16)fexp2(sacc[n][r] - m_i);
                *(bf16x4*)&Pl[16 * w + l15][16 * n + 4 * lq] = pk;
            }
        }

        // ---- O += P V : 24 MFMA per wave (block 5 = l-accumulator) ----
        __builtin_amdgcn_s_setprio(1);
        #pragma unroll
        for (int ks = 0; ks < 4; ++ks) {
            bf16x8 pf = *(const bf16x8*)&Pl[16 * w + l15][32 * ks + 8 * lq];
            #pragma unroll
            for (int n = 0; n < 6; ++n) {
                bf16x8 vf = *(const bf16x8*)&Vt[cur][16 * n + l15][32 * ks + 8 * lq];
                o[n] = __builtin_amdgcn_mfma_f32_16x16x32_bf16(pf, vf, o[n], 0, 0, 0);
            }
        }
        __builtin_amdgcn_s_setprio(0);

        // ---- write next tile into the other buffer, then one barrier ----
        if (more) {
            #pragma unroll
            for (int i = 0; i < 3; ++i) {
                if (act[i]) {
                    *(bf16x8*)(ksdst0[i] + (cur ^ 1) * ksbuf) = krg[i];
                    *(bf16x8*)(vsdst0[i] + (cur ^ 1) * vsbuf) = vrg[i];
                }
            }
            __syncthreads();
        }
    }

    // ---- epilogue: l(row 4lq+r) = shfl(l_i) + o[5]@(l15==0) ----
    #pragma unroll
    for (int r = 0; r < 4; ++r) {
        float l_snk = __shfl(l_i, 4 * lq + r);
        float l_pv  = __shfl(o[5][r], lane & 48);
        float inv = 1.0f / (l_snk + l_pv);
        int row = i0 + 16 * wsub + 4 * lq + r;
        #pragma unroll
        for (int n = 0; n < 5; ++n)
            attnb[(size_t)row * HIDDEN + h * HDIM + 16 * n + l15] = (__bf16)(o[n][r] * inv);
    }
}

// ---------------------------------------------------------------------------
extern "C" void kernel_launch(void* const* d_in, const int* in_sizes, int n_in,
                              void* d_out, int out_size, void* d_ws, size_t ws_size,
                              hipStream_t stream)
{
    const float* x    = (const float*)d_in[0];
    const float* cosb = (const float*)d_in[1];
    const float* sinb = (const float*)d_in[2];
    const float* Wq   = (const float*)d_in[3];
    const float* Wk   = (const float*)d_in[4];
    const float* Wv   = (const float*)d_in[5];
    const float* Wo   = (const float*)d_in[6];
    const float* qw   = (const float*)d_in[7];
    const float* kw   = (const float*)d_in[8];
    float* out = (float*)d_out;

    char* ws = (char*)d_ws;
    __bf16* qkvb  = (__bf16*)ws;                                 // [4096][960]
    __bf16* xb    = qkvb + (size_t)SEQ * 960;                    // [4096][640] = attnb
    __bf16* qb    = xb   + (size_t)SEQ * HIDDEN;                 // [4096][640]
    __bf16* kb    = qb   + (size_t)SEQ * HIDDEN;                 // [4096][160]
    __bf16* vtb   = kb   + (size_t)SEQ * 160;                    // [2][80][4096]
    __bf16* WqkvT = vtb  + (size_t)2 * HDIM * SEQ;               // [1024][640]
    __bf16* WoT   = WqkvT + (size_t)1024 * HIDDEN;               // [640][640]

    prep_kernel<<<dim3(3560), dim3(256), 0, stream>>>(
        x, Wq, Wk, Wv, Wo, xb, WqkvT, WoT);

    gemm_bf16_mfma<__bf16><<<dim3(8, SEQ / 128), dim3(512), 0, stream>>>(
        xb, WqkvT, qkvb, SEQ, 960, HIDDEN, 960);

    normrope_vt_kernel<<<dim3(2688), dim3(256), 0, stream>>>(
        (const unsigned short*)qkvb, cosb, sinb, qw, kw, qb, kb,
        (unsigned short*)vtb);

    flash_attn_mfma<<<dim3(SEQ / BQG, NKV), dim3(512), 0, stream>>>(
        qb, kb, vtb, xb);

    gemm_bf16_mfma<float><<<dim3(HIDDEN / 128, SEQ / 128), dim3(512), 0, stream>>>(
        xb, WoT, out, SEQ, HIDDEN, HIDDEN, HIDDEN);
}

// Round 19
// 63.211 us; speedup vs baseline: 1.1866x; 1.0234x over previous
//
#include <hip/hip_runtime.h>
#include <hip/hip_bf16.h>
#include <stdint.h>

#define SEQ     4096
#define HIDDEN  640
#define HDIM    80
#define NH      8
#define NKV     2
#define WINDOW  512
#define SINK    4
#define BQG     32    // flash q-tile (shared by 4 heads)
#define BK      128   // flash key-tile
#define KSTR    104   // Ks row stride (bf16): 2-way banks on b128 reads
#define VSTR    136   // Vt/Pl row stride (bf16): 2-way banks (128+8)
#define VSTRK   40    // Vtk sink row stride

typedef __bf16 bf16x8 __attribute__((ext_vector_type(8)));
typedef __bf16 bf16x4 __attribute__((ext_vector_type(4)));
typedef float  f32x4  __attribute__((ext_vector_type(4)));

__device__ inline __bf16 f2bf(float f) {
    union { float f; uint32_t u; } x; x.f = f;
    uint32_t r = x.u + 0x7FFF + ((x.u >> 16) & 1);   // RNE, no NaN inputs
    union { unsigned short s; __bf16 b; } y; y.s = (unsigned short)(r >> 16);
    return y.b;
}
__device__ inline float bf2f(unsigned short u) {
    union { uint32_t u; float f; } c; c.u = ((uint32_t)u) << 16; return c.f;
}
__device__ inline float fexp2(float x) {
#if __has_builtin(__builtin_amdgcn_exp2f)
    return __builtin_amdgcn_exp2f(x);
#else
    return exp2f(x);
#endif
}

// ---------------------------------------------------------------------------
// Fused prep: x -> bf16 (blocks [0,2560)) + all weight transposes
// (blocks [2560,3560), 32x32 tiles).  (r12-proven)
// ---------------------------------------------------------------------------
__global__ __launch_bounds__(256) void prep_kernel(
    const float* __restrict__ x, const float* __restrict__ Wq,
    const float* __restrict__ Wk, const float* __restrict__ Wv,
    const float* __restrict__ Wo, __bf16* __restrict__ xb,
    __bf16* __restrict__ WqkvT, __bf16* __restrict__ WoT)
{
    const int flat = blockIdx.x;
    const int tid  = threadIdx.x;
    if (flat < 2560) {
        int i = flat * 256 + tid;
        const float4 v = *(const float4*)&x[4 * i];
        xb[4 * i + 0] = f2bf(v.x);
        xb[4 * i + 1] = f2bf(v.y);
        xb[4 * i + 2] = f2bf(v.z);
        xb[4 * i + 3] = f2bf(v.w);
        return;
    }
    const int wf = flat - 2560;
    const float* src;
    __bf16* dstb;
    int idx, tiles_x, N;
    if (wf < 400)      { src = Wq; dstb = WqkvT;             idx = wf;       tiles_x = 20; N = 640; }
    else if (wf < 500) { src = Wk; dstb = WqkvT + 640 * 640; idx = wf - 400; tiles_x = 5;  N = 160; }
    else if (wf < 600) { src = Wv; dstb = WqkvT + 800 * 640; idx = wf - 500; tiles_x = 5;  N = 160; }
    else               { src = Wo; dstb = WoT;               idx = wf - 600; tiles_x = 20; N = 640; }
    const int n0 = (idx % tiles_x) * 32;
    const int k0 = (idx / tiles_x) * 32;

    __shared__ float t[32][33];
    const int tx = tid & 31, ty = tid >> 5;     // 32 x 8
    #pragma unroll
    for (int i = 0; i < 4; ++i) {
        int r = ty + 8 * i;
        t[r][tx] = src[(size_t)(k0 + r) * N + n0 + tx];
    }
    __syncthreads();
    #pragma unroll
    for (int i = 0; i < 4; ++i) {
        int r = ty + 8 * i;
        dstb[(size_t)(n0 + r) * 640 + k0 + tx] = f2bf(t[tx][r]);
    }
}

// ---------------------------------------------------------------------------
// MFMA bf16 GEMM v3: tile 64x128 (BM=64), 512 threads = 8 waves (2M x 4N),
// macro-step BK=64 (two 32-wide sub-tiles, separate LDS arrays), dbuf LDS,
// single-step-ahead reg prefetch, 1 barrier/macro-step. LDS 61.4 KB ->
// 2 blocks/CU (phase diversity). Grid: (ceil(N/128), M/64).
// Staging: 1536 bf16x8 chunks (A: 512 = 64 rows x 8, B: 1024 = 128 rows x 8),
// 3 chunks per thread (j=0 -> A, j=1,2 -> B), all static indices.
// K-slice order per macro-step identical to r12 form -> bit-identical output.
// ---------------------------------------------------------------------------
template <typename OutT>
__global__ __launch_bounds__(512) void gemm_bf16_mfma(
    const __bf16* __restrict__ A, const __bf16* __restrict__ BT,
    OutT* __restrict__ C, int M, int N, int K, int ldc)
{
    __shared__ __bf16 As[2][2][64][40];    // [h][buf]  20480 B
    __shared__ __bf16 Bs[2][2][128][40];   // [h][buf]  40960 B
    const int BUFA = 64 * 40;
    const int BUFB = 128 * 40;

    const int tid  = threadIdx.x;
    const int wave = tid >> 6;
    const int lane = tid & 63;
    const int wr = wave >> 2, wc = wave & 3;     // 2M x 4N
    const int l15 = lane & 15, lq = lane >> 4;
    const int m0 = blockIdx.y * 64, n0 = blockIdx.x * 128;

    f32x4 acc[2][2];
    #pragma unroll
    for (int m = 0; m < 2; ++m)
        #pragma unroll
        for (int n = 0; n < 2; ++n) acc[m][n] = (f32x4)0.0f;

    // ---- staging descriptors: 3 chunks/thread ----
    // j=0: A chunk tid (row tid>>3, q=tid&7, h=q>>2, sl=q&3)
    // j=1: B chunk tid; j=2: B chunk tid+512  (row b>>3, same q decode)
    size_t goff[3];
    __bf16* ldst[3];           // buf-0 LDS target
    int     bstr[3];           // elems per buf step
    {
        int r0 = tid >> 3, q0 = tid & 7, h0 = q0 >> 2, s0 = q0 & 3;
        goff[0] = (size_t)(m0 + r0) * K + h0 * 32 + 8 * s0;
        ldst[0] = &As[h0][0][r0][8 * s0];
        bstr[0] = BUFA;
        #pragma unroll
        for (int j = 1; j < 3; ++j) {
            int b  = tid + (j - 1) * 512;        // 0..1023
            int rb = b >> 3, qb = b & 7, hb = qb >> 2, sb = qb & 3;
            goff[j] = (size_t)(n0 + rb) * K + hb * 32 + 8 * sb;
            ldst[j] = &Bs[hb][0][rb][8 * sb];
            bstr[j] = BUFB;
        }
    }
    const __bf16* gsrcs[3] = { A, BT, BT };

    const int nk = K >> 6;               // macro-steps of 64

    // prologue: macro-step 0 into buffer 0
    bf16x8 rg0 = *(const bf16x8*)&gsrcs[0][goff[0]];
    bf16x8 rg1 = *(const bf16x8*)&gsrcs[1][goff[1]];
    bf16x8 rg2 = *(const bf16x8*)&gsrcs[2][goff[2]];
    *(bf16x8*)ldst[0] = rg0;
    *(bf16x8*)ldst[1] = rg1;
    *(bf16x8*)ldst[2] = rg2;
    __syncthreads();

    for (int ks = 0; ks < nk; ++ks) {
        const int cur = ks & 1;
        if (ks + 1 < nk) {
            const size_t kadv = (size_t)(ks + 1) * 64;
            rg0 = *(const bf16x8*)&gsrcs[0][goff[0] + kadv];
            rg1 = *(const bf16x8*)&gsrcs[1][goff[1] + kadv];
            rg2 = *(const bf16x8*)&gsrcs[2][goff[2] + kadv];
        }

        __builtin_amdgcn_s_setprio(1);
        #pragma unroll
        for (int h = 0; h < 2; ++h) {
            bf16x8 af[2], bfr[2];
            #pragma unroll
            for (int m = 0; m < 2; ++m)
                af[m] = *(const bf16x8*)&As[h][cur][wr * 32 + m * 16 + l15][8 * lq];
            #pragma unroll
            for (int n = 0; n < 2; ++n)
                bfr[n] = *(const bf16x8*)&Bs[h][cur][wc * 32 + n * 16 + l15][8 * lq];
            #pragma unroll
            for (int m = 0; m < 2; ++m)
                #pragma unroll
                for (int n = 0; n < 2; ++n)
                    acc[m][n] = __builtin_amdgcn_mfma_f32_16x16x32_bf16(af[m], bfr[n], acc[m][n], 0, 0, 0);
        }
        __builtin_amdgcn_s_setprio(0);

        if (ks + 1 < nk) {
            *(bf16x8*)(ldst[0] + (cur ^ 1) * bstr[0]) = rg0;
            *(bf16x8*)(ldst[1] + (cur ^ 1) * bstr[1]) = rg1;
            *(bf16x8*)(ldst[2] + (cur ^ 1) * bstr[2]) = rg2;
        }
        __syncthreads();
    }

    #pragma unroll
    for (int m = 0; m < 2; ++m) {
        #pragma unroll
        for (int n = 0; n < 2; ++n) {
            const int col = n0 + wc * 32 + n * 16 + l15;
            if (col < N) {
                const int rbase = m0 + wr * 32 + m * 16 + 4 * lq;
                #pragma unroll
                for (int r = 0; r < 4; ++r) {
                    if constexpr (sizeof(OutT) == 2)
                        C[(size_t)(rbase + r) * ldc + col] = f2bf(acc[m][n][r]);
                    else
                        C[(size_t)(rbase + r) * ldc + col] = acc[m][n][r];
                }
            }
        }
    }
}

// ---------------------------------------------------------------------------
// Fused RMSNorm+RoPE v2 (vectorized, r18-proven) + V-transpose.
// ---------------------------------------------------------------------------
__global__ __launch_bounds__(256) void normrope_vt_kernel(
    const unsigned short* __restrict__ qkvb, const float* __restrict__ cosb,
    const float* __restrict__ sinb, const float* __restrict__ qw,
    const float* __restrict__ kw, __bf16* __restrict__ qb,
    __bf16* __restrict__ kb, unsigned short* __restrict__ vtb)
{
    const int flat = blockIdx.x;
    const int tid  = threadIdx.x;

    __shared__ float partial[2][100];
    __shared__ float red[2][10];
    __shared__ unsigned short t[32][33];

    if (flat < 2048) {
        const int half = tid >> 7;           // 0..1 -> row of the pair
        const int lt   = tid & 127;
        const int row  = flat * 2 + half;
        const int head = lt / 10;            // 0..9 (lt<100)
        const int c10  = lt - head * 10;     // chunk within head

        float v[8];
        if (lt < 100) {
            const unsigned short* p = qkvb + (size_t)row * 960 + 8 * lt;
            bf16x8 raw = *(const bf16x8*)p;
            #pragma unroll
            for (int j = 0; j < 8; ++j) v[j] = bf2f(((unsigned short*)&raw)[j]);
            float sq = 0.0f;
            #pragma unroll
            for (int j = 0; j < 8; ++j) sq += v[j] * v[j];
            partial[half][lt] = sq;
        }
        __syncthreads();

        if (lt < 10) {
            float s = 0.0f;
            #pragma unroll
            for (int c = 0; c < 10; ++c) s += partial[half][10 * lt + c];
            red[half][lt] = s;
        }
        __syncthreads();

        if (lt < 100) {
            const float rms = rsqrtf(red[half][head] * (1.0f / HDIM) + 1e-5f);
            const bool  isq = (head < NH);
            const float outscale = isq ? (0.11180339887498948f * 1.4426950408889634f) : 1.0f;

            const float* wsrc = isq ? qw : kw;
            float4 w0 = *(const float4*)&wsrc[8 * c10];
            float4 w1 = *(const float4*)&wsrc[8 * c10 + 4];
            float4 cc = *(const float4*)&cosb[(size_t)row * 40 + 4 * c10];
            float4 ss = *(const float4*)&sinb[(size_t)row * 40 + 4 * c10];

            float wv[8] = { w0.x, w0.y, w0.z, w0.w, w1.x, w1.y, w1.z, w1.w };
            float cv[4] = { cc.x, cc.y, cc.z, cc.w };
            float sv[4] = { ss.x, ss.y, ss.z, ss.w };

            bf16x8 outp;
            #pragma unroll
            for (int j = 0; j < 4; ++j) {
                float ve = v[2 * j]     * rms * wv[2 * j];
                float vo = v[2 * j + 1] * rms * wv[2 * j + 1];
                float re = (ve * cv[j] - vo * sv[j]) * outscale;
                float ro = (vo * cv[j] + ve * sv[j]) * outscale;
                outp[2 * j]     = (__bf16)re;
                outp[2 * j + 1] = (__bf16)ro;
            }
            if (isq) {
                *(bf16x8*)&qb[(size_t)row * HIDDEN + 8 * lt] = outp;
            } else {
                *(bf16x8*)&kb[(size_t)row * (NKV * HDIM) + 8 * lt - HIDDEN] = outp;
            }
        }
        return;
    }

    // ---- V transpose: vtb[kvh][d][seq] ----
    const int idx = flat - 2048;             // 0..639
    const int s0 = (idx & 127) * 32;
    const int c0 = (idx >> 7) * 32;
    const int tx = tid & 31, ty = tid >> 5;  // 32 x 8
    #pragma unroll
    for (int i = 0; i < 4; ++i)
        t[ty + 8 * i][tx] = qkvb[(size_t)(s0 + ty + 8 * i) * 960 + 800 + c0 + tx];
    __syncthreads();
    #pragma unroll
    for (int i = 0; i < 4; ++i) {
        int g = c0 + ty + 8 * i;             // 0..159
        int kvh = g / HDIM, d = g % HDIM;
        vtb[((size_t)kvh * HDIM + d) * SEQ + s0 + tx] = t[tx][ty + 8 * i];
    }
}

// ---------------------------------------------------------------------------
// GQA-fused MFMA flash attention (r17/r18-proven, swapped S-operands):
// S = mfma(K, Q) -> lane holds one q-row (l15), keys 16n+4lq+{0..3}.
// Packed b64 P-writes, scalar m/l, ones-column l-sum, sink prepass,
// K/V double-buffer (1 barrier/tile). 512 threads = 8 waves. LDS ~147 KB.
// ---------------------------------------------------------------------------
__global__ __launch_bounds__(512) void flash_attn_mfma(
    const __bf16* __restrict__ qb, const __bf16* __restrict__ kb,
    const __bf16* __restrict__ vtb, __bf16* __restrict__ attnb)
{
    const int i0   = blockIdx.x * BQG;
    const int kvh  = blockIdx.y;
    const int tid  = threadIdx.x;        // 0..511
    const int w    = tid >> 6;           // 0..7
    const int h    = kvh * 4 + (w >> 1);
    const int wsub = w & 1;
    const int lane = tid & 63;
    const int l15  = lane & 15;
    const int lq   = lane >> 4;

    __shared__ __bf16 Ks[2][BK][KSTR];   // 53248 B
    __shared__ __bf16 Vt[2][96][VSTR];   // 52224 B (rows 80..95: ones/zeros)
    __shared__ __bf16 Pl[128][VSTR];     // 34816 B
    __shared__ __bf16 Ksk[16][KSTR];     //  3328 B (sink K, keys 0..15)
    __shared__ __bf16 Vtk[HDIM][VSTRK];  //  6400 B (sink V, keys 0..31)

    // zero K pad columns 80..95 of BOTH buffers
    {
        int b = tid >> 8, r = (tid >> 1) & 127, c = HDIM + 8 * (tid & 1);
        *(float4*)&Ks[b][r][c] = make_float4(0.f, 0.f, 0.f, 0.f);
    }
    // Vt rows 80..95: row 80 = 1.0 (l-accumulator), 81..95 = 0.0
    for (int i = tid; i < 2 * 16 * VSTR; i += 512) {
        int b = i / (16 * VSTR), rem = i % (16 * VSTR);
        int r = rem / VSTR, c = rem % VSTR;
        Vt[b][80 + r][c] = (r == 0) ? (__bf16)1.0f : (__bf16)0.0f;
    }

    // window staging maps: 1280 chunks of 8 bf16 each (chunk = tid + 512*i)
    int koff[3], voff[3];
    __bf16* ksdst0[3];
    __bf16* vsdst0[3];
    bool act[3];
    #pragma unroll
    for (int i = 0; i < 3; ++i) {
        int c = tid + 512 * i;
        act[i] = (c < 1280);
        int cc = act[i] ? c : 0;
        koff[i] = (cc / 10) * (NKV * HDIM) + 8 * (cc % 10);
        voff[i] = (cc >> 4) * SEQ + 8 * (cc & 15);
        ksdst0[i] = &Ks[0][cc / 10][8 * (cc % 10)];
        vsdst0[i] = &Vt[0][cc >> 4][8 * (cc & 15)];
    }
    const size_t ksbuf = (size_t)BK * KSTR;
    const size_t vsbuf = (size_t)96 * VSTR;
    const __bf16* kbase = kb + kvh * HDIM;
    const __bf16* vbase = vtb + (size_t)kvh * HDIM * SEQ;

    // preload Q A-fragments (q-row i0 + 16*wsub + l15)
    bf16x8 qf[3];
    {
        const __bf16* qrow = qb + (size_t)(i0 + 16 * wsub + l15) * HIDDEN + h * HDIM;
        #pragma unroll
        for (int ks = 0; ks < 3; ++ks) {
            int off = 32 * ks + 8 * lq;
            if (off >= HDIM) off = 0;     // dummy: multiplied by zeroed K pad
            qf[ks] = *(const bf16x8*)&qrow[off];
        }
    }

    float m_i = -1e30f, l_i = 0.0f;       // per-lane: q-row i0+16*wsub+l15
    f32x4 o[6];                           // o[5] = P row-sum accumulator
    #pragma unroll
    for (int n = 0; n < 6; ++n) o[n] = (f32x4)0.0f;

    const int w_lo   = i0 - (WINDOW - 1);
    const int w_tile = (w_lo <= 0) ? 0 : (w_lo & ~(BK - 1));
    const int lastt  = (i0 + BQG - 1) & ~(BK - 1);
    const int n_win  = (lastt - w_tile) / BK + 1;
    const bool has_sink = (w_tile > 0);   // sinks disjoint from window

    // ---- prologue: stage tile 0 + sink K/V, one barrier ----
    bf16x8 krg[3], vrg[3];
    #pragma unroll
    for (int i = 0; i < 3; ++i) {
        if (act[i]) {
            krg[i] = *(const bf16x8*)&kbase[(size_t)w_tile * (NKV * HDIM) + koff[i]];
            vrg[i] = *(const bf16x8*)&vbase[(size_t)w_tile + voff[i]];
        }
    }
    if (has_sink) {
        if (tid < 160) {                 // Ksk: 16 rows x 10 chunks
            int r = tid / 10, c8 = tid % 10;
            *(bf16x8*)&Ksk[r][8 * c8] =
                *(const bf16x8*)&kbase[(size_t)r * (NKV * HDIM) + 8 * c8];
        } else if (tid < 192) {          // Ksk pad cols 80..95
            int r = (tid - 160) >> 1, c = HDIM + 8 * (tid & 1);
            *(float4*)&Ksk[r][c] = make_float4(0.f, 0.f, 0.f, 0.f);
        } else if (tid < 512) {          // Vtk: 80 rows x 4 chunks
            int c = tid - 192;           // 0..319
            *(bf16x8*)&Vtk[c >> 2][8 * (c & 3)] =
                *(const bf16x8*)&vbase[(size_t)(c >> 2) * SEQ + 8 * (c & 3)];
        }
    }
    #pragma unroll
    for (int i = 0; i < 3; ++i) {
        if (act[i]) {
            *(bf16x8*)ksdst0[i] = krg[i];
            *(bf16x8*)vsdst0[i] = vrg[i];
        }
    }
    __syncthreads();

    // ---- sink prepass (swapped): keys = 4lq+r, q-row = l15 ----
    if (has_sink) {
        f32x4 sk = (f32x4)0.0f;
        #pragma unroll
        for (int ks = 0; ks < 3; ++ks) {
            bf16x8 kf = *(const bf16x8*)&Ksk[l15][32 * ks + 8 * lq];
            sk = __builtin_amdgcn_mfma_f32_16x16x32_bf16(kf, qf[ks], sk, 0, 0, 0);
        }
        if (lq != 0) {
            #pragma unroll
            for (int r = 0; r < 4; ++r) sk[r] = -1e30f;
        }
        float mx = fmaxf(fmaxf(sk[0], sk[1]), fmaxf(sk[2], sk[3]));
        mx = fmaxf(mx, __shfl_xor(mx, 16));
        mx = fmaxf(mx, __shfl_xor(mx, 32));
        m_i = mx;
        bf16x4 pk;
        float rsum = 0.0f;
        #pragma unroll
        for (int r = 0; r < 4; ++r) {
            float pe = fexp2(sk[r] - m_i);
            pk[r] = (__bf16)pe;
            rsum += pe;
        }
        *(bf16x4*)&Pl[16 * w + l15][4 * lq] = pk;
        bf16x4 zz;
        #pragma unroll
        for (int r = 0; r < 4; ++r) zz[r] = (__bf16)0.0f;
        *(bf16x4*)&Pl[16 * w + l15][16 + 4 * lq] = zz;
        rsum += __shfl_xor(rsum, 16);
        rsum += __shfl_xor(rsum, 32);
        l_i = rsum;
        #pragma unroll
        for (int n = 0; n < 5; ++n) {
            bf16x8 pf = *(const bf16x8*)&Pl[16 * w + l15][8 * lq];
            bf16x8 vf = *(const bf16x8*)&Vtk[16 * n + l15][8 * lq];
            o[n] = __builtin_amdgcn_mfma_f32_16x16x32_bf16(pf, vf, o[n], 0, 0, 0);
        }
    }

    // ---- main loop: window tiles only, 1 barrier/tile ----
    for (int t = 0; t < n_win; ++t) {
        const int cur = t & 1;
        const int j0 = w_tile + t * BK;
        const bool more = (t + 1 < n_win);

        if (more) {
            const int j1 = j0 + BK;
            #pragma unroll
            for (int i = 0; i < 3; ++i) {
                if (act[i]) {
                    krg[i] = *(const bf16x8*)&kbase[(size_t)j1 * (NKV * HDIM) + koff[i]];
                    vrg[i] = *(const bf16x8*)&vbase[(size_t)j1 + voff[i]];
                }
            }
        }

        // ---- S = K Q^T (swapped): 24 MFMA per wave ----
        f32x4 sacc[8];
        #pragma unroll
        for (int n = 0; n < 8; ++n) sacc[n] = (f32x4)0.0f;
        __builtin_amdgcn_s_setprio(1);
        #pragma unroll
        for (int ks = 0; ks < 3; ++ks) {
            #pragma unroll
            for (int n = 0; n < 8; ++n) {
                bf16x8 kf = *(const bf16x8*)&Ks[cur][n * 16 + l15][32 * ks + 8 * lq];
                sacc[n] = __builtin_amdgcn_mfma_f32_16x16x32_bf16(kf, qf[ks], sacc[n], 0, 0, 0);
            }
        }
        __builtin_amdgcn_s_setprio(0);

        // ---- mask: key j = j0+16n+4lq+r, q i = i0+16wsub+l15 ----
        const bool full = (j0 >= i0 - 480) && (j0 <= i0 - 128);
        if (!full) {
            const int i = i0 + 16 * wsub + l15;
            #pragma unroll
            for (int n = 0; n < 8; ++n) {
                #pragma unroll
                for (int r = 0; r < 4; ++r) {
                    int j = j0 + 16 * n + 4 * lq + r;
                    bool allowed = (j <= i) && ((j >= i - (WINDOW - 1)) || (j < SINK));
                    if (!allowed) sacc[n][r] = -1e30f;
                }
            }
        }

        // ---- online softmax (swapped): in-lane max + 2 shfl ----
        {
            float mx = sacc[0][0];
            #pragma unroll
            for (int n = 0; n < 8; ++n) {
                float a = fmaxf(fmaxf(sacc[n][0], sacc[n][1]),
                                fmaxf(sacc[n][2], sacc[n][3]));
                mx = (n == 0) ? a : fmaxf(mx, a);
            }
            mx = fmaxf(mx, __shfl_xor(mx, 16));
            mx = fmaxf(mx, __shfl_xor(mx, 32));

            float alpha_own = 1.0f;
            bool grow = (mx > m_i);
            if (grow) {
                alpha_own = fexp2(m_i - mx);
                m_i = mx;
                l_i *= alpha_own;
            }
            if (__any(grow)) {
                #pragma unroll
                for (int r = 0; r < 4; ++r) {
                    float ar = __shfl(alpha_own, 4 * lq + r);
                    #pragma unroll
                    for (int n = 0; n < 6; ++n) o[n][r] *= ar;
                }
            }
            #pragma unroll
            for (int n = 0; n < 8; ++n) {
                bf16x4 pk;
                #pragma unroll
                for (int r = 0; r < 4; ++r)
                    pk[r] = (__bf16)fexp2(sacc[n][r] - m_i);
                *(bf16x4*)&Pl[16 * w + l15][16 * n + 4 * lq] = pk;
            }
        }

        // ---- O += P V : 24 MFMA per wave (block 5 = l-accumulator) ----
        __builtin_amdgcn_s_setprio(1);
        #pragma unroll
        for (int ks = 0; ks < 4; ++ks) {
            bf16x8 pf = *(const bf16x8*)&Pl[16 * w + l15][32 * ks + 8 * lq];
            #pragma unroll
            for (int n = 0; n < 6; ++n) {
                bf16x8 vf = *(const bf16x8*)&Vt[cur][16 * n + l15][32 * ks + 8 * lq];
                o[n] = __builtin_amdgcn_mfma_f32_16x16x32_bf16(pf, vf, o[n], 0, 0, 0);
            }
        }
        __builtin_amdgcn_s_setprio(0);

        // ---- write next tile into the other buffer, then one barrier ----
        if (more) {
            #pragma unroll
            for (int i = 0; i < 3; ++i) {
                if (act[i]) {
                    *(bf16x8*)(ksdst0[i] + (cur ^ 1) * ksbuf) = krg[i];
                    *(bf16x8*)(vsdst0[i] + (cur ^ 1) * vsbuf) = vrg[i];
                }
            }
            __syncthreads();
        }
    }

    // ---- epilogue: l(row 4lq+r) = shfl(l_i) + o[5]@(l15==0) ----
    #pragma unroll
    for (int r = 0; r < 4; ++r) {
        float l_snk = __shfl(l_i, 4 * lq + r);
        float l_pv  = __shfl(o[5][r], lane & 48);
        float inv = 1.0f / (l_snk + l_pv);
        int row = i0 + 16 * wsub + 4 * lq + r;
        #pragma unroll
        for (int n = 0; n < 5; ++n)
            attnb[(size_t)row * HIDDEN + h * HDIM + 16 * n + l15] = (__bf16)(o[n][r] * inv);
    }
}

// ---------------------------------------------------------------------------
extern "C" void kernel_launch(void* const* d_in, const int* in_sizes, int n_in,
                              void* d_out, int out_size, void* d_ws, size_t ws_size,
                              hipStream_t stream)
{
    const float* x    = (const float*)d_in[0];
    const float* cosb = (const float*)d_in[1];
    const float* sinb = (const float*)d_in[2];
    const float* Wq   = (const float*)d_in[3];
    const float* Wk   = (const float*)d_in[4];
    const float* Wv   = (const float*)d_in[5];
    const float* Wo   = (const float*)d_in[6];
    const float* qw   = (const float*)d_in[7];
    const float* kw   = (const float*)d_in[8];
    float* out = (float*)d_out;

    char* ws = (char*)d_ws;
    __bf16* qkvb  = (__bf16*)ws;                                 // [4096][960]
    __bf16* xb    = qkvb + (size_t)SEQ * 960;                    // [4096][640] = attnb
    __bf16* qb    = xb   + (size_t)SEQ * HIDDEN;                 // [4096][640]
    __bf16* kb    = qb   + (size_t)SEQ * HIDDEN;                 // [4096][160]
    __bf16* vtb   = kb   + (size_t)SEQ * 160;                    // [2][80][4096]
    __bf16* WqkvT = vtb  + (size_t)2 * HDIM * SEQ;               // [1024][640]
    __bf16* WoT   = WqkvT + (size_t)1024 * HIDDEN;               // [640][640]

    prep_kernel<<<dim3(3560), dim3(256), 0, stream>>>(
        x, Wq, Wk, Wv, Wo, xb, WqkvT, WoT);

    gemm_bf16_mfma<__bf16><<<dim3(8, SEQ / 64), dim3(512), 0, stream>>>(
        xb, WqkvT, qkvb, SEQ, 960, HIDDEN, 960);

    normrope_vt_kernel<<<dim3(2688), dim3(256), 0, stream>>>(
        (const unsigned short*)qkvb, cosb, sinb, qw, kw, qb, kb,
        (unsigned short*)vtb);

    flash_attn_mfma<<<dim3(SEQ / BQG, NKV), dim3(512), 0, stream>>>(
        qb, kb, vtb, xb);

    gemm_bf16_mfma<float><<<dim3(HIDDEN / 128, SEQ / 64), dim3(512), 0, stream>>>(
        xb, WoT, out, SEQ, HIDDEN, HIDDEN, HIDDEN);
}

// Round 20
// 60.098 us; speedup vs baseline: 1.2481x; 1.0518x over previous
//
#include <hip/hip_runtime.h>
#include <hip/hip_bf16.h>
#include <stdint.h>

#define SEQ     4096
#define HIDDEN  640
#define HDIM    80
#define NH      8
#define NKV     2
#define WINDOW  512
#define SINK    4
#define BQG     32    // flash q-tile (shared by 4 heads)
#define BK      128   // flash key-tile
#define KSTR    104   // Ks row stride (bf16): 2-way banks on b128 reads
#define VSTR    136   // Vt/Pl row stride (bf16): 2-way banks (128+8)
#define VSTRK   40    // Vtk sink row stride

typedef __bf16 bf16x8 __attribute__((ext_vector_type(8)));
typedef __bf16 bf16x4 __attribute__((ext_vector_type(4)));
typedef float  f32x4  __attribute__((ext_vector_type(4)));

__device__ inline __bf16 f2bf(float f) {
    union { float f; uint32_t u; } x; x.f = f;
    uint32_t r = x.u + 0x7FFF + ((x.u >> 16) & 1);   // RNE, no NaN inputs
    union { unsigned short s; __bf16 b; } y; y.s = (unsigned short)(r >> 16);
    return y.b;
}
__device__ inline float bf2f(unsigned short u) {
    union { uint32_t u; float f; } c; c.u = ((uint32_t)u) << 16; return c.f;
}
__device__ inline float fexp2(float x) {
#if __has_builtin(__builtin_amdgcn_exp2f)
    return __builtin_amdgcn_exp2f(x);
#else
    return exp2f(x);
#endif
}

// ---------------------------------------------------------------------------
// Fused prep: x -> bf16 (blocks [0,2560)) + all weight transposes
// (blocks [2560,3560), 32x32 tiles).  (r12-proven)
// ---------------------------------------------------------------------------
__global__ __launch_bounds__(256) void prep_kernel(
    const float* __restrict__ x, const float* __restrict__ Wq,
    const float* __restrict__ Wk, const float* __restrict__ Wv,
    const float* __restrict__ Wo, __bf16* __restrict__ xb,
    __bf16* __restrict__ WqkvT, __bf16* __restrict__ WoT)
{
    const int flat = blockIdx.x;
    const int tid  = threadIdx.x;
    if (flat < 2560) {
        int i = flat * 256 + tid;
        const float4 v = *(const float4*)&x[4 * i];
        xb[4 * i + 0] = f2bf(v.x);
        xb[4 * i + 1] = f2bf(v.y);
        xb[4 * i + 2] = f2bf(v.z);
        xb[4 * i + 3] = f2bf(v.w);
        return;
    }
    const int wf = flat - 2560;
    const float* src;
    __bf16* dstb;
    int idx, tiles_x, N;
    if (wf < 400)      { src = Wq; dstb = WqkvT;             idx = wf;       tiles_x = 20; N = 640; }
    else if (wf < 500) { src = Wk; dstb = WqkvT + 640 * 640; idx = wf - 400; tiles_x = 5;  N = 160; }
    else if (wf < 600) { src = Wv; dstb = WqkvT + 800 * 640; idx = wf - 500; tiles_x = 5;  N = 160; }
    else               { src = Wo; dstb = WoT;               idx = wf - 600; tiles_x = 20; N = 640; }
    const int n0 = (idx % tiles_x) * 32;
    const int k0 = (idx / tiles_x) * 32;

    __shared__ float t[32][33];
    const int tx = tid & 31, ty = tid >> 5;     // 32 x 8
    #pragma unroll
    for (int i = 0; i < 4; ++i) {
        int r = ty + 8 * i;
        t[r][tx] = src[(size_t)(k0 + r) * N + n0 + tx];
    }
    __syncthreads();
    #pragma unroll
    for (int i = 0; i < 4; ++i) {
        int r = ty + 8 * i;
        dstb[(size_t)(n0 + r) * 640 + k0 + tx] = f2bf(t[tx][r]);
    }
}

// ---------------------------------------------------------------------------
// MFMA bf16 GEMM v3 (r19-proven): tile 64x128, 512 threads = 8 waves
// (2M x 4N), macro-step BK=64, dbuf LDS, 1 barrier/macro-step.
// Grid (ceil(N/128), M/64).
// ---------------------------------------------------------------------------
template <typename OutT>
__global__ __launch_bounds__(512) void gemm_bf16_mfma(
    const __bf16* __restrict__ A, const __bf16* __restrict__ BT,
    OutT* __restrict__ C, int M, int N, int K, int ldc)
{
    __shared__ __bf16 As[2][2][64][40];    // [h][buf]  20480 B
    __shared__ __bf16 Bs[2][2][128][40];   // [h][buf]  40960 B
    const int BUFA = 64 * 40;
    const int BUFB = 128 * 40;

    const int tid  = threadIdx.x;
    const int wave = tid >> 6;
    const int lane = tid & 63;
    const int wr = wave >> 2, wc = wave & 3;     // 2M x 4N
    const int l15 = lane & 15, lq = lane >> 4;
    const int m0 = blockIdx.y * 64, n0 = blockIdx.x * 128;

    f32x4 acc[2][2];
    #pragma unroll
    for (int m = 0; m < 2; ++m)
        #pragma unroll
        for (int n = 0; n < 2; ++n) acc[m][n] = (f32x4)0.0f;

    size_t goff[3];
    __bf16* ldst[3];
    int     bstr[3];
    {
        int r0 = tid >> 3, q0 = tid & 7, h0 = q0 >> 2, s0 = q0 & 3;
        goff[0] = (size_t)(m0 + r0) * K + h0 * 32 + 8 * s0;
        ldst[0] = &As[h0][0][r0][8 * s0];
        bstr[0] = BUFA;
        #pragma unroll
        for (int j = 1; j < 3; ++j) {
            int b  = tid + (j - 1) * 512;
            int rb = b >> 3, qb = b & 7, hb = qb >> 2, sb = qb & 3;
            goff[j] = (size_t)(n0 + rb) * K + hb * 32 + 8 * sb;
            ldst[j] = &Bs[hb][0][rb][8 * sb];
            bstr[j] = BUFB;
        }
    }
    const __bf16* gsrcs[3] = { A, BT, BT };

    const int nk = K >> 6;

    bf16x8 rg0 = *(const bf16x8*)&gsrcs[0][goff[0]];
    bf16x8 rg1 = *(const bf16x8*)&gsrcs[1][goff[1]];
    bf16x8 rg2 = *(const bf16x8*)&gsrcs[2][goff[2]];
    *(bf16x8*)ldst[0] = rg0;
    *(bf16x8*)ldst[1] = rg1;
    *(bf16x8*)ldst[2] = rg2;
    __syncthreads();

    for (int ks = 0; ks < nk; ++ks) {
        const int cur = ks & 1;
        if (ks + 1 < nk) {
            const size_t kadv = (size_t)(ks + 1) * 64;
            rg0 = *(const bf16x8*)&gsrcs[0][goff[0] + kadv];
            rg1 = *(const bf16x8*)&gsrcs[1][goff[1] + kadv];
            rg2 = *(const bf16x8*)&gsrcs[2][goff[2] + kadv];
        }

        __builtin_amdgcn_s_setprio(1);
        #pragma unroll
        for (int h = 0; h < 2; ++h) {
            bf16x8 af[2], bfr[2];
            #pragma unroll
            for (int m = 0; m < 2; ++m)
                af[m] = *(const bf16x8*)&As[h][cur][wr * 32 + m * 16 + l15][8 * lq];
            #pragma unroll
            for (int n = 0; n < 2; ++n)
                bfr[n] = *(const bf16x8*)&Bs[h][cur][wc * 32 + n * 16 + l15][8 * lq];
            #pragma unroll
            for (int m = 0; m < 2; ++m)
                #pragma unroll
                for (int n = 0; n < 2; ++n)
                    acc[m][n] = __builtin_amdgcn_mfma_f32_16x16x32_bf16(af[m], bfr[n], acc[m][n], 0, 0, 0);
        }
        __builtin_amdgcn_s_setprio(0);

        if (ks + 1 < nk) {
            *(bf16x8*)(ldst[0] + (cur ^ 1) * bstr[0]) = rg0;
            *(bf16x8*)(ldst[1] + (cur ^ 1) * bstr[1]) = rg1;
            *(bf16x8*)(ldst[2] + (cur ^ 1) * bstr[2]) = rg2;
        }
        __syncthreads();
    }

    #pragma unroll
    for (int m = 0; m < 2; ++m) {
        #pragma unroll
        for (int n = 0; n < 2; ++n) {
            const int col = n0 + wc * 32 + n * 16 + l15;
            if (col < N) {
                const int rbase = m0 + wr * 32 + m * 16 + 4 * lq;
                #pragma unroll
                for (int r = 0; r < 4; ++r) {
                    if constexpr (sizeof(OutT) == 2)
                        C[(size_t)(rbase + r) * ldc + col] = f2bf(acc[m][n][r]);
                    else
                        C[(size_t)(rbase + r) * ldc + col] = acc[m][n][r];
                }
            }
        }
    }
}

// ---------------------------------------------------------------------------
// Out-projection GEMM: tile 64x160 -> grid (4, 64) = 256 blocks = exactly
// 1 block/CU (perfect balance; the 64x128 variant left 192 CUs half-idle).
// 8 waves = 4M x 2N, wave tile 16x80 (acc[5]); macro-step BK=64, dbuf LDS
// (71.7 KB), 1 barrier/macro-step. Same k-slice order -> identical numerics.
// ---------------------------------------------------------------------------
__global__ __launch_bounds__(512) void gemm_bf16_n160(
    const __bf16* __restrict__ A, const __bf16* __restrict__ BT,
    float* __restrict__ C, int M, int K, int ldc)
{
    __shared__ __bf16 As[2][2][64][40];    // 20480 B
    __shared__ __bf16 Bs[2][2][160][40];   // 51200 B
    const int BUFA = 64 * 40;
    const int BUFB = 160 * 40;

    const int tid  = threadIdx.x;
    const int wave = tid >> 6;
    const int lane = tid & 63;
    const int wr = wave >> 1, wc = wave & 1;     // 4M x 2N
    const int l15 = lane & 15, lq = lane >> 4;
    const int m0 = blockIdx.y * 64, n0 = blockIdx.x * 160;

    f32x4 acc[5];
    #pragma unroll
    for (int n = 0; n < 5; ++n) acc[n] = (f32x4)0.0f;

    // staging: A 512 chunks + B 1280 chunks = 1792; slots j=0 (A), 1..3 (B)
    size_t goff[4];
    __bf16* ldst[4];
    int     bstr[4];
    const bool act3 = (tid < 256);               // slot 3 covers B chunks 1024..1279
    {
        int r0 = tid >> 3, q0 = tid & 7, h0 = q0 >> 2, s0 = q0 & 3;
        goff[0] = (size_t)(m0 + r0) * K + h0 * 32 + 8 * s0;
        ldst[0] = &As[h0][0][r0][8 * s0];
        bstr[0] = BUFA;
        #pragma unroll
        for (int j = 1; j < 4; ++j) {
            int b  = tid + (j - 1) * 512;
            if (j == 3 && !act3) b = 0;
            int rb = b >> 3, qb = b & 7, hb = qb >> 2, sb = qb & 3;
            goff[j] = (size_t)(n0 + rb) * K + hb * 32 + 8 * sb;
            ldst[j] = &Bs[hb][0][rb][8 * sb];
            bstr[j] = BUFB;
        }
    }
    const __bf16* gsrcs[4] = { A, BT, BT, BT };

    const int nk = K >> 6;

    bf16x8 rg0 = *(const bf16x8*)&gsrcs[0][goff[0]];
    bf16x8 rg1 = *(const bf16x8*)&gsrcs[1][goff[1]];
    bf16x8 rg2 = *(const bf16x8*)&gsrcs[2][goff[2]];
    bf16x8 rg3;
    if (act3) rg3 = *(const bf16x8*)&gsrcs[3][goff[3]];
    *(bf16x8*)ldst[0] = rg0;
    *(bf16x8*)ldst[1] = rg1;
    *(bf16x8*)ldst[2] = rg2;
    if (act3) *(bf16x8*)ldst[3] = rg3;
    __syncthreads();

    for (int ks = 0; ks < nk; ++ks) {
        const int cur = ks & 1;
        if (ks + 1 < nk) {
            const size_t kadv = (size_t)(ks + 1) * 64;
            rg0 = *(const bf16x8*)&gsrcs[0][goff[0] + kadv];
            rg1 = *(const bf16x8*)&gsrcs[1][goff[1] + kadv];
            rg2 = *(const bf16x8*)&gsrcs[2][goff[2] + kadv];
            if (act3) rg3 = *(const bf16x8*)&gsrcs[3][goff[3] + kadv];
        }

        __builtin_amdgcn_s_setprio(1);
        #pragma unroll
        for (int h = 0; h < 2; ++h) {
            bf16x8 af = *(const bf16x8*)&As[h][cur][wr * 16 + l15][8 * lq];
            #pragma unroll
            for (int n = 0; n < 5; ++n) {
                bf16x8 bfr = *(const bf16x8*)&Bs[h][cur][wc * 80 + n * 16 + l15][8 * lq];
                acc[n] = __builtin_amdgcn_mfma_f32_16x16x32_bf16(af, bfr, acc[n], 0, 0, 0);
            }
        }
        __builtin_amdgcn_s_setprio(0);

        if (ks + 1 < nk) {
            *(bf16x8*)(ldst[0] + (cur ^ 1) * bstr[0]) = rg0;
            *(bf16x8*)(ldst[1] + (cur ^ 1) * bstr[1]) = rg1;
            *(bf16x8*)(ldst[2] + (cur ^ 1) * bstr[2]) = rg2;
            if (act3) *(bf16x8*)(ldst[3] + (cur ^ 1) * bstr[3]) = rg3;
        }
        __syncthreads();
    }

    #pragma unroll
    for (int n = 0; n < 5; ++n) {
        const int col = n0 + wc * 80 + n * 16 + l15;
        const int rbase = m0 + wr * 16 + 4 * lq;
        #pragma unroll
        for (int r = 0; r < 4; ++r)
            C[(size_t)(rbase + r) * ldc + col] = acc[n][r];
    }
}

// ---------------------------------------------------------------------------
// Fused RMSNorm+RoPE v2 (vectorized, r18-proven) + V-transpose.
// ---------------------------------------------------------------------------
__global__ __launch_bounds__(256) void normrope_vt_kernel(
    const unsigned short* __restrict__ qkvb, const float* __restrict__ cosb,
    const float* __restrict__ sinb, const float* __restrict__ qw,
    const float* __restrict__ kw, __bf16* __restrict__ qb,
    __bf16* __restrict__ kb, unsigned short* __restrict__ vtb)
{
    const int flat = blockIdx.x;
    const int tid  = threadIdx.x;

    __shared__ float partial[2][100];
    __shared__ float red[2][10];
    __shared__ unsigned short t[32][33];

    if (flat < 2048) {
        const int half = tid >> 7;           // 0..1 -> row of the pair
        const int lt   = tid & 127;
        const int row  = flat * 2 + half;
        const int head = lt / 10;            // 0..9 (lt<100)
        const int c10  = lt - head * 10;     // chunk within head

        float v[8];
        if (lt < 100) {
            const unsigned short* p = qkvb + (size_t)row * 960 + 8 * lt;
            bf16x8 raw = *(const bf16x8*)p;
            #pragma unroll
            for (int j = 0; j < 8; ++j) v[j] = bf2f(((unsigned short*)&raw)[j]);
            float sq = 0.0f;
            #pragma unroll
            for (int j = 0; j < 8; ++j) sq += v[j] * v[j];
            partial[half][lt] = sq;
        }
        __syncthreads();

        if (lt < 10) {
            float s = 0.0f;
            #pragma unroll
            for (int c = 0; c < 10; ++c) s += partial[half][10 * lt + c];
            red[half][lt] = s;
        }
        __syncthreads();

        if (lt < 100) {
            const float rms = rsqrtf(red[half][head] * (1.0f / HDIM) + 1e-5f);
            const bool  isq = (head < NH);
            const float outscale = isq ? (0.11180339887498948f * 1.4426950408889634f) : 1.0f;

            const float* wsrc = isq ? qw : kw;
            float4 w0 = *(const float4*)&wsrc[8 * c10];
            float4 w1 = *(const float4*)&wsrc[8 * c10 + 4];
            float4 cc = *(const float4*)&cosb[(size_t)row * 40 + 4 * c10];
            float4 ss = *(const float4*)&sinb[(size_t)row * 40 + 4 * c10];

            float wv[8] = { w0.x, w0.y, w0.z, w0.w, w1.x, w1.y, w1.z, w1.w };
            float cv[4] = { cc.x, cc.y, cc.z, cc.w };
            float sv[4] = { ss.x, ss.y, ss.z, ss.w };

            bf16x8 outp;
            #pragma unroll
            for (int j = 0; j < 4; ++j) {
                float ve = v[2 * j]     * rms * wv[2 * j];
                float vo = v[2 * j + 1] * rms * wv[2 * j + 1];
                float re = (ve * cv[j] - vo * sv[j]) * outscale;
                float ro = (vo * cv[j] + ve * sv[j]) * outscale;
                outp[2 * j]     = (__bf16)re;
                outp[2 * j + 1] = (__bf16)ro;
            }
            if (isq) {
                *(bf16x8*)&qb[(size_t)row * HIDDEN + 8 * lt] = outp;
            } else {
                *(bf16x8*)&kb[(size_t)row * (NKV * HDIM) + 8 * lt - HIDDEN] = outp;
            }
        }
        return;
    }

    // ---- V transpose: vtb[kvh][d][seq] ----
    const int idx = flat - 2048;             // 0..639
    const int s0 = (idx & 127) * 32;
    const int c0 = (idx >> 7) * 32;
    const int tx = tid & 31, ty = tid >> 5;  // 32 x 8
    #pragma unroll
    for (int i = 0; i < 4; ++i)
        t[ty + 8 * i][tx] = qkvb[(size_t)(s0 + ty + 8 * i) * 960 + 800 + c0 + tx];
    __syncthreads();
    #pragma unroll
    for (int i = 0; i < 4; ++i) {
        int g = c0 + ty + 8 * i;             // 0..159
        int kvh = g / HDIM, d = g % HDIM;
        vtb[((size_t)kvh * HDIM + d) * SEQ + s0 + tx] = t[tx][ty + 8 * i];
    }
}

// ---------------------------------------------------------------------------
// GQA-fused MFMA flash attention (r17-19-proven, swapped S-operands) with
// ones-fragment hoisted to a register: the l-accumulator's B-operand is
// constant (l15==0 -> ones, else zeros), so Vt rows 80..95 and their init
// are removed (-8.7 KB LDS, -4 LDS reads/lane/tile). LDS ~141 KB.
// ---------------------------------------------------------------------------
__global__ __launch_bounds__(512) void flash_attn_mfma(
    const __bf16* __restrict__ qb, const __bf16* __restrict__ kb,
    const __bf16* __restrict__ vtb, __bf16* __restrict__ attnb)
{
    const int i0   = blockIdx.x * BQG;
    const int kvh  = blockIdx.y;
    const int tid  = threadIdx.x;        // 0..511
    const int w    = tid >> 6;           // 0..7
    const int h    = kvh * 4 + (w >> 1);
    const int wsub = w & 1;
    const int lane = tid & 63;
    const int l15  = lane & 15;
    const int lq   = lane >> 4;

    __shared__ __bf16 Ks[2][BK][KSTR];   // 53248 B
    __shared__ __bf16 Vt[2][HDIM][VSTR]; // 43520 B
    __shared__ __bf16 Pl[128][VSTR];     // 34816 B
    __shared__ __bf16 Ksk[16][KSTR];     //  3328 B (sink K, keys 0..15)
    __shared__ __bf16 Vtk[HDIM][VSTRK];  //  6400 B (sink V, keys 0..31)

    // zero K pad columns 80..95 of BOTH buffers
    {
        int b = tid >> 8, r = (tid >> 1) & 127, c = HDIM + 8 * (tid & 1);
        *(float4*)&Ks[b][r][c] = make_float4(0.f, 0.f, 0.f, 0.f);
    }

    // constant ones-fragment for the l-accumulator (replaces Vt rows 80..95)
    bf16x8 vones;
    #pragma unroll
    for (int j = 0; j < 8; ++j) vones[j] = (l15 == 0) ? (__bf16)1.0f : (__bf16)0.0f;

    // window staging maps: 1280 chunks of 8 bf16 each (chunk = tid + 512*i)
    int koff[3], voff[3];
    __bf16* ksdst0[3];
    __bf16* vsdst0[3];
    bool act[3];
    #pragma unroll
    for (int i = 0; i < 3; ++i) {
        int c = tid + 512 * i;
        act[i] = (c < 1280);
        int cc = act[i] ? c : 0;
        koff[i] = (cc / 10) * (NKV * HDIM) + 8 * (cc % 10);
        voff[i] = (cc >> 4) * SEQ + 8 * (cc & 15);
        ksdst0[i] = &Ks[0][cc / 10][8 * (cc % 10)];
        vsdst0[i] = &Vt[0][cc >> 4][8 * (cc & 15)];
    }
    const size_t ksbuf = (size_t)BK * KSTR;
    const size_t vsbuf = (size_t)HDIM * VSTR;
    const __bf16* kbase = kb + kvh * HDIM;
    const __bf16* vbase = vtb + (size_t)kvh * HDIM * SEQ;

    // preload Q A-fragments (q-row i0 + 16*wsub + l15)
    bf16x8 qf[3];
    {
        const __bf16* qrow = qb + (size_t)(i0 + 16 * wsub + l15) * HIDDEN + h * HDIM;
        #pragma unroll
        for (int ks = 0; ks < 3; ++ks) {
            int off = 32 * ks + 8 * lq;
            if (off >= HDIM) off = 0;     // dummy: multiplied by zeroed K pad
            qf[ks] = *(const bf16x8*)&qrow[off];
        }
    }

    float m_i = -1e30f, l_i = 0.0f;       // per-lane: q-row i0+16*wsub+l15
    f32x4 o[6];                           // o[5] = P row-sum accumulator
    #pragma unroll
    for (int n = 0; n < 6; ++n) o[n] = (f32x4)0.0f;

    const int w_lo   = i0 - (WINDOW - 1);
    const int w_tile = (w_lo <= 0) ? 0 : (w_lo & ~(BK - 1));
    const int lastt  = (i0 + BQG - 1) & ~(BK - 1);
    const int n_win  = (lastt - w_tile) / BK + 1;
    const bool has_sink = (w_tile > 0);   // sinks disjoint from window

    // ---- prologue: stage tile 0 + sink K/V, one barrier ----
    bf16x8 krg[3], vrg[3];
    #pragma unroll
    for (int i = 0; i < 3; ++i) {
        if (act[i]) {
            krg[i] = *(const bf16x8*)&kbase[(size_t)w_tile * (NKV * HDIM) + koff[i]];
            vrg[i] = *(const bf16x8*)&vbase[(size_t)w_tile + voff[i]];
        }
    }
    if (has_sink) {
        if (tid < 160) {                 // Ksk: 16 rows x 10 chunks
            int r = tid / 10, c8 = tid % 10;
            *(bf16x8*)&Ksk[r][8 * c8] =
                *(const bf16x8*)&kbase[(size_t)r * (NKV * HDIM) + 8 * c8];
        } else if (tid < 192) {          // Ksk pad cols 80..95
            int r = (tid - 160) >> 1, c = HDIM + 8 * (tid & 1);
            *(float4*)&Ksk[r][c] = make_float4(0.f, 0.f, 0.f, 0.f);
        } else if (tid < 512) {          // Vtk: 80 rows x 4 chunks
            int c = tid - 192;           // 0..319
            *(bf16x8*)&Vtk[c >> 2][8 * (c & 3)] =
                *(const bf16x8*)&vbase[(size_t)(c >> 2) * SEQ + 8 * (c & 3)];
        }
    }
    #pragma unroll
    for (int i = 0; i < 3; ++i) {
        if (act[i]) {
            *(bf16x8*)ksdst0[i] = krg[i];
            *(bf16x8*)vsdst0[i] = vrg[i];
        }
    }
    __syncthreads();

    // ---- sink prepass (swapped): keys = 4lq+r, q-row = l15 ----
    if (has_sink) {
        f32x4 sk = (f32x4)0.0f;
        #pragma unroll
        for (int ks = 0; ks < 3; ++ks) {
            bf16x8 kf = *(const bf16x8*)&Ksk[l15][32 * ks + 8 * lq];
            sk = __builtin_amdgcn_mfma_f32_16x16x32_bf16(kf, qf[ks], sk, 0, 0, 0);
        }
        if (lq != 0) {
            #pragma unroll
            for (int r = 0; r < 4; ++r) sk[r] = -1e30f;
        }
        float mx = fmaxf(fmaxf(sk[0], sk[1]), fmaxf(sk[2], sk[3]));
        mx = fmaxf(mx, __shfl_xor(mx, 16));
        mx = fmaxf(mx, __shfl_xor(mx, 32));
        m_i = mx;
        bf16x4 pk;
        float rsum = 0.0f;
        #pragma unroll
        for (int r = 0; r < 4; ++r) {
            float pe = fexp2(sk[r] - m_i);
            pk[r] = (__bf16)pe;
            rsum += pe;
        }
        *(bf16x4*)&Pl[16 * w + l15][4 * lq] = pk;
        bf16x4 zz;
        #pragma unroll
        for (int r = 0; r < 4; ++r) zz[r] = (__bf16)0.0f;
        *(bf16x4*)&Pl[16 * w + l15][16 + 4 * lq] = zz;
        rsum += __shfl_xor(rsum, 16);
        rsum += __shfl_xor(rsum, 32);
        l_i = rsum;
        #pragma unroll
        for (int n = 0; n < 5; ++n) {
            bf16x8 pf = *(const bf16x8*)&Pl[16 * w + l15][8 * lq];
            bf16x8 vf = *(const bf16x8*)&Vtk[16 * n + l15][8 * lq];
            o[n] = __builtin_amdgcn_mfma_f32_16x16x32_bf16(pf, vf, o[n], 0, 0, 0);
        }
    }

    // ---- main loop: window tiles only, 1 barrier/tile ----
    for (int t = 0; t < n_win; ++t) {
        const int cur = t & 1;
        const int j0 = w_tile + t * BK;
        const bool more = (t + 1 < n_win);

        if (more) {
            const int j1 = j0 + BK;
            #pragma unroll
            for (int i = 0; i < 3; ++i) {
                if (act[i]) {
                    krg[i] = *(const bf16x8*)&kbase[(size_t)j1 * (NKV * HDIM) + koff[i]];
                    vrg[i] = *(const bf16x8*)&vbase[(size_t)j1 + voff[i]];
                }
            }
        }

        // ---- S = K Q^T (swapped): 24 MFMA per wave ----
        f32x4 sacc[8];
        #pragma unroll
        for (int n = 0; n < 8; ++n) sacc[n] = (f32x4)0.0f;
        __builtin_amdgcn_s_setprio(1);
        #pragma unroll
        for (int ks = 0; ks < 3; ++ks) {
            #pragma unroll
            for (int n = 0; n < 8; ++n) {
                bf16x8 kf = *(const bf16x8*)&Ks[cur][n * 16 + l15][32 * ks + 8 * lq];
                sacc[n] = __builtin_amdgcn_mfma_f32_16x16x32_bf16(kf, qf[ks], sacc[n], 0, 0, 0);
            }
        }
        __builtin_amdgcn_s_setprio(0);

        // ---- mask: key j = j0+16n+4lq+r, q i = i0+16wsub+l15 ----
        const bool full = (j0 >= i0 - 480) && (j0 <= i0 - 128);
        if (!full) {
            const int i = i0 + 16 * wsub + l15;
            #pragma unroll
            for (int n = 0; n < 8; ++n) {
                #pragma unroll
                for (int r = 0; r < 4; ++r) {
                    int j = j0 + 16 * n + 4 * lq + r;
                    bool allowed = (j <= i) && ((j >= i - (WINDOW - 1)) || (j < SINK));
                    if (!allowed) sacc[n][r] = -1e30f;
                }
            }
        }

        // ---- online softmax (swapped): in-lane max + 2 shfl ----
        {
            float mx = sacc[0][0];
            #pragma unroll
            for (int n = 0; n < 8; ++n) {
                float a = fmaxf(fmaxf(sacc[n][0], sacc[n][1]),
                                fmaxf(sacc[n][2], sacc[n][3]));
                mx = (n == 0) ? a : fmaxf(mx, a);
            }
            mx = fmaxf(mx, __shfl_xor(mx, 16));
            mx = fmaxf(mx, __shfl_xor(mx, 32));

            float alpha_own = 1.0f;
            bool grow = (mx > m_i);
            if (grow) {
                alpha_own = fexp2(m_i - mx);
                m_i = mx;
                l_i *= alpha_own;
            }
            if (__any(grow)) {
                #pragma unroll
                for (int r = 0; r < 4; ++r) {
                    float ar = __shfl(alpha_own, 4 * lq + r);
                    #pragma unroll
                    for (int n = 0; n < 6; ++n) o[n][r] *= ar;
                }
            }
            #pragma unroll
            for (int n = 0; n < 8; ++n) {
                bf16x4 pk;
                #pragma unroll
                for (int r = 0; r < 4; ++r)
                    pk[r] = (__bf16)fexp2(sacc[n][r] - m_i);
                *(bf16x4*)&Pl[16 * w + l15][16 * n + 4 * lq] = pk;
            }
        }

        // ---- O += P V : 20 MFMA + 4 l-accum MFMA per wave ----
        __builtin_amdgcn_s_setprio(1);
        #pragma unroll
        for (int ks = 0; ks < 4; ++ks) {
            bf16x8 pf = *(const bf16x8*)&Pl[16 * w + l15][32 * ks + 8 * lq];
            #pragma unroll
            for (int n = 0; n < 5; ++n) {
                bf16x8 vf = *(const bf16x8*)&Vt[cur][16 * n + l15][32 * ks + 8 * lq];
                o[n] = __builtin_amdgcn_mfma_f32_16x16x32_bf16(pf, vf, o[n], 0, 0, 0);
            }
            o[5] = __builtin_amdgcn_mfma_f32_16x16x32_bf16(pf, vones, o[5], 0, 0, 0);
        }
        __builtin_amdgcn_s_setprio(0);

        // ---- write next tile into the other buffer, then one barrier ----
        if (more) {
            #pragma unroll
            for (int i = 0; i < 3; ++i) {
                if (act[i]) {
                    *(bf16x8*)(ksdst0[i] + (cur ^ 1) * ksbuf) = krg[i];
                    *(bf16x8*)(vsdst0[i] + (cur ^ 1) * vsbuf) = vrg[i];
                }
            }
            __syncthreads();
        }
    }

    // ---- epilogue: l(row 4lq+r) = shfl(l_i) + o[5]@(l15==0) ----
    #pragma unroll
    for (int r = 0; r < 4; ++r) {
        float l_snk = __shfl(l_i, 4 * lq + r);
        float l_pv  = __shfl(o[5][r], lane & 48);
        float inv = 1.0f / (l_snk + l_pv);
        int row = i0 + 16 * wsub + 4 * lq + r;
        #pragma unroll
        for (int n = 0; n < 5; ++n)
            attnb[(size_t)row * HIDDEN + h * HDIM + 16 * n + l15] = (__bf16)(o[n][r] * inv);
    }
}

// ---------------------------------------------------------------------------
extern "C" void kernel_launch(void* const* d_in, const int* in_sizes, int n_in,
                              void* d_out, int out_size, void* d_ws, size_t ws_size,
                              hipStream_t stream)
{
    const float* x    = (const float*)d_in[0];
    const float* cosb = (const float*)d_in[1];
    const float* sinb = (const float*)d_in[2];
    const float* Wq   = (const float*)d_in[3];
    const float* Wk   = (const float*)d_in[4];
    const float* Wv   = (const float*)d_in[5];
    const float* Wo   = (const float*)d_in[6];
    const float* qw   = (const float*)d_in[7];
    const float* kw   = (const float*)d_in[8];
    float* out = (float*)d_out;

    char* ws = (char*)d_ws;
    __bf16* qkvb  = (__bf16*)ws;                                 // [4096][960]
    __bf16* xb    = qkvb + (size_t)SEQ * 960;                    // [4096][640] = attnb
    __bf16* qb    = xb   + (size_t)SEQ * HIDDEN;                 // [4096][640]
    __bf16* kb    = qb   + (size_t)SEQ * HIDDEN;                 // [4096][160]
    __bf16* vtb   = kb   + (size_t)SEQ * 160;                    // [2][80][4096]
    __bf16* WqkvT = vtb  + (size_t)2 * HDIM * SEQ;               // [1024][640]
    __bf16* WoT   = WqkvT + (size_t)1024 * HIDDEN;               // [640][640]

    prep_kernel<<<dim3(3560), dim3(256), 0, stream>>>(
        x, Wq, Wk, Wv, Wo, xb, WqkvT, WoT);

    gemm_bf16_mfma<__bf16><<<dim3(8, SEQ / 64), dim3(512), 0, stream>>>(
        xb, WqkvT, qkvb, SEQ, 960, HIDDEN, 960);

    normrope_vt_kernel<<<dim3(2688), dim3(256), 0, stream>>>(
        (const unsigned short*)qkvb, cosb, sinb, qw, kw, qb, kb,
        (unsigned short*)vtb);

    flash_attn_mfma<<<dim3(SEQ / BQG, NKV), dim3(512), 0, stream>>>(
        qb, kb, vtb, xb);

    gemm_bf16_n160<<<dim3(HIDDEN / 160, SEQ / 64), dim3(512), 0, stream>>>(
        xb, WoT, out, SEQ, HIDDEN, HIDDEN);
}

// Round 21
// 59.638 us; speedup vs baseline: 1.2577x; 1.0077x over previous
//
#include <hip/hip_runtime.h>
#include <hip/hip_bf16.h>
#include <stdint.h>

#define SEQ     4096
#define HIDDEN  640
#define HDIM    80
#define NH      8
#define NKV     2
#define WINDOW  512
#define SINK    4
#define BQG     32    // flash q-tile (shared by 4 heads)
#define BK      128   // flash key-tile
#define KSTR    104   // Ks row stride (bf16): 2-way banks on b128 reads
#define VSTR    136   // Vt/Pl row stride (bf16): 2-way banks (128+8)
#define VSTRK   40    // Vtk sink row stride

typedef __bf16 bf16x8 __attribute__((ext_vector_type(8)));
typedef __bf16 bf16x4 __attribute__((ext_vector_type(4)));
typedef float  f32x4  __attribute__((ext_vector_type(4)));

__device__ inline __bf16 f2bf(float f) {
    union { float f; uint32_t u; } x; x.f = f;
    uint32_t r = x.u + 0x7FFF + ((x.u >> 16) & 1);   // RNE, no NaN inputs
    union { unsigned short s; __bf16 b; } y; y.s = (unsigned short)(r >> 16);
    return y.b;
}
__device__ inline float bf2f(unsigned short u) {
    union { uint32_t u; float f; } c; c.u = ((uint32_t)u) << 16; return c.f;
}
__device__ inline float fexp2(float x) {
#if __has_builtin(__builtin_amdgcn_exp2f)
    return __builtin_amdgcn_exp2f(x);
#else
    return exp2f(x);
#endif
}

// ---------------------------------------------------------------------------
// Fused prep: x -> bf16 (blocks [0,2560)) + all weight transposes
// (blocks [2560,3560), 32x32 tiles).  (r12-proven)
// ---------------------------------------------------------------------------
__global__ __launch_bounds__(256) void prep_kernel(
    const float* __restrict__ x, const float* __restrict__ Wq,
    const float* __restrict__ Wk, const float* __restrict__ Wv,
    const float* __restrict__ Wo, __bf16* __restrict__ xb,
    __bf16* __restrict__ WqkvT, __bf16* __restrict__ WoT)
{
    const int flat = blockIdx.x;
    const int tid  = threadIdx.x;
    if (flat < 2560) {
        int i = flat * 256 + tid;
        const float4 v = *(const float4*)&x[4 * i];
        xb[4 * i + 0] = f2bf(v.x);
        xb[4 * i + 1] = f2bf(v.y);
        xb[4 * i + 2] = f2bf(v.z);
        xb[4 * i + 3] = f2bf(v.w);
        return;
    }
    const int wf = flat - 2560;
    const float* src;
    __bf16* dstb;
    int idx, tiles_x, N;
    if (wf < 400)      { src = Wq; dstb = WqkvT;             idx = wf;       tiles_x = 20; N = 640; }
    else if (wf < 500) { src = Wk; dstb = WqkvT + 640 * 640; idx = wf - 400; tiles_x = 5;  N = 160; }
    else if (wf < 600) { src = Wv; dstb = WqkvT + 800 * 640; idx = wf - 500; tiles_x = 5;  N = 160; }
    else               { src = Wo; dstb = WoT;               idx = wf - 600; tiles_x = 20; N = 640; }
    const int n0 = (idx % tiles_x) * 32;
    const int k0 = (idx / tiles_x) * 32;

    __shared__ float t[32][33];
    const int tx = tid & 31, ty = tid >> 5;     // 32 x 8
    #pragma unroll
    for (int i = 0; i < 4; ++i) {
        int r = ty + 8 * i;
        t[r][tx] = src[(size_t)(k0 + r) * N + n0 + tx];
    }
    __syncthreads();
    #pragma unroll
    for (int i = 0; i < 4; ++i) {
        int r = ty + 8 * i;
        dstb[(size_t)(n0 + r) * 640 + k0 + tx] = f2bf(t[tx][r]);
    }
}

// ---------------------------------------------------------------------------
// MFMA bf16 GEMM v3 (r19-proven math) with XCD-friendly grid: grid is now
// (M/64, ceil(N/128)) so the 8 n-blocks sharing one A-panel have flat IDs
// m + 64*n == m (mod 8) -> SAME XCD -> A-panel re-reads hit that XCD's L2
// (was spread over 8 XCDs). B panels (1.2 MB total) fit each L2.
// ---------------------------------------------------------------------------
template <typename OutT>
__global__ __launch_bounds__(512) void gemm_bf16_mfma(
    const __bf16* __restrict__ A, const __bf16* __restrict__ BT,
    OutT* __restrict__ C, int M, int N, int K, int ldc)
{
    __shared__ __bf16 As[2][2][64][40];    // [h][buf]  20480 B
    __shared__ __bf16 Bs[2][2][128][40];   // [h][buf]  40960 B
    const int BUFA = 64 * 40;
    const int BUFB = 128 * 40;

    const int tid  = threadIdx.x;
    const int wave = tid >> 6;
    const int lane = tid & 63;
    const int wr = wave >> 2, wc = wave & 3;     // 2M x 4N
    const int l15 = lane & 15, lq = lane >> 4;
    const int m0 = blockIdx.x * 64, n0 = blockIdx.y * 128;   // swapped roles

    f32x4 acc[2][2];
    #pragma unroll
    for (int m = 0; m < 2; ++m)
        #pragma unroll
        for (int n = 0; n < 2; ++n) acc[m][n] = (f32x4)0.0f;

    size_t goff[3];
    __bf16* ldst[3];
    int     bstr[3];
    {
        int r0 = tid >> 3, q0 = tid & 7, h0 = q0 >> 2, s0 = q0 & 3;
        goff[0] = (size_t)(m0 + r0) * K + h0 * 32 + 8 * s0;
        ldst[0] = &As[h0][0][r0][8 * s0];
        bstr[0] = BUFA;
        #pragma unroll
        for (int j = 1; j < 3; ++j) {
            int b  = tid + (j - 1) * 512;
            int rb = b >> 3, qb = b & 7, hb = qb >> 2, sb = qb & 3;
            goff[j] = (size_t)(n0 + rb) * K + hb * 32 + 8 * sb;
            ldst[j] = &Bs[hb][0][rb][8 * sb];
            bstr[j] = BUFB;
        }
    }
    const __bf16* gsrcs[3] = { A, BT, BT };

    const int nk = K >> 6;

    bf16x8 rg0 = *(const bf16x8*)&gsrcs[0][goff[0]];
    bf16x8 rg1 = *(const bf16x8*)&gsrcs[1][goff[1]];
    bf16x8 rg2 = *(const bf16x8*)&gsrcs[2][goff[2]];
    *(bf16x8*)ldst[0] = rg0;
    *(bf16x8*)ldst[1] = rg1;
    *(bf16x8*)ldst[2] = rg2;
    __syncthreads();

    for (int ks = 0; ks < nk; ++ks) {
        const int cur = ks & 1;
        if (ks + 1 < nk) {
            const size_t kadv = (size_t)(ks + 1) * 64;
            rg0 = *(const bf16x8*)&gsrcs[0][goff[0] + kadv];
            rg1 = *(const bf16x8*)&gsrcs[1][goff[1] + kadv];
            rg2 = *(const bf16x8*)&gsrcs[2][goff[2] + kadv];
        }

        __builtin_amdgcn_s_setprio(1);
        #pragma unroll
        for (int h = 0; h < 2; ++h) {
            bf16x8 af[2], bfr[2];
            #pragma unroll
            for (int m = 0; m < 2; ++m)
                af[m] = *(const bf16x8*)&As[h][cur][wr * 32 + m * 16 + l15][8 * lq];
            #pragma unroll
            for (int n = 0; n < 2; ++n)
                bfr[n] = *(const bf16x8*)&Bs[h][cur][wc * 32 + n * 16 + l15][8 * lq];
            #pragma unroll
            for (int m = 0; m < 2; ++m)
                #pragma unroll
                for (int n = 0; n < 2; ++n)
                    acc[m][n] = __builtin_amdgcn_mfma_f32_16x16x32_bf16(af[m], bfr[n], acc[m][n], 0, 0, 0);
        }
        __builtin_amdgcn_s_setprio(0);

        if (ks + 1 < nk) {
            *(bf16x8*)(ldst[0] + (cur ^ 1) * bstr[0]) = rg0;
            *(bf16x8*)(ldst[1] + (cur ^ 1) * bstr[1]) = rg1;
            *(bf16x8*)(ldst[2] + (cur ^ 1) * bstr[2]) = rg2;
        }
        __syncthreads();
    }

    #pragma unroll
    for (int m = 0; m < 2; ++m) {
        #pragma unroll
        for (int n = 0; n < 2; ++n) {
            const int col = n0 + wc * 32 + n * 16 + l15;
            if (col < N) {
                const int rbase = m0 + wr * 32 + m * 16 + 4 * lq;
                #pragma unroll
                for (int r = 0; r < 4; ++r) {
                    if constexpr (sizeof(OutT) == 2)
                        C[(size_t)(rbase + r) * ldc + col] = f2bf(acc[m][n][r]);
                    else
                        C[(size_t)(rbase + r) * ldc + col] = acc[m][n][r];
                }
            }
        }
    }
}

// ---------------------------------------------------------------------------
// Out-projection GEMM 64x160 (r20-proven math), grid swapped to (M/64, 4)
// for same-XCD A-panel reuse.
// ---------------------------------------------------------------------------
__global__ __launch_bounds__(512) void gemm_bf16_n160(
    const __bf16* __restrict__ A, const __bf16* __restrict__ BT,
    float* __restrict__ C, int M, int K, int ldc)
{
    __shared__ __bf16 As[2][2][64][40];    // 20480 B
    __shared__ __bf16 Bs[2][2][160][40];   // 51200 B
    const int BUFA = 64 * 40;
    const int BUFB = 160 * 40;

    const int tid  = threadIdx.x;
    const int wave = tid >> 6;
    const int lane = tid & 63;
    const int wr = wave >> 1, wc = wave & 1;     // 4M x 2N
    const int l15 = lane & 15, lq = lane >> 4;
    const int m0 = blockIdx.x * 64, n0 = blockIdx.y * 160;   // swapped roles

    f32x4 acc[5];
    #pragma unroll
    for (int n = 0; n < 5; ++n) acc[n] = (f32x4)0.0f;

    size_t goff[4];
    __bf16* ldst[4];
    int     bstr[4];
    const bool act3 = (tid < 256);
    {
        int r0 = tid >> 3, q0 = tid & 7, h0 = q0 >> 2, s0 = q0 & 3;
        goff[0] = (size_t)(m0 + r0) * K + h0 * 32 + 8 * s0;
        ldst[0] = &As[h0][0][r0][8 * s0];
        bstr[0] = BUFA;
        #pragma unroll
        for (int j = 1; j < 4; ++j) {
            int b  = tid + (j - 1) * 512;
            if (j == 3 && !act3) b = 0;
            int rb = b >> 3, qb = b & 7, hb = qb >> 2, sb = qb & 3;
            goff[j] = (size_t)(n0 + rb) * K + hb * 32 + 8 * sb;
            ldst[j] = &Bs[hb][0][rb][8 * sb];
            bstr[j] = BUFB;
        }
    }
    const __bf16* gsrcs[4] = { A, BT, BT, BT };

    const int nk = K >> 6;

    bf16x8 rg0 = *(const bf16x8*)&gsrcs[0][goff[0]];
    bf16x8 rg1 = *(const bf16x8*)&gsrcs[1][goff[1]];
    bf16x8 rg2 = *(const bf16x8*)&gsrcs[2][goff[2]];
    bf16x8 rg3;
    if (act3) rg3 = *(const bf16x8*)&gsrcs[3][goff[3]];
    *(bf16x8*)ldst[0] = rg0;
    *(bf16x8*)ldst[1] = rg1;
    *(bf16x8*)ldst[2] = rg2;
    if (act3) *(bf16x8*)ldst[3] = rg3;
    __syncthreads();

    for (int ks = 0; ks < nk; ++ks) {
        const int cur = ks & 1;
        if (ks + 1 < nk) {
            const size_t kadv = (size_t)(ks + 1) * 64;
            rg0 = *(const bf16x8*)&gsrcs[0][goff[0] + kadv];
            rg1 = *(const bf16x8*)&gsrcs[1][goff[1] + kadv];
            rg2 = *(const bf16x8*)&gsrcs[2][goff[2] + kadv];
            if (act3) rg3 = *(const bf16x8*)&gsrcs[3][goff[3] + kadv];
        }

        __builtin_amdgcn_s_setprio(1);
        #pragma unroll
        for (int h = 0; h < 2; ++h) {
            bf16x8 af = *(const bf16x8*)&As[h][cur][wr * 16 + l15][8 * lq];
            #pragma unroll
            for (int n = 0; n < 5; ++n) {
                bf16x8 bfr = *(const bf16x8*)&Bs[h][cur][wc * 80 + n * 16 + l15][8 * lq];
                acc[n] = __builtin_amdgcn_mfma_f32_16x16x32_bf16(af, bfr, acc[n], 0, 0, 0);
            }
        }
        __builtin_amdgcn_s_setprio(0);

        if (ks + 1 < nk) {
            *(bf16x8*)(ldst[0] + (cur ^ 1) * bstr[0]) = rg0;
            *(bf16x8*)(ldst[1] + (cur ^ 1) * bstr[1]) = rg1;
            *(bf16x8*)(ldst[2] + (cur ^ 1) * bstr[2]) = rg2;
            if (act3) *(bf16x8*)(ldst[3] + (cur ^ 1) * bstr[3]) = rg3;
        }
        __syncthreads();
    }

    #pragma unroll
    for (int n = 0; n < 5; ++n) {
        const int col = n0 + wc * 80 + n * 16 + l15;
        const int rbase = m0 + wr * 16 + 4 * lq;
        #pragma unroll
        for (int r = 0; r < 4; ++r)
            C[(size_t)(rbase + r) * ldc + col] = acc[n][r];
    }
}

// ---------------------------------------------------------------------------
// Fused RMSNorm+RoPE v2 (vectorized, r18-proven) + V-transpose.
// ---------------------------------------------------------------------------
__global__ __launch_bounds__(256) void normrope_vt_kernel(
    const unsigned short* __restrict__ qkvb, const float* __restrict__ cosb,
    const float* __restrict__ sinb, const float* __restrict__ qw,
    const float* __restrict__ kw, __bf16* __restrict__ qb,
    __bf16* __restrict__ kb, unsigned short* __restrict__ vtb)
{
    const int flat = blockIdx.x;
    const int tid  = threadIdx.x;

    __shared__ float partial[2][100];
    __shared__ float red[2][10];
    __shared__ unsigned short t[32][33];

    if (flat < 2048) {
        const int half = tid >> 7;           // 0..1 -> row of the pair
        const int lt   = tid & 127;
        const int row  = flat * 2 + half;
        const int head = lt / 10;            // 0..9 (lt<100)
        const int c10  = lt - head * 10;     // chunk within head

        float v[8];
        if (lt < 100) {
            const unsigned short* p = qkvb + (size_t)row * 960 + 8 * lt;
            bf16x8 raw = *(const bf16x8*)p;
            #pragma unroll
            for (int j = 0; j < 8; ++j) v[j] = bf2f(((unsigned short*)&raw)[j]);
            float sq = 0.0f;
            #pragma unroll
            for (int j = 0; j < 8; ++j) sq += v[j] * v[j];
            partial[half][lt] = sq;
        }
        __syncthreads();

        if (lt < 10) {
            float s = 0.0f;
            #pragma unroll
            for (int c = 0; c < 10; ++c) s += partial[half][10 * lt + c];
            red[half][lt] = s;
        }
        __syncthreads();

        if (lt < 100) {
            const float rms = rsqrtf(red[half][head] * (1.0f / HDIM) + 1e-5f);
            const bool  isq = (head < NH);
            const float outscale = isq ? (0.11180339887498948f * 1.4426950408889634f) : 1.0f;

            const float* wsrc = isq ? qw : kw;
            float4 w0 = *(const float4*)&wsrc[8 * c10];
            float4 w1 = *(const float4*)&wsrc[8 * c10 + 4];
            float4 cc = *(const float4*)&cosb[(size_t)row * 40 + 4 * c10];
            float4 ss = *(const float4*)&sinb[(size_t)row * 40 + 4 * c10];

            float wv[8] = { w0.x, w0.y, w0.z, w0.w, w1.x, w1.y, w1.z, w1.w };
            float cv[4] = { cc.x, cc.y, cc.z, cc.w };
            float sv[4] = { ss.x, ss.y, ss.z, ss.w };

            bf16x8 outp;
            #pragma unroll
            for (int j = 0; j < 4; ++j) {
                float ve = v[2 * j]     * rms * wv[2 * j];
                float vo = v[2 * j + 1] * rms * wv[2 * j + 1];
                float re = (ve * cv[j] - vo * sv[j]) * outscale;
                float ro = (vo * cv[j] + ve * sv[j]) * outscale;
                outp[2 * j]     = (__bf16)re;
                outp[2 * j + 1] = (__bf16)ro;
            }
            if (isq) {
                *(bf16x8*)&qb[(size_t)row * HIDDEN + 8 * lt] = outp;
            } else {
                *(bf16x8*)&kb[(size_t)row * (NKV * HDIM) + 8 * lt - HIDDEN] = outp;
            }
        }
        return;
    }

    // ---- V transpose: vtb[kvh][d][seq] ----
    const int idx = flat - 2048;             // 0..639
    const int s0 = (idx & 127) * 32;
    const int c0 = (idx >> 7) * 32;
    const int tx = tid & 31, ty = tid >> 5;  // 32 x 8
    #pragma unroll
    for (int i = 0; i < 4; ++i)
        t[ty + 8 * i][tx] = qkvb[(size_t)(s0 + ty + 8 * i) * 960 + 800 + c0 + tx];
    __syncthreads();
    #pragma unroll
    for (int i = 0; i < 4; ++i) {
        int g = c0 + ty + 8 * i;             // 0..159
        int kvh = g / HDIM, d = g % HDIM;
        vtb[((size_t)kvh * HDIM + d) * SEQ + s0 + tx] = t[tx][ty + 8 * i];
    }
}

// ---------------------------------------------------------------------------
// GQA-fused MFMA flash attention (r20-proven) + XCD-chunked block swizzle:
// dispatch bx -> i0_idx = (bx%8)*16 + bx/8 (bijective, 128%8==0), so each
// XCD handles 16 CONSECUTIVE q-tiles -> the shared K/V window (4/5 tile
// overlap between neighbors) stays in that XCD's L2.
// ---------------------------------------------------------------------------
__global__ __launch_bounds__(512) void flash_attn_mfma(
    const __bf16* __restrict__ qb, const __bf16* __restrict__ kb,
    const __bf16* __restrict__ vtb, __bf16* __restrict__ attnb)
{
    const int bx   = blockIdx.x;
    const int i0   = ((bx & 7) * 16 + (bx >> 3)) * BQG;   // chunked XCD swizzle
    const int kvh  = blockIdx.y;
    const int tid  = threadIdx.x;        // 0..511
    const int w    = tid >> 6;           // 0..7
    const int h    = kvh * 4 + (w >> 1);
    const int wsub = w & 1;
    const int lane = tid & 63;
    const int l15  = lane & 15;
    const int lq   = lane >> 4;

    __shared__ __bf16 Ks[2][BK][KSTR];   // 53248 B
    __shared__ __bf16 Vt[2][HDIM][VSTR]; // 43520 B
    __shared__ __bf16 Pl[128][VSTR];     // 34816 B
    __shared__ __bf16 Ksk[16][KSTR];     //  3328 B (sink K, keys 0..15)
    __shared__ __bf16 Vtk[HDIM][VSTRK];  //  6400 B (sink V, keys 0..31)

    // zero K pad columns 80..95 of BOTH buffers
    {
        int b = tid >> 8, r = (tid >> 1) & 127, c = HDIM + 8 * (tid & 1);
        *(float4*)&Ks[b][r][c] = make_float4(0.f, 0.f, 0.f, 0.f);
    }

    // constant ones-fragment for the l-accumulator
    bf16x8 vones;
    #pragma unroll
    for (int j = 0; j < 8; ++j) vones[j] = (l15 == 0) ? (__bf16)1.0f : (__bf16)0.0f;

    // window staging maps: 1280 chunks of 8 bf16 each (chunk = tid + 512*i)
    int koff[3], voff[3];
    __bf16* ksdst0[3];
    __bf16* vsdst0[3];
    bool act[3];
    #pragma unroll
    for (int i = 0; i < 3; ++i) {
        int c = tid + 512 * i;
        act[i] = (c < 1280);
        int cc = act[i] ? c : 0;
        koff[i] = (cc / 10) * (NKV * HDIM) + 8 * (cc % 10);
        voff[i] = (cc >> 4) * SEQ + 8 * (cc & 15);
        ksdst0[i] = &Ks[0][cc / 10][8 * (cc % 10)];
        vsdst0[i] = &Vt[0][cc >> 4][8 * (cc & 15)];
    }
    const size_t ksbuf = (size_t)BK * KSTR;
    const size_t vsbuf = (size_t)HDIM * VSTR;
    const __bf16* kbase = kb + kvh * HDIM;
    const __bf16* vbase = vtb + (size_t)kvh * HDIM * SEQ;

    // preload Q A-fragments (q-row i0 + 16*wsub + l15)
    bf16x8 qf[3];
    {
        const __bf16* qrow = qb + (size_t)(i0 + 16 * wsub + l15) * HIDDEN + h * HDIM;
        #pragma unroll
        for (int ks = 0; ks < 3; ++ks) {
            int off = 32 * ks + 8 * lq;
            if (off >= HDIM) off = 0;     // dummy: multiplied by zeroed K pad
            qf[ks] = *(const bf16x8*)&qrow[off];
        }
    }

    float m_i = -1e30f, l_i = 0.0f;       // per-lane: q-row i0+16*wsub+l15
    f32x4 o[6];                           // o[5] = P row-sum accumulator
    #pragma unroll
    for (int n = 0; n < 6; ++n) o[n] = (f32x4)0.0f;

    const int w_lo   = i0 - (WINDOW - 1);
    const int w_tile = (w_lo <= 0) ? 0 : (w_lo & ~(BK - 1));
    const int lastt  = (i0 + BQG - 1) & ~(BK - 1);
    const int n_win  = (lastt - w_tile) / BK + 1;
    const bool has_sink = (w_tile > 0);   // sinks disjoint from window

    // ---- prologue: stage tile 0 + sink K/V, one barrier ----
    bf16x8 krg[3], vrg[3];
    #pragma unroll
    for (int i = 0; i < 3; ++i) {
        if (act[i]) {
            krg[i] = *(const bf16x8*)&kbase[(size_t)w_tile * (NKV * HDIM) + koff[i]];
            vrg[i] = *(const bf16x8*)&vbase[(size_t)w_tile + voff[i]];
        }
    }
    if (has_sink) {
        if (tid < 160) {                 // Ksk: 16 rows x 10 chunks
            int r = tid / 10, c8 = tid % 10;
            *(bf16x8*)&Ksk[r][8 * c8] =
                *(const bf16x8*)&kbase[(size_t)r * (NKV * HDIM) + 8 * c8];
        } else if (tid < 192) {          // Ksk pad cols 80..95
            int r = (tid - 160) >> 1, c = HDIM + 8 * (tid & 1);
            *(float4*)&Ksk[r][c] = make_float4(0.f, 0.f, 0.f, 0.f);
        } else if (tid < 512) {          // Vtk: 80 rows x 4 chunks
            int c = tid - 192;           // 0..319
            *(bf16x8*)&Vtk[c >> 2][8 * (c & 3)] =
                *(const bf16x8*)&vbase[(size_t)(c >> 2) * SEQ + 8 * (c & 3)];
        }
    }
    #pragma unroll
    for (int i = 0; i < 3; ++i) {
        if (act[i]) {
            *(bf16x8*)ksdst0[i] = krg[i];
            *(bf16x8*)vsdst0[i] = vrg[i];
        }
    }
    __syncthreads();

    // ---- sink prepass (swapped): keys = 4lq+r, q-row = l15 ----
    if (has_sink) {
        f32x4 sk = (f32x4)0.0f;
        #pragma unroll
        for (int ks = 0; ks < 3; ++ks) {
            bf16x8 kf = *(const bf16x8*)&Ksk[l15][32 * ks + 8 * lq];
            sk = __builtin_amdgcn_mfma_f32_16x16x32_bf16(kf, qf[ks], sk, 0, 0, 0);
        }
        if (lq != 0) {
            #pragma unroll
            for (int r = 0; r < 4; ++r) sk[r] = -1e30f;
        }
        float mx = fmaxf(fmaxf(sk[0], sk[1]), fmaxf(sk[2], sk[3]));
        mx = fmaxf(mx, __shfl_xor(mx, 16));
        mx = fmaxf(mx, __shfl_xor(mx, 32));
        m_i = mx;
        bf16x4 pk;
        float rsum = 0.0f;
        #pragma unroll
        for (int r = 0; r < 4; ++r) {
            float pe = fexp2(sk[r] - m_i);
            pk[r] = (__bf16)pe;
            rsum += pe;
        }
        *(bf16x4*)&Pl[16 * w + l15][4 * lq] = pk;
        bf16x4 zz;
        #pragma unroll
        for (int r = 0; r < 4; ++r) zz[r] = (__bf16)0.0f;
        *(bf16x4*)&Pl[16 * w + l15][16 + 4 * lq] = zz;
        rsum += __shfl_xor(rsum, 16);
        rsum += __shfl_xor(rsum, 32);
        l_i = rsum;
        #pragma unroll
        for (int n = 0; n < 5; ++n) {
            bf16x8 pf = *(const bf16x8*)&Pl[16 * w + l15][8 * lq];
            bf16x8 vf = *(const bf16x8*)&Vtk[16 * n + l15][8 * lq];
            o[n] = __builtin_amdgcn_mfma_f32_16x16x32_bf16(pf, vf, o[n], 0, 0, 0);
        }
    }

    // ---- main loop: window tiles only, 1 barrier/tile ----
    for (int t = 0; t < n_win; ++t) {
        const int cur = t & 1;
        const int j0 = w_tile + t * BK;
        const bool more = (t + 1 < n_win);

        if (more) {
            const int j1 = j0 + BK;
            #pragma unroll
            for (int i = 0; i < 3; ++i) {
                if (act[i]) {
                    krg[i] = *(const bf16x8*)&kbase[(size_t)j1 * (NKV * HDIM) + koff[i]];
                    vrg[i] = *(const bf16x8*)&vbase[(size_t)j1 + voff[i]];
                }
            }
        }

        // ---- S = K Q^T (swapped): 24 MFMA per wave ----
        f32x4 sacc[8];
        #pragma unroll
        for (int n = 0; n < 8; ++n) sacc[n] = (f32x4)0.0f;
        __builtin_amdgcn_s_setprio(1);
        #pragma unroll
        for (int ks = 0; ks < 3; ++ks) {
            #pragma unroll
            for (int n = 0; n < 8; ++n) {
                bf16x8 kf = *(const bf16x8*)&Ks[cur][n * 16 + l15][32 * ks + 8 * lq];
                sacc[n] = __builtin_amdgcn_mfma_f32_16x16x32_bf16(kf, qf[ks], sacc[n], 0, 0, 0);
            }
        }
        __builtin_amdgcn_s_setprio(0);

        // ---- mask: key j = j0+16n+4lq+r, q i = i0+16wsub+l15 ----
        const bool full = (j0 >= i0 - 480) && (j0 <= i0 - 128);
        if (!full) {
            const int i = i0 + 16 * wsub + l15;
            #pragma unroll
            for (int n = 0; n < 8; ++n) {
                #pragma unroll
                for (int r = 0; r < 4; ++r) {
                    int j = j0 + 16 * n + 4 * lq + r;
                    bool allowed = (j <= i) && ((j >= i - (WINDOW - 1)) || (j < SINK));
                    if (!allowed) sacc[n][r] = -1e30f;
                }
            }
        }

        // ---- online softmax (swapped): in-lane max + 2 shfl ----
        {
            float mx = sacc[0][0];
            #pragma unroll
            for (int n = 0; n < 8; ++n) {
                float a = fmaxf(fmaxf(sacc[n][0], sacc[n][1]),
                                fmaxf(sacc[n][2], sacc[n][3]));
                mx = (n == 0) ? a : fmaxf(mx, a);
            }
            mx = fmaxf(mx, __shfl_xor(mx, 16));
            mx = fmaxf(mx, __shfl_xor(mx, 32));

            float alpha_own = 1.0f;
            bool grow = (mx > m_i);
            if (grow) {
                alpha_own = fexp2(m_i - mx);
                m_i = mx;
                l_i *= alpha_own;
            }
            if (__any(grow)) {
                #pragma unroll
                for (int r = 0; r < 4; ++r) {
                    float ar = __shfl(alpha_own, 4 * lq + r);
                    #pragma unroll
                    for (int n = 0; n < 6; ++n) o[n][r] *= ar;
                }
            }
            #pragma unroll
            for (int n = 0; n < 8; ++n) {
                bf16x4 pk;
                #pragma unroll
                for (int r = 0; r < 4; ++r)
                    pk[r] = (__bf16)fexp2(sacc[n][r] - m_i);
                *(bf16x4*)&Pl[16 * w + l15][16 * n + 4 * lq] = pk;
            }
        }

        // ---- O += P V : 20 MFMA + 4 l-accum MFMA per wave ----
        __builtin_amdgcn_s_setprio(1);
        #pragma unroll
        for (int ks = 0; ks < 4; ++ks) {
            bf16x8 pf = *(const bf16x8*)&Pl[16 * w + l15][32 * ks + 8 * lq];
            #pragma unroll
            for (int n = 0; n < 5; ++n) {
                bf16x8 vf = *(const bf16x8*)&Vt[cur][16 * n + l15][32 * ks + 8 * lq];
                o[n] = __builtin_amdgcn_mfma_f32_16x16x32_bf16(pf, vf, o[n], 0, 0, 0);
            }
            o[5] = __builtin_amdgcn_mfma_f32_16x16x32_bf16(pf, vones, o[5], 0, 0, 0);
        }
        __builtin_amdgcn_s_setprio(0);

        // ---- write next tile into the other buffer, then one barrier ----
        if (more) {
            #pragma unroll
            for (int i = 0; i < 3; ++i) {
                if (act[i]) {
                    *(bf16x8*)(ksdst0[i] + (cur ^ 1) * ksbuf) = krg[i];
                    *(bf16x8*)(vsdst0[i] + (cur ^ 1) * vsbuf) = vrg[i];
                }
            }
            __syncthreads();
        }
    }

    // ---- epilogue: l(row 4lq+r) = shfl(l_i) + o[5]@(l15==0) ----
    #pragma unroll
    for (int r = 0; r < 4; ++r) {
        float l_snk = __shfl(l_i, 4 * lq + r);
        float l_pv  = __shfl(o[5][r], lane & 48);
        float inv = 1.0f / (l_snk + l_pv);
        int row = i0 + 16 * wsub + 4 * lq + r;
        #pragma unroll
        for (int n = 0; n < 5; ++n)
            attnb[(size_t)row * HIDDEN + h * HDIM + 16 * n + l15] = (__bf16)(o[n][r] * inv);
    }
}

// ---------------------------------------------------------------------------
extern "C" void kernel_launch(void* const* d_in, const int* in_sizes, int n_in,
                              void* d_out, int out_size, void* d_ws, size_t ws_size,
                              hipStream_t stream)
{
    const float* x    = (const float*)d_in[0];
    const float* cosb = (const float*)d_in[1];
    const float* sinb = (const float*)d_in[2];
    const float* Wq   = (const float*)d_in[3];
    const float* Wk   = (const float*)d_in[4];
    const float* Wv   = (const float*)d_in[5];
    const float* Wo   = (const float*)d_in[6];
    const float* qw   = (const float*)d_in[7];
    const float* kw   = (const float*)d_in[8];
    float* out = (float*)d_out;

    char* ws = (char*)d_ws;
    __bf16* qkvb  = (__bf16*)ws;                                 // [4096][960]
    __bf16* xb    = qkvb + (size_t)SEQ * 960;                    // [4096][640] = attnb
    __bf16* qb    = xb   + (size_t)SEQ * HIDDEN;                 // [4096][640]
    __bf16* kb    = qb   + (size_t)SEQ * HIDDEN;                 // [4096][160]
    __bf16* vtb   = kb   + (size_t)SEQ * 160;                    // [2][80][4096]
    __bf16* WqkvT = vtb  + (size_t)2 * HDIM * SEQ;               // [1024][640]
    __bf16* WoT   = WqkvT + (size_t)1024 * HIDDEN;               // [640][640]

    prep_kernel<<<dim3(3560), dim3(256), 0, stream>>>(
        x, Wq, Wk, Wv, Wo, xb, WqkvT, WoT);

    gemm_bf16_mfma<__bf16><<<dim3(SEQ / 64, 8), dim3(512), 0, stream>>>(
        xb, WqkvT, qkvb, SEQ, 960, HIDDEN, 960);

    normrope_vt_kernel<<<dim3(2688), dim3(256), 0, stream>>>(
        (const unsigned short*)qkvb, cosb, sinb, qw, kw, qb, kb,
        (unsigned short*)vtb);

    flash_attn_mfma<<<dim3(SEQ / BQG, NKV), dim3(512), 0, stream>>>(
        qb, kb, vtb, xb);

    gemm_bf16_n160<<<dim3(SEQ / 64, HIDDEN / 160), dim3(512), 0, stream>>>(
        xb, WoT, out, SEQ, HIDDEN, HIDDEN);
}